// Round 2
// baseline (982.074 us; speedup 1.0000x reference)
//
#include <hip/hip_runtime.h>
#include <hip/hip_bf16.h>
#include <cstdint>
#include <cstddef>

// SingleheadTransformerDecoderLayer: L=S=2048, N=4, E=1024, FF=4096, fp32 I/O.
// Round 9: LDS bank-conflict fix. Round-8 counters showed 6.3M
// SQ_LDS_BANK_CONFLICT on gemm256 (MfmaUtil 24.5%): the [rows][32] slab put
// fragment-read lanes on only 2 of 8 16B bank-slots (bank bit6 = row parity).
// New slab layout [16 rowgroups][4 koctets][16 rows][8 elems]: every
// fragment read AND every gll16 staging write is one contiguous 1024B
// wave access (lane L at base + L*16) -- the empirically conflict-free
// pattern. Applied to BOTH engines (gemm256 8-phase, gemm_bt 2-phase).
// Ring/phase/vmcnt structure unchanged from round 8.
//
// Workspace layout (161MB):
//   [0,32)    xf   : fp32 residual [8192,1024]
//   [32,48)   hb   : bf16 LN out
//   [48,64)   vb   : bf16 V          } sb bf16 scores [n][l][s] = [32,64)
//   [64,80)   qb   : bf16 Q          }   (hb,vb dead by score-GEMM time)
//   [80,96)   kb   : bf16 K  (reused as attn-out ao after score GEMM)
//   [96,112)  vt   : bf16 V^T [n][e][s]
//   [48,112)  hid  : bf16 MLP hidden [8192,4096] (vb,qb,kb,vt dead)
//   [112,128) memb : bf16 copy of `memory`
//   [128,160) wts  : bf16 weights; [160,161) bb : bf16 biases

using bf16_t = __bf16;
typedef __bf16 bf16x8 __attribute__((ext_vector_type(8)));
typedef __bf16 bf16x4 __attribute__((ext_vector_type(4)));
typedef float f32x4 __attribute__((ext_vector_type(4)));

// ---------------- async global->LDS, 16B/lane, wave-uniform LDS base --------
__device__ __forceinline__ void gll16(const void* g, void* lds) {
  __builtin_amdgcn_global_load_lds(
      (__attribute__((address_space(1))) void*)(g),
      (__attribute__((address_space(3))) void*)(lds), 16, 0, 0);
}

// ---------------- fp32 -> bf16 cast (8 elems/thread) ------------------------
__global__ __launch_bounds__(256) void f32_to_bf16_n(
    const float* __restrict__ in, bf16_t* __restrict__ out, int n) {
  const size_t i = ((size_t)blockIdx.x * 256 + threadIdx.x) * 8;
  if (i >= (size_t)n) return;
  f32x4 a = *(const f32x4*)(in + i);
  f32x4 b = *(const f32x4*)(in + i + 4);
  bf16x8 v;
#pragma unroll
  for (int j = 0; j < 4; ++j) { v[j] = (bf16_t)a[j]; v[4 + j] = (bf16_t)b[j]; }
  *(bf16x8*)(out + i) = v;
}

// ---------------- fused multi-segment fp32 -> bf16 cast ---------------------
struct CastSeg { const float* src; bf16_t* dst; int chunks; };
struct CastDesc { CastSeg s[16]; };
__global__ __launch_bounds__(256) void cast_multi(CastDesc d) {
  int blk = blockIdx.x, seg = 0, base = 0;
  while (blk - base >= d.s[seg].chunks) { base += d.s[seg].chunks; ++seg; }
  const size_t i = (size_t)(blk - base) * 1024 + threadIdx.x * 4;
  f32x4 a = *(const f32x4*)(d.s[seg].src + i);
  bf16x4 v;
#pragma unroll
  for (int j = 0; j < 4; ++j) v[j] = (bf16_t)a[j];
  *(bf16x4*)(d.s[seg].dst + i) = v;
}

// ---------------- LayerNorm over E=1024, one block per row ------------------
__global__ __launch_bounds__(256) void ln_kernel(
    const float* __restrict__ x, const float* __restrict__ g,
    const float* __restrict__ b, bf16_t* __restrict__ out) {
  const int row = blockIdx.x, tid = threadIdx.x;
  const float* xr = x + (size_t)row * 1024;
  float v0 = xr[tid], v1 = xr[tid + 256], v2 = xr[tid + 512], v3 = xr[tid + 768];
  float s = v0 + v1 + v2 + v3;
  float ss = v0 * v0 + v1 * v1 + v2 * v2 + v3 * v3;
#pragma unroll
  for (int off = 32; off > 0; off >>= 1) {
    s += __shfl_down(s, off, 64);
    ss += __shfl_down(ss, off, 64);
  }
  __shared__ float red[8];
  const int w = tid >> 6, lane = tid & 63;
  if (lane == 0) { red[w] = s; red[4 + w] = ss; }
  __syncthreads();
  s = red[0] + red[1] + red[2] + red[3];
  ss = red[4] + red[5] + red[6] + red[7];
  const float mean = s * (1.f / 1024.f);
  float var = ss * (1.f / 1024.f) - mean * mean;
  var = var < 0.f ? 0.f : var;
  const float inv = rsqrtf(var + 1e-5f);
  bf16_t* orow = out + (size_t)row * 1024;
  orow[tid]       = (bf16_t)((v0 - mean) * inv * g[tid]       + b[tid]);
  orow[tid + 256] = (bf16_t)((v1 - mean) * inv * g[tid + 256] + b[tid + 256]);
  orow[tid + 512] = (bf16_t)((v2 - mean) * inv * g[tid + 512] + b[tid + 512]);
  orow[tid + 768] = (bf16_t)((v3 - mean) * inv * g[tid + 768] + b[tid + 768]);
}

// ---------------- softmax over S=2048, bf16 in-place, optional causal -------
template <int CAUSAL>
__global__ __launch_bounds__(256) void softmax_kernel(bf16_t* __restrict__ sc) {
  const int row = blockIdx.x, tid = threadIdx.x;
  const int l = row & 2047;
  bf16_t* sr = sc + (size_t)row * 2048;
  float v[8];
  float mx = -3.4e38f;
#pragma unroll
  for (int i = 0; i < 8; ++i) {
    const int j = tid + i * 256;
    v[i] = (CAUSAL && j > l) ? -3.4e38f : (float)sr[j];
    mx = fmaxf(mx, v[i]);
  }
#pragma unroll
  for (int off = 32; off > 0; off >>= 1) mx = fmaxf(mx, __shfl_down(mx, off, 64));
  __shared__ float red[8];
  const int w = tid >> 6, lane = tid & 63;
  if (lane == 0) red[w] = mx;
  __syncthreads();
  mx = fmaxf(fmaxf(red[0], red[1]), fmaxf(red[2], red[3]));
  float sum = 0.f;
#pragma unroll
  for (int i = 0; i < 8; ++i) { v[i] = __expf(v[i] - mx); sum += v[i]; }
#pragma unroll
  for (int off = 32; off > 0; off >>= 1) sum += __shfl_down(sum, off, 64);
  if (lane == 0) red[4 + w] = sum;
  __syncthreads();
  sum = red[4] + red[5] + red[6] + red[7];
  const float r = 1.f / sum;
#pragma unroll
  for (int i = 0; i < 8; ++i) sr[tid + i * 256] = (bf16_t)(v[i] * r);
}

// ---------------- V transpose: [s*4+n, e] -> vt[n][e][s] --------------------
__global__ __launch_bounds__(256) void transpose_v(const bf16_t* __restrict__ v,
                                                   bf16_t* __restrict__ vt) {
  __shared__ bf16_t tile[64][72];
  const int n = blockIdx.z;
  const int s0 = blockIdx.x * 64, e0 = blockIdx.y * 64;
  const int tid = threadIdx.x;
#pragma unroll
  for (int j = 0; j < 2; ++j) {
    int flat = j * 256 + tid;
    int r = flat >> 3, c8 = (flat & 7) * 8;
    bf16x8 val = *(const bf16x8*)(v + ((size_t)(s0 + r) * 4 + n) * 1024 + e0 + c8);
#pragma unroll
    for (int i = 0; i < 8; ++i) tile[r][c8 + i] = val[i];
  }
  __syncthreads();
#pragma unroll
  for (int j = 0; j < 2; ++j) {
    int flat = j * 256 + tid;
    int er = flat >> 3, s8 = (flat & 7) * 8;
    bf16x8 val;
#pragma unroll
    for (int i = 0; i < 8; ++i) val[i] = tile[s8 + i][er];
    *(bf16x8*)(vt + ((size_t)n * 1024 + e0 + er) * 2048 + s0 + s8) = val;
  }
}

// ---------------- generic C = A @ W^T GEMM, double-buffered LDS -------------
// (old 128x128 engine -- kept for the 128-block grids: PV, out-proj, MLP2)
// Slab layout per kslice: [8 rowgroups][4 koctets][16 rows][8 elems]
//   elem(r,k') at rg*512 + koct*128 + (r&15)*8 + (k'&7); every fragment
//   read and every gll16 write is a contiguous 1024B wave access.
// EPI: 0 = bf16 store (acc+bias)*scale; 1 = bf16 store acc;
//      2 = fp32 store res[idx]+acc+bias; 3 = QuickGELU -> bf16.
// MODE: 0 = plain (z = batch); 1 = causal score (skip col0 > row0);
//       2 = causal PV (K capped at row0+128); 3 = fused QKV.
template <int EPI, int MODE, int NS>
__global__ __launch_bounds__(256) void gemm_bt(
    const bf16_t* __restrict__ A, const bf16_t* __restrict__ Aalt,
    long lda, long sA,
    const bf16_t* __restrict__ W0, const bf16_t* __restrict__ W1,
    const bf16_t* __restrict__ W2, long ldw, long sW,
    void* __restrict__ C0, void* __restrict__ C1, void* __restrict__ C2,
    long ldc, long sC,
    const bf16_t* __restrict__ bias, const float* __restrict__ res,
    float scale, int K) {
  const size_t row0 = (size_t)blockIdx.y * 128;
  const size_t col0 = (size_t)blockIdx.x * 128;
  if (MODE == 1 && col0 > row0) return;  // fully-masked causal tile
  const int z = blockIdx.z;
  constexpr int BK = NS * 32;

  const bf16_t* Ap = (MODE == 3) ? (z == 0 ? A : Aalt) : A + (size_t)z * sA;
  const bf16_t* Wp = (MODE == 3) ? (z == 0 ? W0 : (z == 1 ? W1 : W2))
                                 : W0 + (size_t)z * sW;
  void* Cp = (MODE == 3) ? (z == 0 ? C0 : (z == 1 ? C1 : C2)) : C0;
  const size_t zoffC = (MODE == 3) ? 0 : (size_t)z * sC;
  const bf16_t* biasp = bias ? bias + (MODE == 3 ? z * 1024 : 0) : nullptr;
  const float scl = (MODE == 3 && z != 0) ? 1.f : scale;
  const int kend = (MODE == 2) ? min(K, (int)row0 + 128) : K;

  __shared__ __align__(16) bf16_t As[2][NS][128 * 32];
  __shared__ __align__(16) bf16_t Bs[2][NS][128 * 32];
  const int tid = threadIdx.x;
  const int wv = tid >> 6, lane = tid & 63;
  const int quad = lane >> 4, l15 = lane & 15;
  const int wr = wv >> 1, wc = wv & 1;

  // staging: chunk c = wv*2NS + j covers slab ksc=c>>3, rowgroup rg=c&7;
  // lane L: row rg*16+(L&15), kcol ksc*32+(L>>4)*8. LDS dest rg*512 elems
  // within slab (contiguous 1024B per gll16).
  const bf16_t* gA[2 * NS];
  const bf16_t* gW[2 * NS];
  int dof[2 * NS];  // wave-uniform LDS elem offset within parity buffer
#pragma unroll
  for (int j = 0; j < 2 * NS; ++j) {
    const int c = wv * 2 * NS + j;
    const int ksc = c >> 3;
    const int rg = c & 7;
    const int rr = rg * 16 + (lane & 15);
    const int cc = ksc * 32 + (lane >> 4) * 8;
    gA[j] = Ap + (row0 + rr) * lda + cc;
    gW[j] = Wp + (col0 + rr) * ldw + cc;
    dof[j] = ksc * 4096 + rg * 512;
  }

  f32x4 acc[4][4];
#pragma unroll
  for (int mi = 0; mi < 4; ++mi)
#pragma unroll
    for (int ni = 0; ni < 4; ++ni) acc[mi][ni] = (f32x4)0.f;

#pragma unroll
  for (int j = 0; j < 2 * NS; ++j) {
    gll16(gA[j], &As[0][0][0] + dof[j]);
    gll16(gW[j], &Bs[0][0][0] + dof[j]);
  }

  const int frag = quad * 128 + l15 * 8;  // elems within a 512-elem rowgroup

  int p = 0;
  for (int k0 = 0; k0 < kend; k0 += BK, p ^= 1) {
    __syncthreads();
    const int kn = k0 + BK;
    if (kn < kend) {
#pragma unroll
      for (int j = 0; j < 2 * NS; ++j) {
        gll16(gA[j] + kn, &As[p ^ 1][0][0] + dof[j]);
        gll16(gW[j] + kn, &Bs[p ^ 1][0][0] + dof[j]);
      }
    }
#pragma unroll
    for (int ks = 0; ks < NS; ++ks) {
      bf16x8 af[4], bfv[4];
#pragma unroll
      for (int mi = 0; mi < 4; ++mi)
        af[mi] = *(const bf16x8*)(As[p][ks] + (wr * 4 + mi) * 512 + frag);
#pragma unroll
      for (int ni = 0; ni < 4; ++ni)
        bfv[ni] = *(const bf16x8*)(Bs[p][ks] + (wc * 4 + ni) * 512 + frag);
#pragma unroll
      for (int mi = 0; mi < 4; ++mi)
#pragma unroll
        for (int ni = 0; ni < 4; ++ni)
          acc[mi][ni] = __builtin_amdgcn_mfma_f32_16x16x32_bf16(
              af[mi], bfv[ni], acc[mi][ni], 0, 0, 0);
    }
  }

  float* Cf = (float*)Cp;
  bf16_t* Cb = (bf16_t*)Cp;
#pragma unroll
  for (int mi = 0; mi < 4; ++mi) {
    const size_t gr = row0 + wr * 64 + mi * 16 + quad * 4;
#pragma unroll
    for (int ni = 0; ni < 4; ++ni) {
      const size_t gc = col0 + wc * 64 + ni * 16 + l15;
      float bv = 0.f;
      if (EPI == 0 || EPI == 2 || EPI == 3) bv = biasp ? (float)biasp[gc] : 0.f;
#pragma unroll
      for (int r = 0; r < 4; ++r) {
        float v = acc[mi][ni][r];
        const size_t idx = zoffC + (gr + r) * ldc + gc;
        if (EPI == 0) {
          Cb[idx] = (bf16_t)((v + bv) * scl);
        } else if (EPI == 1) {
          Cb[idx] = (bf16_t)v;
        } else if (EPI == 2) {
          Cf[idx] = res[idx] + v + bv;
        } else {
          float t = v + bv;
          Cb[idx] = (bf16_t)(t * (1.f / (1.f + __expf(-1.702f * t))));
        }
      }
    }
  }
}

// ---------------- 256x256 8-phase GEMM engine (T3+T4+T5) --------------------
// 512 threads = 8 waves (2M x 4N); wave tile 128x64; BK=64 as two kslice
// slots per operand; 2x double-buffer => 8 slots, 128 KiB total.
// Slab layout per kslice slot: [16 rowgroups][4 koctets][16 rows][8 elems]
//   elem(r,k') at (r>>4)*512 + (k'>>3)*128 + (r&15)*8 + (k'&7).
//   Fragment read (m,ks): lanes cover one contiguous 1024B block
//   (quad*128 + l15*8 elems) -> conflict-free; gll16 staging writes one
//   1024B rowgroup per call (wave-uniform dest rg*512), per-lane global
//   src row rg*16+(L&15), kcol (L>>4)*8 (16x64B coalesced lines).
// Half-tile ring: half h = {tile u=h>>2, ks=(h>>1)&1, op=h&1}, issued at
// phase g = h-6. Phase g=4t+q computes quadrant q of tile t (kk=q>>1,
// mh=q&1, 16 MFMA). Steady-state wait: vmcnt(6) at each tile boundary
// (3 newest halves in flight); vmcnt(0) only for the last tile. Raw
// s_barrier everywhere -- no __syncthreads() in the loop.
// EPI: 0 = bf16 (acc+bias)*scale; 1 = bf16 acc; 3 = QuickGELU bf16.
// MODE: 0 = plain z-batch; 1 = causal score (skip bx>by); 3 = fused QKV.
template <int EPI, int MODE>
__global__ __launch_bounds__(512, 2) void gemm256(
    const bf16_t* __restrict__ A, const bf16_t* __restrict__ Aalt,
    long lda, long sA,
    const bf16_t* __restrict__ W0, const bf16_t* __restrict__ W1,
    const bf16_t* __restrict__ W2, long ldw, long sW,
    void* __restrict__ C0, void* __restrict__ C1, void* __restrict__ C2,
    long ldc, long sC,
    const bf16_t* __restrict__ bias, float scale, int K) {
  // XCD-aware bijective chunked swizzle (all launch grids have nwg % 8 == 0).
  const int gx = gridDim.x, gy = gridDim.y;
  const int nwg = gx * gy * (int)gridDim.z;
  const int hw = (int)blockIdx.x + gx * ((int)blockIdx.y + gy * (int)blockIdx.z);
  const int logical = (hw & 7) * (nwg >> 3) + (hw >> 3);
  const int bx = logical % gx;
  const int by = (logical / gx) % gy;
  const int z  = logical / (gx * gy);
  const size_t row0 = (size_t)by * 256, col0 = (size_t)bx * 256;
  if (MODE == 1 && bx > by) return;  // fully-masked causal tile

  const bf16_t* Ap = (MODE == 3) ? (z == 0 ? A : Aalt) : A + (size_t)z * sA;
  const bf16_t* Wp = (MODE == 3) ? (z == 0 ? W0 : (z == 1 ? W1 : W2))
                                 : W0 + (size_t)z * sW;
  void* Cp = (MODE == 3) ? (z == 0 ? C0 : (z == 1 ? C1 : C2)) : C0;
  const size_t zoffC = (MODE == 3) ? 0 : (size_t)z * sC;
  const bf16_t* biasp = bias ? bias + (MODE == 3 ? z * 1024 : 0) : nullptr;
  const float scl = (MODE == 3 && z != 0) ? 1.f : scale;

  __shared__ __align__(16) bf16_t As[2][2][8192];  // [parity][kslice]
  __shared__ __align__(16) bf16_t Bs[2][2][8192];

  const int tid = threadIdx.x;
  const int lane = tid & 63, wid = tid >> 6;
  const int l15 = lane & 15, quad = lane >> 4;
  const int wm = wid >> 2, wn = wid & 3;

  // Staging: wave wid covers rowgroups 2*wid and 2*wid+1 of each half.
  const bf16_t* pA[2];
  const bf16_t* pB[2];
#pragma unroll
  for (int j = 0; j < 2; ++j) {
    const int rr = (wid * 2 + j) * 16 + (lane & 15);
    const int kc = (lane >> 4) * 8;
    pA[j] = Ap + (row0 + rr) * lda + kc;
    pB[j] = Wp + (col0 + rr) * ldw + kc;
  }
  const int d0 = (wid * 2) * 512;      // wave-uniform LDS elem base, j=0
  const int d1 = (wid * 2 + 1) * 512;  // j=1

  const int T = K >> 6;    // number of BK=64 tiles
  const int HT = 4 * T;    // total half-tiles

  auto stage = [&](int h) {
    if (h >= HT) return;
    const int u = h >> 2, ks = (h >> 1) & 1;
    const int coff = u * 64 + ks * 32;
    if (h & 1) {
      gll16(pB[0] + coff, &Bs[u & 1][ks][0] + d0);
      gll16(pB[1] + coff, &Bs[u & 1][ks][0] + d1);
    } else {
      gll16(pA[0] + coff, &As[u & 1][ks][0] + d0);
      gll16(pA[1] + coff, &As[u & 1][ks][0] + d1);
    }
  };

  f32x4 acc[2][4][4];
#pragma unroll
  for (int mh = 0; mh < 2; ++mh)
#pragma unroll
    for (int mi = 0; mi < 4; ++mi)
#pragma unroll
      for (int ni = 0; ni < 4; ++ni) acc[mh][mi][ni] = (f32x4)0.f;

  // prologue: 6 halves in flight before the first compute phase
#pragma unroll
  for (int h = 0; h < 6; ++h) stage(h);

  const int frag = quad * 128 + l15 * 8;  // elems within a 512-elem rowgroup

  for (int t = 0; t < T; ++t) {
    const int p = t & 1;
    const int g4 = 4 * t;
    bf16x8 bfv[4];

// PH: phase 0..3; KK: k-slice; MH: fragment-half. B fragments loaded when
// MH==0, reused (in regs, across the barrier) when MH==1.
#define PHASE(PH, KK, MH)                                                     \
    {                                                                         \
      stage(g4 + 6 + PH);                                                     \
      bf16x8 af[4];                                                           \
      if (PH == 0) {                                                          \
        /* gate tile t's staging: all but newest 3 halves complete */         \
        if (t + 1 < T) asm volatile("s_waitcnt vmcnt(6)" ::: "memory");       \
        else           asm volatile("s_waitcnt vmcnt(0)" ::: "memory");       \
        __builtin_amdgcn_s_barrier();                                         \
      }                                                                       \
      _Pragma("unroll")                                                       \
      for (int mi = 0; mi < 4; ++mi)                                          \
        af[mi] = *(const bf16x8*)(&As[p][KK][0] +                             \
                                  (wm * 8 + MH * 4 + mi) * 512 + frag);       \
      if (MH == 0) {                                                          \
        _Pragma("unroll")                                                     \
        for (int ni = 0; ni < 4; ++ni)                                        \
          bfv[ni] = *(const bf16x8*)(&Bs[p][KK][0] +                          \
                                     (wn * 4 + ni) * 512 + frag);             \
      }                                                                       \
      if (PH != 0) __builtin_amdgcn_s_barrier();                              \
      asm volatile("s_waitcnt lgkmcnt(0)" ::: "memory");                      \
      __builtin_amdgcn_sched_barrier(0);                                      \
      __builtin_amdgcn_s_setprio(1);                                         \
      _Pragma("unroll")                                                       \
      for (int mi = 0; mi < 4; ++mi)                                          \
        _Pragma("unroll")                                                     \
        for (int ni = 0; ni < 4; ++ni)                                        \
          acc[MH][mi][ni] = __builtin_amdgcn_mfma_f32_16x16x32_bf16(          \
              af[mi], bfv[ni], acc[MH][mi][ni], 0, 0, 0);                     \
      __builtin_amdgcn_s_setprio(0);                                          \
      __builtin_amdgcn_s_barrier();                                           \
    }

    PHASE(0, 0, 0)
    PHASE(1, 0, 1)
    PHASE(2, 1, 0)
    PHASE(3, 1, 1)
#undef PHASE
  }

  // epilogue: C/D layout col=lane&15, row=quad*4+r
  bf16_t* Cb = (bf16_t*)Cp;
#pragma unroll
  for (int mh = 0; mh < 2; ++mh)
#pragma unroll
    for (int mi = 0; mi < 4; ++mi) {
      const size_t gr = row0 + wm * 128 + mh * 64 + mi * 16 + quad * 4;
#pragma unroll
      for (int ni = 0; ni < 4; ++ni) {
        const size_t gc = col0 + wn * 64 + ni * 16 + l15;
        float bv = 0.f;
        if (EPI == 0 || EPI == 3) bv = biasp ? (float)biasp[gc] : 0.f;
#pragma unroll
        for (int r = 0; r < 4; ++r) {
          const float v = acc[mh][mi][ni][r];
          const size_t idx = zoffC + (gr + r) * ldc + gc;
          if (EPI == 0) {
            Cb[idx] = (bf16_t)((v + bv) * scl);
          } else if (EPI == 1) {
            Cb[idx] = (bf16_t)v;
          } else {
            const float tt = v + bv;
            Cb[idx] = (bf16_t)(tt * (1.f / (1.f + __expf(-1.702f * tt))));
          }
        }
      }
    }
}

// ---------------- host-side launch helpers ----------------------------------
template <int EPI, int MODE, int NS = 1>
static void launch_gemm(hipStream_t stream, int M, int N, int Z,
                        const void* A, const void* Aalt, long lda, long sA,
                        const void* W0, const void* W1, const void* W2,
                        long ldw, long sW,
                        void* C0, void* C1, void* C2, long ldc, long sC,
                        const void* bias, const float* res, float scale, int K) {
  dim3 grid(N / 128, M / 128, Z);
  gemm_bt<EPI, MODE, NS><<<grid, dim3(256), 0, stream>>>(
      (const bf16_t*)A, (const bf16_t*)Aalt, lda, sA,
      (const bf16_t*)W0, (const bf16_t*)W1, (const bf16_t*)W2, ldw, sW,
      C0, C1, C2, ldc, sC, (const bf16_t*)bias, res, scale, K);
}

template <int EPI, int MODE>
static void launch_gemm256(hipStream_t stream, int M, int N, int Z,
                           const void* A, const void* Aalt, long lda, long sA,
                           const void* W0, const void* W1, const void* W2,
                           long ldw, long sW,
                           void* C0, void* C1, void* C2, long ldc, long sC,
                           const void* bias, float scale, int K) {
  dim3 grid(N / 256, M / 256, Z);  // nwg % 8 == 0 for all call sites
  gemm256<EPI, MODE><<<grid, dim3(512), 0, stream>>>(
      (const bf16_t*)A, (const bf16_t*)Aalt, lda, sA,
      (const bf16_t*)W0, (const bf16_t*)W1, (const bf16_t*)W2, ldw, sW,
      C0, C1, C2, ldc, sC, (const bf16_t*)bias, scale, K);
}

extern "C" void kernel_launch(void* const* d_in, const int* in_sizes, int n_in,
                              void* d_out, int out_size, void* d_ws, size_t ws_size,
                              hipStream_t stream) {
  (void)in_sizes; (void)n_in; (void)out_size; (void)ws_size;
  const float* tgt  = (const float*)d_in[0];
  const float* mem  = (const float*)d_in[1];
  // d_in[2] (mask) unused: causality applied structurally.
  const float* sa_qw = (const float*)d_in[3];
  const float* sa_kw = (const float*)d_in[4];
  const float* sa_vw = (const float*)d_in[5];
  const float* sa_b  = (const float*)d_in[6];
  const float* sa_ow = (const float*)d_in[7];
  const float* sa_ob = (const float*)d_in[8];
  const float* ca_qw = (const float*)d_in[9];
  const float* ca_kw = (const float*)d_in[10];
  const float* ca_vw = (const float*)d_in[11];
  const float* ca_b  = (const float*)d_in[12];
  const float* ca_ow = (const float*)d_in[13];
  const float* ca_ob = (const float*)d_in[14];
  const float* ln1g = (const float*)d_in[15];
  const float* ln1b = (const float*)d_in[16];
  const float* ln2g = (const float*)d_in[17];
  const float* ln2b = (const float*)d_in[18];
  const float* ln3g = (const float*)d_in[19];
  const float* ln3b = (const float*)d_in[20];
  const float* w1 = (const float*)d_in[21];
  const float* b1 = (const float*)d_in[22];
  const float* w2 = (const float*)d_in[23];
  const float* b2 = (const float*)d_in[24];

  char* ws = (char*)d_ws;
  const size_t MB = 1048576;
  float*  xf   = (float*)(ws);             // [0,32)   fp32 residual
  bf16_t* hb   = (bf16_t*)(ws + 32 * MB);  // [32,48)  LN out
  bf16_t* vb   = (bf16_t*)(ws + 48 * MB);  // [48,64)  V
  bf16_t* qb   = (bf16_t*)(ws + 64 * MB);  // [64,80)  Q
  bf16_t* kb   = (bf16_t*)(ws + 80 * MB);  // [80,96)  K
  bf16_t* vt   = (bf16_t*)(ws + 96 * MB);  // [96,112) V^T [n][e][s]
  bf16_t* sb   = (bf16_t*)(ws + 32 * MB);  // [32,64)  scores/probs
  bf16_t* ao   = kb;                       // [80,96)  attn out (kb dead)
  bf16_t* hid  = (bf16_t*)(ws + 48 * MB);  // [48,112) MLP hidden
  bf16_t* memb = (bf16_t*)(ws + 112 * MB); // [112,128) bf16 memory
  bf16_t* wt   = (bf16_t*)(ws + 128 * MB); // [128,160) bf16 weights
  bf16_t* bb   = (bf16_t*)(ws + 160 * MB); // biases

  const size_t M1 = 1048576;  // elems per E*E weight
  bf16_t* saq = wt,          *sak = wt + M1,     *sav = wt + 2 * M1;
  bf16_t* sao = wt + 3 * M1, *caq = wt + 4 * M1, *cak = wt + 5 * M1;
  bf16_t* cav = wt + 6 * M1, *cao = wt + 7 * M1;
  bf16_t* w1b = wt + 8 * M1;   // 4M elems
  bf16_t* w2b = wt + 12 * M1;  // 4M elems

  const float qscale = 0.03125f;  // 1024^-0.5

  // ---- fused weight/bias conversions (one launch) ----
  CastDesc cd;
  auto seg = [&](int i, const float* s, bf16_t* d, int elems) {
    cd.s[i] = CastSeg{s, d, elems / 1024};
  };
  seg(0, sa_qw, saq, 1 << 20);  seg(1, sa_kw, sak, 1 << 20);
  seg(2, sa_vw, sav, 1 << 20);  seg(3, sa_ow, sao, 1 << 20);
  seg(4, ca_qw, caq, 1 << 20);  seg(5, ca_kw, cak, 1 << 20);
  seg(6, ca_vw, cav, 1 << 20);  seg(7, ca_ow, cao, 1 << 20);
  seg(8, w1, w1b, 1 << 22);     seg(9, w2, w2b, 1 << 22);
  seg(10, sa_b, bb, 3072);      seg(11, sa_ob, bb + 3072, 1024);
  seg(12, ca_b, bb + 4096, 3072); seg(13, ca_ob, bb + 7168, 1024);
  seg(14, b1, bb + 8192, 4096); seg(15, b2, bb + 12288, 1024);
  int total_chunks = 0;
  for (int i = 0; i < 16; ++i) total_chunks += cd.s[i].chunks;
  cast_multi<<<total_chunks, 256, 0, stream>>>(cd);
  f32_to_bf16_n<<<4096, 256, 0, stream>>>(mem, memb, 1 << 23);

  // ================= self-attention (causal) =================
  ln_kernel<<<8192, 256, 0, stream>>>(tgt, ln1g, ln1b, hb);
  launch_gemm256<0, 3>(stream, 8192, 1024, 3, hb, hb, 1024, 0,
                       saq, sak, sav, 1024, 0, qb, kb, vb, 1024, 0,
                       bb, qscale, 1024);
  transpose_v<<<dim3(32, 16, 4), 256, 0, stream>>>(vb, vt);
  launch_gemm256<1, 1>(stream, 2048, 2048, 4, qb, nullptr, 4096, 1024,
                       kb, nullptr, nullptr, 4096, 1024,
                       sb, nullptr, nullptr, 2048, 4194304, nullptr,
                       1.f, 1024);
  softmax_kernel<1><<<8192, 256, 0, stream>>>(sb);
  launch_gemm<0, 2, 2>(stream, 2048, 1024, 4, sb, nullptr, 2048, 4194304,
                       vt, nullptr, nullptr, 2048, 2097152,
                       ao, nullptr, nullptr, 4096, 1024, nullptr, nullptr,
                       1.f, 2048);
  launch_gemm<2, 0, 2>(stream, 8192, 1024, 1, ao, nullptr, 1024, 0,
                       sao, nullptr, nullptr, 1024, 0,
                       xf, nullptr, nullptr, 1024, 0, bb + 3072, tgt,
                       1.f, 1024);

  // ================= cross-attention (no mask) =================
  ln_kernel<<<8192, 256, 0, stream>>>(xf, ln2g, ln2b, hb);
  launch_gemm256<0, 3>(stream, 8192, 1024, 3, hb, memb, 1024, 0,
                       caq, cak, cav, 1024, 0, qb, kb, vb, 1024, 0,
                       bb + 4096, qscale, 1024);
  transpose_v<<<dim3(32, 16, 4), 256, 0, stream>>>(vb, vt);
  launch_gemm256<1, 0>(stream, 2048, 2048, 4, qb, nullptr, 4096, 1024,
                       kb, nullptr, nullptr, 4096, 1024,
                       sb, nullptr, nullptr, 2048, 4194304, nullptr,
                       1.f, 1024);
  softmax_kernel<0><<<8192, 256, 0, stream>>>(sb);
  launch_gemm<0, 0, 2>(stream, 2048, 1024, 4, sb, nullptr, 2048, 4194304,
                       vt, nullptr, nullptr, 2048, 2097152,
                       ao, nullptr, nullptr, 4096, 1024, nullptr, nullptr,
                       1.f, 2048);
  launch_gemm<2, 0, 2>(stream, 8192, 1024, 1, ao, nullptr, 1024, 0,
                       cao, nullptr, nullptr, 1024, 0,
                       xf, nullptr, nullptr, 1024, 0, bb + 7168, xf,
                       1.f, 1024);

  // ================= MLP (QuickGELU) =================
  ln_kernel<<<8192, 256, 0, stream>>>(xf, ln3g, ln3b, hb);
  launch_gemm256<3, 0>(stream, 8192, 4096, 1, hb, nullptr, 1024, 0,
                       w1b, nullptr, nullptr, 1024, 0,
                       hid, nullptr, nullptr, 4096, 0, bb + 8192,
                       1.f, 1024);
  launch_gemm<2, 0, 2>(stream, 8192, 1024, 1, hid, nullptr, 4096, 0,
                       w2b, nullptr, nullptr, 4096, 0,
                       d_out, nullptr, nullptr, 1024, 0, bb + 12288, xf,
                       1.f, 4096);
}

// Round 3
// 826.156 us; speedup vs baseline: 1.1887x; 1.1887x over previous
//
#include <hip/hip_runtime.h>
#include <hip/hip_bf16.h>
#include <cstdint>
#include <cstddef>

// SingleheadTransformerDecoderLayer: L=S=2048, N=4, E=1024, FF=4096, fp32 I/O.
// Round 10: both-sides LDS swizzle. Round-8 layout ([rows][32] slabs, 64B row
// stride, lane-adjacent staging) had 4-8 way bank conflicts on fragment reads
// (8.4M/6.3M conflicts, MfmaUtil ~25%). Round-9's contiguous-LDS fix zeroed
// conflicts but scattered the per-lane global staging reads (16 rows per
// 16-lane group) -> VMEM coalescer couldn't merge -> FETCH_SIZE 2.7-4x
// (282MB on MLP2), HBM-bound regression. This round keeps round-8's
// lane-adjacent global pattern AND conflict-free reads via a 16B-slot
// involution XOR keyed on row: slot' = slot ^ ((row>>1)&3).
//   - read side: frag elem = row*32 + (quad ^ ((l15>>1)&3))*8 -> each
//     8-lane octet hits 8 distinct (row-parity, slot) = all 32 banks.
//   - write side: gll16 stays linear (1024B rowgroups); global source
//     k-octet = (lane&3) ^ ((lane>>3)&3) -- permutation WITHIN each 64B
//     run, so lanes 4q..4q+3 still cover one aligned 64B line (coalesced).
// Same involution on both sides (rule #21). Ring/phase/vmcnt unchanged.
//
// Workspace layout (161MB):
//   [0,32)    xf   : fp32 residual [8192,1024]
//   [32,48)   hb   : bf16 LN out
//   [48,64)   vb   : bf16 V          } sb bf16 scores [n][l][s] = [32,64)
//   [64,80)   qb   : bf16 Q          }   (hb,vb dead by score-GEMM time)
//   [80,96)   kb   : bf16 K  (reused as attn-out ao after score GEMM)
//   [96,112)  vt   : bf16 V^T [n][e][s]
//   [48,112)  hid  : bf16 MLP hidden [8192,4096] (vb,qb,kb,vt dead)
//   [112,128) memb : bf16 copy of `memory`
//   [128,160) wts  : bf16 weights; [160,161) bb : bf16 biases

using bf16_t = __bf16;
typedef __bf16 bf16x8 __attribute__((ext_vector_type(8)));
typedef __bf16 bf16x4 __attribute__((ext_vector_type(4)));
typedef float f32x4 __attribute__((ext_vector_type(4)));

// ---------------- async global->LDS, 16B/lane, wave-uniform LDS base --------
__device__ __forceinline__ void gll16(const void* g, void* lds) {
  __builtin_amdgcn_global_load_lds(
      (__attribute__((address_space(1))) void*)(g),
      (__attribute__((address_space(3))) void*)(lds), 16, 0, 0);
}

// ---------------- fp32 -> bf16 cast (8 elems/thread) ------------------------
__global__ __launch_bounds__(256) void f32_to_bf16_n(
    const float* __restrict__ in, bf16_t* __restrict__ out, int n) {
  const size_t i = ((size_t)blockIdx.x * 256 + threadIdx.x) * 8;
  if (i >= (size_t)n) return;
  f32x4 a = *(const f32x4*)(in + i);
  f32x4 b = *(const f32x4*)(in + i + 4);
  bf16x8 v;
#pragma unroll
  for (int j = 0; j < 4; ++j) { v[j] = (bf16_t)a[j]; v[4 + j] = (bf16_t)b[j]; }
  *(bf16x8*)(out + i) = v;
}

// ---------------- fused multi-segment fp32 -> bf16 cast ---------------------
struct CastSeg { const float* src; bf16_t* dst; int chunks; };
struct CastDesc { CastSeg s[16]; };
__global__ __launch_bounds__(256) void cast_multi(CastDesc d) {
  int blk = blockIdx.x, seg = 0, base = 0;
  while (blk - base >= d.s[seg].chunks) { base += d.s[seg].chunks; ++seg; }
  const size_t i = (size_t)(blk - base) * 1024 + threadIdx.x * 4;
  f32x4 a = *(const f32x4*)(d.s[seg].src + i);
  bf16x4 v;
#pragma unroll
  for (int j = 0; j < 4; ++j) v[j] = (bf16_t)a[j];
  *(bf16x4*)(d.s[seg].dst + i) = v;
}

// ---------------- LayerNorm over E=1024, one block per row ------------------
__global__ __launch_bounds__(256) void ln_kernel(
    const float* __restrict__ x, const float* __restrict__ g,
    const float* __restrict__ b, bf16_t* __restrict__ out) {
  const int row = blockIdx.x, tid = threadIdx.x;
  const float* xr = x + (size_t)row * 1024;
  float v0 = xr[tid], v1 = xr[tid + 256], v2 = xr[tid + 512], v3 = xr[tid + 768];
  float s = v0 + v1 + v2 + v3;
  float ss = v0 * v0 + v1 * v1 + v2 * v2 + v3 * v3;
#pragma unroll
  for (int off = 32; off > 0; off >>= 1) {
    s += __shfl_down(s, off, 64);
    ss += __shfl_down(ss, off, 64);
  }
  __shared__ float red[8];
  const int w = tid >> 6, lane = tid & 63;
  if (lane == 0) { red[w] = s; red[4 + w] = ss; }
  __syncthreads();
  s = red[0] + red[1] + red[2] + red[3];
  ss = red[4] + red[5] + red[6] + red[7];
  const float mean = s * (1.f / 1024.f);
  float var = ss * (1.f / 1024.f) - mean * mean;
  var = var < 0.f ? 0.f : var;
  const float inv = rsqrtf(var + 1e-5f);
  bf16_t* orow = out + (size_t)row * 1024;
  orow[tid]       = (bf16_t)((v0 - mean) * inv * g[tid]       + b[tid]);
  orow[tid + 256] = (bf16_t)((v1 - mean) * inv * g[tid + 256] + b[tid + 256]);
  orow[tid + 512] = (bf16_t)((v2 - mean) * inv * g[tid + 512] + b[tid + 512]);
  orow[tid + 768] = (bf16_t)((v3 - mean) * inv * g[tid + 768] + b[tid + 768]);
}

// ---------------- softmax over S=2048, bf16 in-place, optional causal -------
template <int CAUSAL>
__global__ __launch_bounds__(256) void softmax_kernel(bf16_t* __restrict__ sc) {
  const int row = blockIdx.x, tid = threadIdx.x;
  const int l = row & 2047;
  bf16_t* sr = sc + (size_t)row * 2048;
  float v[8];
  float mx = -3.4e38f;
#pragma unroll
  for (int i = 0; i < 8; ++i) {
    const int j = tid + i * 256;
    v[i] = (CAUSAL && j > l) ? -3.4e38f : (float)sr[j];
    mx = fmaxf(mx, v[i]);
  }
#pragma unroll
  for (int off = 32; off > 0; off >>= 1) mx = fmaxf(mx, __shfl_down(mx, off, 64));
  __shared__ float red[8];
  const int w = tid >> 6, lane = tid & 63;
  if (lane == 0) red[w] = mx;
  __syncthreads();
  mx = fmaxf(fmaxf(red[0], red[1]), fmaxf(red[2], red[3]));
  float sum = 0.f;
#pragma unroll
  for (int i = 0; i < 8; ++i) { v[i] = __expf(v[i] - mx); sum += v[i]; }
#pragma unroll
  for (int off = 32; off > 0; off >>= 1) sum += __shfl_down(sum, off, 64);
  if (lane == 0) red[4 + w] = sum;
  __syncthreads();
  sum = red[4] + red[5] + red[6] + red[7];
  const float r = 1.f / sum;
#pragma unroll
  for (int i = 0; i < 8; ++i) sr[tid + i * 256] = (bf16_t)(v[i] * r);
}

// ---------------- V transpose: [s*4+n, e] -> vt[n][e][s] --------------------
__global__ __launch_bounds__(256) void transpose_v(const bf16_t* __restrict__ v,
                                                   bf16_t* __restrict__ vt) {
  __shared__ bf16_t tile[64][72];
  const int n = blockIdx.z;
  const int s0 = blockIdx.x * 64, e0 = blockIdx.y * 64;
  const int tid = threadIdx.x;
#pragma unroll
  for (int j = 0; j < 2; ++j) {
    int flat = j * 256 + tid;
    int r = flat >> 3, c8 = (flat & 7) * 8;
    bf16x8 val = *(const bf16x8*)(v + ((size_t)(s0 + r) * 4 + n) * 1024 + e0 + c8);
#pragma unroll
    for (int i = 0; i < 8; ++i) tile[r][c8 + i] = val[i];
  }
  __syncthreads();
#pragma unroll
  for (int j = 0; j < 2; ++j) {
    int flat = j * 256 + tid;
    int er = flat >> 3, s8 = (flat & 7) * 8;
    bf16x8 val;
#pragma unroll
    for (int i = 0; i < 8; ++i) val[i] = tile[s8 + i][er];
    *(bf16x8*)(vt + ((size_t)n * 1024 + e0 + er) * 2048 + s0 + s8) = val;
  }
}

// ---------------- generic C = A @ W^T GEMM, double-buffered LDS -------------
// (128x128 engine -- for the 128-block grids: PV, out-proj, MLP2)
// Slab per kslice = [128 rows][32 k] row-major (64B row stride), 16B slots
// swizzled: elem(r,k) at byte r*64 + ((k>>3)^((r>>1)&3))*16 + (k&7)*2.
// Staging: gll16 writes linear 1024B rowgroups; global source lane L reads
// row rg*16+(L>>2), k-octet (L&3)^((L>>3)&3) (permutation within one 64B
// run -> coalesced). Frag read: row*32 + (quad^((l15>>1)&3))*8 elems.
// EPI: 0 = bf16 store (acc+bias)*scale; 1 = bf16 store acc;
//      2 = fp32 store res[idx]+acc+bias; 3 = QuickGELU -> bf16.
// MODE: 0 = plain (z = batch); 1 = causal score (skip col0 > row0);
//       2 = causal PV (K capped at row0+128); 3 = fused QKV.
template <int EPI, int MODE, int NS>
__global__ __launch_bounds__(256) void gemm_bt(
    const bf16_t* __restrict__ A, const bf16_t* __restrict__ Aalt,
    long lda, long sA,
    const bf16_t* __restrict__ W0, const bf16_t* __restrict__ W1,
    const bf16_t* __restrict__ W2, long ldw, long sW,
    void* __restrict__ C0, void* __restrict__ C1, void* __restrict__ C2,
    long ldc, long sC,
    const bf16_t* __restrict__ bias, const float* __restrict__ res,
    float scale, int K) {
  const size_t row0 = (size_t)blockIdx.y * 128;
  const size_t col0 = (size_t)blockIdx.x * 128;
  if (MODE == 1 && col0 > row0) return;  // fully-masked causal tile
  const int z = blockIdx.z;
  constexpr int BK = NS * 32;

  const bf16_t* Ap = (MODE == 3) ? (z == 0 ? A : Aalt) : A + (size_t)z * sA;
  const bf16_t* Wp = (MODE == 3) ? (z == 0 ? W0 : (z == 1 ? W1 : W2))
                                 : W0 + (size_t)z * sW;
  void* Cp = (MODE == 3) ? (z == 0 ? C0 : (z == 1 ? C1 : C2)) : C0;
  const size_t zoffC = (MODE == 3) ? 0 : (size_t)z * sC;
  const bf16_t* biasp = bias ? bias + (MODE == 3 ? z * 1024 : 0) : nullptr;
  const float scl = (MODE == 3 && z != 0) ? 1.f : scale;
  const int kend = (MODE == 2) ? min(K, (int)row0 + 128) : K;

  __shared__ __align__(16) bf16_t As[2][NS][128 * 32];
  __shared__ __align__(16) bf16_t Bs[2][NS][128 * 32];
  const int tid = threadIdx.x;
  const int wv = tid >> 6, lane = tid & 63;
  const int quad = lane >> 4, l15 = lane & 15;
  const int wr = wv >> 1, wc = wv & 1;

  // staging: chunk c = wv*2NS+j -> kslice ksc=c>>3, rowgroup rg=c&7.
  // lane L: row rg*16+(L>>2), k-octet (L&3)^((L>>3)&3) (64B-local perm).
  const bf16_t* gA[2 * NS];
  const bf16_t* gW[2 * NS];
  int dof[2 * NS];  // wave-uniform LDS elem offset within parity buffer
  const int soct = (lane & 3) ^ ((lane >> 3) & 3);
#pragma unroll
  for (int j = 0; j < 2 * NS; ++j) {
    const int c = wv * 2 * NS + j;
    const int ksc = c >> 3;
    const int rg = c & 7;
    const int rr = rg * 16 + (lane >> 2);
    const int cc = ksc * 32 + soct * 8;
    gA[j] = Ap + (row0 + rr) * lda + cc;
    gW[j] = Wp + (col0 + rr) * ldw + cc;
    dof[j] = ksc * 4096 + rg * 512;
  }

  f32x4 acc[4][4];
#pragma unroll
  for (int mi = 0; mi < 4; ++mi)
#pragma unroll
    for (int ni = 0; ni < 4; ++ni) acc[mi][ni] = (f32x4)0.f;

#pragma unroll
  for (int j = 0; j < 2 * NS; ++j) {
    gll16(gA[j], &As[0][0][0] + dof[j]);
    gll16(gW[j], &Bs[0][0][0] + dof[j]);
  }

  // frag lane offset: row=base+l15 -> l15*32 + swizzled 16B slot
  const int fro = l15 * 32 + (quad ^ ((l15 >> 1) & 3)) * 8;

  int p = 0;
  for (int k0 = 0; k0 < kend; k0 += BK, p ^= 1) {
    __syncthreads();
    const int kn = k0 + BK;
    if (kn < kend) {
#pragma unroll
      for (int j = 0; j < 2 * NS; ++j) {
        gll16(gA[j] + kn, &As[p ^ 1][0][0] + dof[j]);
        gll16(gW[j] + kn, &Bs[p ^ 1][0][0] + dof[j]);
      }
    }
#pragma unroll
    for (int ks = 0; ks < NS; ++ks) {
      bf16x8 af[4], bfv[4];
#pragma unroll
      for (int mi = 0; mi < 4; ++mi)
        af[mi] = *(const bf16x8*)(As[p][ks] + (wr * 4 + mi) * 512 + fro);
#pragma unroll
      for (int ni = 0; ni < 4; ++ni)
        bfv[ni] = *(const bf16x8*)(Bs[p][ks] + (wc * 4 + ni) * 512 + fro);
#pragma unroll
      for (int mi = 0; mi < 4; ++mi)
#pragma unroll
        for (int ni = 0; ni < 4; ++ni)
          acc[mi][ni] = __builtin_amdgcn_mfma_f32_16x16x32_bf16(
              af[mi], bfv[ni], acc[mi][ni], 0, 0, 0);
    }
  }

  float* Cf = (float*)Cp;
  bf16_t* Cb = (bf16_t*)Cp;
#pragma unroll
  for (int mi = 0; mi < 4; ++mi) {
    const size_t gr = row0 + wr * 64 + mi * 16 + quad * 4;
#pragma unroll
    for (int ni = 0; ni < 4; ++ni) {
      const size_t gc = col0 + wc * 64 + ni * 16 + l15;
      float bv = 0.f;
      if (EPI == 0 || EPI == 2 || EPI == 3) bv = biasp ? (float)biasp[gc] : 0.f;
#pragma unroll
      for (int r = 0; r < 4; ++r) {
        float v = acc[mi][ni][r];
        const size_t idx = zoffC + (gr + r) * ldc + gc;
        if (EPI == 0) {
          Cb[idx] = (bf16_t)((v + bv) * scl);
        } else if (EPI == 1) {
          Cb[idx] = (bf16_t)v;
        } else if (EPI == 2) {
          Cf[idx] = res[idx] + v + bv;
        } else {
          float t = v + bv;
          Cb[idx] = (bf16_t)(t * (1.f / (1.f + __expf(-1.702f * t))));
        }
      }
    }
  }
}

// ---------------- 256x256 8-phase GEMM engine (T3+T4+T5) --------------------
// 512 threads = 8 waves (2M x 4N); wave tile 128x64; BK=64 as two kslice
// slots per operand; 2x double-buffer => 8 slots, 128 KiB total.
// Slab per kslice slot = [256 rows][32 k] row-major with the same 16B-slot
// swizzle as gemm_bt (see above). Staging: wave wid covers rowgroups
// 2wid, 2wid+1 per half; lane L reads row rg*16+(L>>2), k-octet
// (L&3)^((L>>3)&3); gll16 dest linear rowgroups.
// Half-tile ring: half h = {tile u=h>>2, ks=(h>>1)&1, op=h&1}, issued at
// phase g = h-6. Phase g=4t+q computes quadrant q of tile t (kk=q>>1,
// mh=q&1, 16 MFMA). Steady-state wait: vmcnt(6) at each tile boundary
// (3 newest halves in flight); vmcnt(0) only for the last tile. Raw
// s_barrier everywhere -- no __syncthreads() in the loop.
// EPI: 0 = bf16 (acc+bias)*scale; 1 = bf16 acc; 3 = QuickGELU bf16.
// MODE: 0 = plain z-batch; 1 = causal score (skip bx>by); 3 = fused QKV.
template <int EPI, int MODE>
__global__ __launch_bounds__(512, 2) void gemm256(
    const bf16_t* __restrict__ A, const bf16_t* __restrict__ Aalt,
    long lda, long sA,
    const bf16_t* __restrict__ W0, const bf16_t* __restrict__ W1,
    const bf16_t* __restrict__ W2, long ldw, long sW,
    void* __restrict__ C0, void* __restrict__ C1, void* __restrict__ C2,
    long ldc, long sC,
    const bf16_t* __restrict__ bias, float scale, int K) {
  // XCD-aware bijective chunked swizzle (all launch grids have nwg % 8 == 0).
  const int gx = gridDim.x, gy = gridDim.y;
  const int nwg = gx * gy * (int)gridDim.z;
  const int hw = (int)blockIdx.x + gx * ((int)blockIdx.y + gy * (int)blockIdx.z);
  const int logical = (hw & 7) * (nwg >> 3) + (hw >> 3);
  const int bx = logical % gx;
  const int by = (logical / gx) % gy;
  const int z  = logical / (gx * gy);
  const size_t row0 = (size_t)by * 256, col0 = (size_t)bx * 256;
  if (MODE == 1 && bx > by) return;  // fully-masked causal tile

  const bf16_t* Ap = (MODE == 3) ? (z == 0 ? A : Aalt) : A + (size_t)z * sA;
  const bf16_t* Wp = (MODE == 3) ? (z == 0 ? W0 : (z == 1 ? W1 : W2))
                                 : W0 + (size_t)z * sW;
  void* Cp = (MODE == 3) ? (z == 0 ? C0 : (z == 1 ? C1 : C2)) : C0;
  const size_t zoffC = (MODE == 3) ? 0 : (size_t)z * sC;
  const bf16_t* biasp = bias ? bias + (MODE == 3 ? z * 1024 : 0) : nullptr;
  const float scl = (MODE == 3 && z != 0) ? 1.f : scale;

  __shared__ __align__(16) bf16_t As[2][2][8192];  // [parity][kslice]
  __shared__ __align__(16) bf16_t Bs[2][2][8192];

  const int tid = threadIdx.x;
  const int lane = tid & 63, wid = tid >> 6;
  const int l15 = lane & 15, quad = lane >> 4;
  const int wm = wid >> 2, wn = wid & 3;

  // Staging: wave wid covers rowgroups 2*wid and 2*wid+1 of each half.
  const int soct = (lane & 3) ^ ((lane >> 3) & 3);
  const bf16_t* pA[2];
  const bf16_t* pB[2];
#pragma unroll
  for (int j = 0; j < 2; ++j) {
    const int rr = (wid * 2 + j) * 16 + (lane >> 2);
    const int kc = soct * 8;
    pA[j] = Ap + (row0 + rr) * lda + kc;
    pB[j] = Wp + (col0 + rr) * ldw + kc;
  }
  const int d0 = (wid * 2) * 512;      // wave-uniform LDS elem base, j=0
  const int d1 = (wid * 2 + 1) * 512;  // j=1

  const int T = K >> 6;    // number of BK=64 tiles
  const int HT = 4 * T;    // total half-tiles

  auto stage = [&](int h) {
    if (h >= HT) return;
    const int u = h >> 2, ks = (h >> 1) & 1;
    const int coff = u * 64 + ks * 32;
    if (h & 1) {
      gll16(pB[0] + coff, &Bs[u & 1][ks][0] + d0);
      gll16(pB[1] + coff, &Bs[u & 1][ks][0] + d1);
    } else {
      gll16(pA[0] + coff, &As[u & 1][ks][0] + d0);
      gll16(pA[1] + coff, &As[u & 1][ks][0] + d1);
    }
  };

  f32x4 acc[2][4][4];
#pragma unroll
  for (int mh = 0; mh < 2; ++mh)
#pragma unroll
    for (int mi = 0; mi < 4; ++mi)
#pragma unroll
      for (int ni = 0; ni < 4; ++ni) acc[mh][mi][ni] = (f32x4)0.f;

  // prologue: 6 halves in flight before the first compute phase
#pragma unroll
  for (int h = 0; h < 6; ++h) stage(h);

  // frag lane offset: row=base+l15 -> l15*32 + swizzled 16B slot
  const int fro = l15 * 32 + (quad ^ ((l15 >> 1) & 3)) * 8;

  for (int t = 0; t < T; ++t) {
    const int p = t & 1;
    const int g4 = 4 * t;
    bf16x8 bfv[4];

// PH: phase 0..3; KK: k-slice; MH: fragment-half. B fragments loaded when
// MH==0, reused (in regs, across the barrier) when MH==1.
#define PHASE(PH, KK, MH)                                                     \
    {                                                                         \
      stage(g4 + 6 + PH);                                                     \
      bf16x8 af[4];                                                           \
      if (PH == 0) {                                                          \
        /* gate tile t's staging: all but newest 3 halves complete */         \
        if (t + 1 < T) asm volatile("s_waitcnt vmcnt(6)" ::: "memory");       \
        else           asm volatile("s_waitcnt vmcnt(0)" ::: "memory");       \
        __builtin_amdgcn_s_barrier();                                         \
      }                                                                       \
      _Pragma("unroll")                                                       \
      for (int mi = 0; mi < 4; ++mi)                                          \
        af[mi] = *(const bf16x8*)(&As[p][KK][0] +                             \
                                  (wm * 8 + MH * 4 + mi) * 512 + fro);        \
      if (MH == 0) {                                                          \
        _Pragma("unroll")                                                     \
        for (int ni = 0; ni < 4; ++ni)                                        \
          bfv[ni] = *(const bf16x8*)(&Bs[p][KK][0] +                          \
                                     (wn * 4 + ni) * 512 + fro);              \
      }                                                                       \
      if (PH != 0) __builtin_amdgcn_s_barrier();                              \
      asm volatile("s_waitcnt lgkmcnt(0)" ::: "memory");                      \
      __builtin_amdgcn_sched_barrier(0);                                      \
      __builtin_amdgcn_s_setprio(1);                                         \
      _Pragma("unroll")                                                       \
      for (int mi = 0; mi < 4; ++mi)                                          \
        _Pragma("unroll")                                                     \
        for (int ni = 0; ni < 4; ++ni)                                        \
          acc[MH][mi][ni] = __builtin_amdgcn_mfma_f32_16x16x32_bf16(          \
              af[mi], bfv[ni], acc[MH][mi][ni], 0, 0, 0);                     \
      __builtin_amdgcn_s_setprio(0);                                          \
      __builtin_amdgcn_s_barrier();                                           \
    }

    PHASE(0, 0, 0)
    PHASE(1, 0, 1)
    PHASE(2, 1, 0)
    PHASE(3, 1, 1)
#undef PHASE
  }

  // epilogue: C/D layout col=lane&15, row=quad*4+r
  bf16_t* Cb = (bf16_t*)Cp;
#pragma unroll
  for (int mh = 0; mh < 2; ++mh)
#pragma unroll
    for (int mi = 0; mi < 4; ++mi) {
      const size_t gr = row0 + wm * 128 + mh * 64 + mi * 16 + quad * 4;
#pragma unroll
      for (int ni = 0; ni < 4; ++ni) {
        const size_t gc = col0 + wn * 64 + ni * 16 + l15;
        float bv = 0.f;
        if (EPI == 0 || EPI == 3) bv = biasp ? (float)biasp[gc] : 0.f;
#pragma unroll
        for (int r = 0; r < 4; ++r) {
          const float v = acc[mh][mi][ni][r];
          const size_t idx = zoffC + (gr + r) * ldc + gc;
          if (EPI == 0) {
            Cb[idx] = (bf16_t)((v + bv) * scl);
          } else if (EPI == 1) {
            Cb[idx] = (bf16_t)v;
          } else {
            const float tt = v + bv;
            Cb[idx] = (bf16_t)(tt * (1.f / (1.f + __expf(-1.702f * tt))));
          }
        }
      }
    }
}

// ---------------- host-side launch helpers ----------------------------------
template <int EPI, int MODE, int NS = 1>
static void launch_gemm(hipStream_t stream, int M, int N, int Z,
                        const void* A, const void* Aalt, long lda, long sA,
                        const void* W0, const void* W1, const void* W2,
                        long ldw, long sW,
                        void* C0, void* C1, void* C2, long ldc, long sC,
                        const void* bias, const float* res, float scale, int K) {
  dim3 grid(N / 128, M / 128, Z);
  gemm_bt<EPI, MODE, NS><<<grid, dim3(256), 0, stream>>>(
      (const bf16_t*)A, (const bf16_t*)Aalt, lda, sA,
      (const bf16_t*)W0, (const bf16_t*)W1, (const bf16_t*)W2, ldw, sW,
      C0, C1, C2, ldc, sC, (const bf16_t*)bias, res, scale, K);
}

template <int EPI, int MODE>
static void launch_gemm256(hipStream_t stream, int M, int N, int Z,
                           const void* A, const void* Aalt, long lda, long sA,
                           const void* W0, const void* W1, const void* W2,
                           long ldw, long sW,
                           void* C0, void* C1, void* C2, long ldc, long sC,
                           const void* bias, float scale, int K) {
  dim3 grid(N / 256, M / 256, Z);  // nwg % 8 == 0 for all call sites
  gemm256<EPI, MODE><<<grid, dim3(512), 0, stream>>>(
      (const bf16_t*)A, (const bf16_t*)Aalt, lda, sA,
      (const bf16_t*)W0, (const bf16_t*)W1, (const bf16_t*)W2, ldw, sW,
      C0, C1, C2, ldc, sC, (const bf16_t*)bias, scale, K);
}

extern "C" void kernel_launch(void* const* d_in, const int* in_sizes, int n_in,
                              void* d_out, int out_size, void* d_ws, size_t ws_size,
                              hipStream_t stream) {
  (void)in_sizes; (void)n_in; (void)out_size; (void)ws_size;
  const float* tgt  = (const float*)d_in[0];
  const float* mem  = (const float*)d_in[1];
  // d_in[2] (mask) unused: causality applied structurally.
  const float* sa_qw = (const float*)d_in[3];
  const float* sa_kw = (const float*)d_in[4];
  const float* sa_vw = (const float*)d_in[5];
  const float* sa_b  = (const float*)d_in[6];
  const float* sa_ow = (const float*)d_in[7];
  const float* sa_ob = (const float*)d_in[8];
  const float* ca_qw = (const float*)d_in[9];
  const float* ca_kw = (const float*)d_in[10];
  const float* ca_vw = (const float*)d_in[11];
  const float* ca_b  = (const float*)d_in[12];
  const float* ca_ow = (const float*)d_in[13];
  const float* ca_ob = (const float*)d_in[14];
  const float* ln1g = (const float*)d_in[15];
  const float* ln1b = (const float*)d_in[16];
  const float* ln2g = (const float*)d_in[17];
  const float* ln2b = (const float*)d_in[18];
  const float* ln3g = (const float*)d_in[19];
  const float* ln3b = (const float*)d_in[20];
  const float* w1 = (const float*)d_in[21];
  const float* b1 = (const float*)d_in[22];
  const float* w2 = (const float*)d_in[23];
  const float* b2 = (const float*)d_in[24];

  char* ws = (char*)d_ws;
  const size_t MB = 1048576;
  float*  xf   = (float*)(ws);             // [0,32)   fp32 residual
  bf16_t* hb   = (bf16_t*)(ws + 32 * MB);  // [32,48)  LN out
  bf16_t* vb   = (bf16_t*)(ws + 48 * MB);  // [48,64)  V
  bf16_t* qb   = (bf16_t*)(ws + 64 * MB);  // [64,80)  Q
  bf16_t* kb   = (bf16_t*)(ws + 80 * MB);  // [80,96)  K
  bf16_t* vt   = (bf16_t*)(ws + 96 * MB);  // [96,112) V^T [n][e][s]
  bf16_t* sb   = (bf16_t*)(ws + 32 * MB);  // [32,64)  scores/probs
  bf16_t* ao   = kb;                       // [80,96)  attn out (kb dead)
  bf16_t* hid  = (bf16_t*)(ws + 48 * MB);  // [48,112) MLP hidden
  bf16_t* memb = (bf16_t*)(ws + 112 * MB); // [112,128) bf16 memory
  bf16_t* wt   = (bf16_t*)(ws + 128 * MB); // [128,160) bf16 weights
  bf16_t* bb   = (bf16_t*)(ws + 160 * MB); // biases

  const size_t M1 = 1048576;  // elems per E*E weight
  bf16_t* saq = wt,          *sak = wt + M1,     *sav = wt + 2 * M1;
  bf16_t* sao = wt + 3 * M1, *caq = wt + 4 * M1, *cak = wt + 5 * M1;
  bf16_t* cav = wt + 6 * M1, *cao = wt + 7 * M1;
  bf16_t* w1b = wt + 8 * M1;   // 4M elems
  bf16_t* w2b = wt + 12 * M1;  // 4M elems

  const float qscale = 0.03125f;  // 1024^-0.5

  // ---- fused weight/bias conversions (one launch) ----
  CastDesc cd;
  auto seg = [&](int i, const float* s, bf16_t* d, int elems) {
    cd.s[i] = CastSeg{s, d, elems / 1024};
  };
  seg(0, sa_qw, saq, 1 << 20);  seg(1, sa_kw, sak, 1 << 20);
  seg(2, sa_vw, sav, 1 << 20);  seg(3, sa_ow, sao, 1 << 20);
  seg(4, ca_qw, caq, 1 << 20);  seg(5, ca_kw, cak, 1 << 20);
  seg(6, ca_vw, cav, 1 << 20);  seg(7, ca_ow, cao, 1 << 20);
  seg(8, w1, w1b, 1 << 22);     seg(9, w2, w2b, 1 << 22);
  seg(10, sa_b, bb, 3072);      seg(11, sa_ob, bb + 3072, 1024);
  seg(12, ca_b, bb + 4096, 3072); seg(13, ca_ob, bb + 7168, 1024);
  seg(14, b1, bb + 8192, 4096); seg(15, b2, bb + 12288, 1024);
  int total_chunks = 0;
  for (int i = 0; i < 16; ++i) total_chunks += cd.s[i].chunks;
  cast_multi<<<total_chunks, 256, 0, stream>>>(cd);
  f32_to_bf16_n<<<4096, 256, 0, stream>>>(mem, memb, 1 << 23);

  // ================= self-attention (causal) =================
  ln_kernel<<<8192, 256, 0, stream>>>(tgt, ln1g, ln1b, hb);
  launch_gemm256<0, 3>(stream, 8192, 1024, 3, hb, hb, 1024, 0,
                       saq, sak, sav, 1024, 0, qb, kb, vb, 1024, 0,
                       bb, qscale, 1024);
  transpose_v<<<dim3(32, 16, 4), 256, 0, stream>>>(vb, vt);
  launch_gemm256<1, 1>(stream, 2048, 2048, 4, qb, nullptr, 4096, 1024,
                       kb, nullptr, nullptr, 4096, 1024,
                       sb, nullptr, nullptr, 2048, 4194304, nullptr,
                       1.f, 1024);
  softmax_kernel<1><<<8192, 256, 0, stream>>>(sb);
  launch_gemm<0, 2, 2>(stream, 2048, 1024, 4, sb, nullptr, 2048, 4194304,
                       vt, nullptr, nullptr, 2048, 2097152,
                       ao, nullptr, nullptr, 4096, 1024, nullptr, nullptr,
                       1.f, 2048);
  launch_gemm<2, 0, 2>(stream, 8192, 1024, 1, ao, nullptr, 1024, 0,
                       sao, nullptr, nullptr, 1024, 0,
                       xf, nullptr, nullptr, 1024, 0, bb + 3072, tgt,
                       1.f, 1024);

  // ================= cross-attention (no mask) =================
  ln_kernel<<<8192, 256, 0, stream>>>(xf, ln2g, ln2b, hb);
  launch_gemm256<0, 3>(stream, 8192, 1024, 3, hb, memb, 1024, 0,
                       caq, cak, cav, 1024, 0, qb, kb, vb, 1024, 0,
                       bb + 4096, qscale, 1024);
  transpose_v<<<dim3(32, 16, 4), 256, 0, stream>>>(vb, vt);
  launch_gemm256<1, 0>(stream, 2048, 2048, 4, qb, nullptr, 4096, 1024,
                       kb, nullptr, nullptr, 4096, 1024,
                       sb, nullptr, nullptr, 2048, 4194304, nullptr,
                       1.f, 1024);
  softmax_kernel<0><<<8192, 256, 0, stream>>>(sb);
  launch_gemm<0, 0, 2>(stream, 2048, 1024, 4, sb, nullptr, 2048, 4194304,
                       vt, nullptr, nullptr, 2048, 2097152,
                       ao, nullptr, nullptr, 4096, 1024, nullptr, nullptr,
                       1.f, 2048);
  launch_gemm<2, 0, 2>(stream, 8192, 1024, 1, ao, nullptr, 1024, 0,
                       cao, nullptr, nullptr, 1024, 0,
                       xf, nullptr, nullptr, 1024, 0, bb + 7168, xf,
                       1.f, 1024);

  // ================= MLP (QuickGELU) =================
  ln_kernel<<<8192, 256, 0, stream>>>(xf, ln3g, ln3b, hb);
  launch_gemm256<3, 0>(stream, 8192, 4096, 1, hb, nullptr, 1024, 0,
                       w1b, nullptr, nullptr, 1024, 0,
                       hid, nullptr, nullptr, 4096, 0, bb + 8192,
                       1.f, 1024);
  launch_gemm<2, 0, 2>(stream, 8192, 1024, 1, hid, nullptr, 4096, 0,
                       w2b, nullptr, nullptr, 4096, 0,
                       d_out, nullptr, nullptr, 1024, 0, bb + 12288, xf,
                       1.f, 4096);
}

// Round 4
// 821.799 us; speedup vs baseline: 1.1950x; 1.0053x over previous
//
#include <hip/hip_runtime.h>
#include <hip/hip_bf16.h>
#include <cstdint>
#include <cstddef>

// SingleheadTransformerDecoderLayer: L=S=2048, N=4, E=1024, FF=4096, fp32 I/O.
// Round 11: un-pin the gemm256 schedule. Round-10 got conflicts to 0 and
// fetch to ideal, yet gemm256 sat at 608 TF == m233's 2-phase stall number:
// the per-phase sched_barrier(0)+lgkmcnt(0) (rule-#18 cargo-cult; only
// needed for asm ds_reads) plus 2 barriers/phase fully serialized
// [read burst | LDS wait | MFMA burst | 2x barrier] = ~2100 cyc/phase vs
// 620 MFMA floor. New phase = [vmcnt(4|0) @PH0] -> s_barrier -> stage ->
// ds_read -> setprio/16xMFMA/setprio. One barrier per phase; compiler now
// interleaves ds_read with MFMA via its own fine-grained lgkmcnt. Hazards
// re-audited: stage@PHk writes a slot last read at phase k-1; reader's
// reads complete before its MFMAs, which precede barrier@k, which gates
// the writer. vmcnt count at PH0 is 4 (2 halves in flight) since stage
// now issues after the barrier. gemm_bt engine untouched.
//
// Workspace layout (161MB):
//   [0,32)    xf   : fp32 residual [8192,1024]
//   [32,48)   hb   : bf16 LN out
//   [48,64)   vb   : bf16 V          } sb bf16 scores [n][l][s] = [32,64)
//   [64,80)   qb   : bf16 Q          }   (hb,vb dead by score-GEMM time)
//   [80,96)   kb   : bf16 K  (reused as attn-out ao after score GEMM)
//   [96,112)  vt   : bf16 V^T [n][e][s]
//   [48,112)  hid  : bf16 MLP hidden [8192,4096] (vb,qb,kb,vt dead)
//   [112,128) memb : bf16 copy of `memory`
//   [128,160) wts  : bf16 weights; [160,161) bb : bf16 biases

using bf16_t = __bf16;
typedef __bf16 bf16x8 __attribute__((ext_vector_type(8)));
typedef __bf16 bf16x4 __attribute__((ext_vector_type(4)));
typedef float f32x4 __attribute__((ext_vector_type(4)));

// ---------------- async global->LDS, 16B/lane, wave-uniform LDS base --------
__device__ __forceinline__ void gll16(const void* g, void* lds) {
  __builtin_amdgcn_global_load_lds(
      (__attribute__((address_space(1))) void*)(g),
      (__attribute__((address_space(3))) void*)(lds), 16, 0, 0);
}

// ---------------- fp32 -> bf16 cast (8 elems/thread) ------------------------
__global__ __launch_bounds__(256) void f32_to_bf16_n(
    const float* __restrict__ in, bf16_t* __restrict__ out, int n) {
  const size_t i = ((size_t)blockIdx.x * 256 + threadIdx.x) * 8;
  if (i >= (size_t)n) return;
  f32x4 a = *(const f32x4*)(in + i);
  f32x4 b = *(const f32x4*)(in + i + 4);
  bf16x8 v;
#pragma unroll
  for (int j = 0; j < 4; ++j) { v[j] = (bf16_t)a[j]; v[4 + j] = (bf16_t)b[j]; }
  *(bf16x8*)(out + i) = v;
}

// ---------------- fused multi-segment fp32 -> bf16 cast ---------------------
struct CastSeg { const float* src; bf16_t* dst; int chunks; };
struct CastDesc { CastSeg s[16]; };
__global__ __launch_bounds__(256) void cast_multi(CastDesc d) {
  int blk = blockIdx.x, seg = 0, base = 0;
  while (blk - base >= d.s[seg].chunks) { base += d.s[seg].chunks; ++seg; }
  const size_t i = (size_t)(blk - base) * 1024 + threadIdx.x * 4;
  f32x4 a = *(const f32x4*)(d.s[seg].src + i);
  bf16x4 v;
#pragma unroll
  for (int j = 0; j < 4; ++j) v[j] = (bf16_t)a[j];
  *(bf16x4*)(d.s[seg].dst + i) = v;
}

// ---------------- LayerNorm over E=1024, one block per row ------------------
__global__ __launch_bounds__(256) void ln_kernel(
    const float* __restrict__ x, const float* __restrict__ g,
    const float* __restrict__ b, bf16_t* __restrict__ out) {
  const int row = blockIdx.x, tid = threadIdx.x;
  const float* xr = x + (size_t)row * 1024;
  float v0 = xr[tid], v1 = xr[tid + 256], v2 = xr[tid + 512], v3 = xr[tid + 768];
  float s = v0 + v1 + v2 + v3;
  float ss = v0 * v0 + v1 * v1 + v2 * v2 + v3 * v3;
#pragma unroll
  for (int off = 32; off > 0; off >>= 1) {
    s += __shfl_down(s, off, 64);
    ss += __shfl_down(ss, off, 64);
  }
  __shared__ float red[8];
  const int w = tid >> 6, lane = tid & 63;
  if (lane == 0) { red[w] = s; red[4 + w] = ss; }
  __syncthreads();
  s = red[0] + red[1] + red[2] + red[3];
  ss = red[4] + red[5] + red[6] + red[7];
  const float mean = s * (1.f / 1024.f);
  float var = ss * (1.f / 1024.f) - mean * mean;
  var = var < 0.f ? 0.f : var;
  const float inv = rsqrtf(var + 1e-5f);
  bf16_t* orow = out + (size_t)row * 1024;
  orow[tid]       = (bf16_t)((v0 - mean) * inv * g[tid]       + b[tid]);
  orow[tid + 256] = (bf16_t)((v1 - mean) * inv * g[tid + 256] + b[tid + 256]);
  orow[tid + 512] = (bf16_t)((v2 - mean) * inv * g[tid + 512] + b[tid + 512]);
  orow[tid + 768] = (bf16_t)((v3 - mean) * inv * g[tid + 768] + b[tid + 768]);
}

// ---------------- softmax over S=2048, bf16 in-place, optional causal -------
template <int CAUSAL>
__global__ __launch_bounds__(256) void softmax_kernel(bf16_t* __restrict__ sc) {
  const int row = blockIdx.x, tid = threadIdx.x;
  const int l = row & 2047;
  bf16_t* sr = sc + (size_t)row * 2048;
  float v[8];
  float mx = -3.4e38f;
#pragma unroll
  for (int i = 0; i < 8; ++i) {
    const int j = tid + i * 256;
    v[i] = (CAUSAL && j > l) ? -3.4e38f : (float)sr[j];
    mx = fmaxf(mx, v[i]);
  }
#pragma unroll
  for (int off = 32; off > 0; off >>= 1) mx = fmaxf(mx, __shfl_down(mx, off, 64));
  __shared__ float red[8];
  const int w = tid >> 6, lane = tid & 63;
  if (lane == 0) red[w] = mx;
  __syncthreads();
  mx = fmaxf(fmaxf(red[0], red[1]), fmaxf(red[2], red[3]));
  float sum = 0.f;
#pragma unroll
  for (int i = 0; i < 8; ++i) { v[i] = __expf(v[i] - mx); sum += v[i]; }
#pragma unroll
  for (int off = 32; off > 0; off >>= 1) sum += __shfl_down(sum, off, 64);
  if (lane == 0) red[4 + w] = sum;
  __syncthreads();
  sum = red[4] + red[5] + red[6] + red[7];
  const float r = 1.f / sum;
#pragma unroll
  for (int i = 0; i < 8; ++i) sr[tid + i * 256] = (bf16_t)(v[i] * r);
}

// ---------------- V transpose: [s*4+n, e] -> vt[n][e][s] --------------------
__global__ __launch_bounds__(256) void transpose_v(const bf16_t* __restrict__ v,
                                                   bf16_t* __restrict__ vt) {
  __shared__ bf16_t tile[64][72];
  const int n = blockIdx.z;
  const int s0 = blockIdx.x * 64, e0 = blockIdx.y * 64;
  const int tid = threadIdx.x;
#pragma unroll
  for (int j = 0; j < 2; ++j) {
    int flat = j * 256 + tid;
    int r = flat >> 3, c8 = (flat & 7) * 8;
    bf16x8 val = *(const bf16x8*)(v + ((size_t)(s0 + r) * 4 + n) * 1024 + e0 + c8);
#pragma unroll
    for (int i = 0; i < 8; ++i) tile[r][c8 + i] = val[i];
  }
  __syncthreads();
#pragma unroll
  for (int j = 0; j < 2; ++j) {
    int flat = j * 256 + tid;
    int er = flat >> 3, s8 = (flat & 7) * 8;
    bf16x8 val;
#pragma unroll
    for (int i = 0; i < 8; ++i) val[i] = tile[s8 + i][er];
    *(bf16x8*)(vt + ((size_t)n * 1024 + e0 + er) * 2048 + s0 + s8) = val;
  }
}

// ---------------- generic C = A @ W^T GEMM, double-buffered LDS -------------
// (128x128 engine -- for the 128-block grids: PV, out-proj, MLP2)
// Slab per kslice = [128 rows][32 k] row-major (64B row stride), 16B slots
// swizzled: elem(r,k) at byte r*64 + ((k>>3)^((r>>1)&3))*16 + (k&7)*2.
// Staging: gll16 writes linear 1024B rowgroups; global source lane L reads
// row rg*16+(L>>2), k-octet (L&3)^((L>>3)&3) (permutation within one 64B
// run -> coalesced). Frag read: row*32 + (quad^((l15>>1)&3))*8 elems.
// EPI: 0 = bf16 store (acc+bias)*scale; 1 = bf16 store acc;
//      2 = fp32 store res[idx]+acc+bias; 3 = QuickGELU -> bf16.
// MODE: 0 = plain (z = batch); 1 = causal score (skip col0 > row0);
//       2 = causal PV (K capped at row0+128); 3 = fused QKV.
template <int EPI, int MODE, int NS>
__global__ __launch_bounds__(256) void gemm_bt(
    const bf16_t* __restrict__ A, const bf16_t* __restrict__ Aalt,
    long lda, long sA,
    const bf16_t* __restrict__ W0, const bf16_t* __restrict__ W1,
    const bf16_t* __restrict__ W2, long ldw, long sW,
    void* __restrict__ C0, void* __restrict__ C1, void* __restrict__ C2,
    long ldc, long sC,
    const bf16_t* __restrict__ bias, const float* __restrict__ res,
    float scale, int K) {
  const size_t row0 = (size_t)blockIdx.y * 128;
  const size_t col0 = (size_t)blockIdx.x * 128;
  if (MODE == 1 && col0 > row0) return;  // fully-masked causal tile
  const int z = blockIdx.z;
  constexpr int BK = NS * 32;

  const bf16_t* Ap = (MODE == 3) ? (z == 0 ? A : Aalt) : A + (size_t)z * sA;
  const bf16_t* Wp = (MODE == 3) ? (z == 0 ? W0 : (z == 1 ? W1 : W2))
                                 : W0 + (size_t)z * sW;
  void* Cp = (MODE == 3) ? (z == 0 ? C0 : (z == 1 ? C1 : C2)) : C0;
  const size_t zoffC = (MODE == 3) ? 0 : (size_t)z * sC;
  const bf16_t* biasp = bias ? bias + (MODE == 3 ? z * 1024 : 0) : nullptr;
  const float scl = (MODE == 3 && z != 0) ? 1.f : scale;
  const int kend = (MODE == 2) ? min(K, (int)row0 + 128) : K;

  __shared__ __align__(16) bf16_t As[2][NS][128 * 32];
  __shared__ __align__(16) bf16_t Bs[2][NS][128 * 32];
  const int tid = threadIdx.x;
  const int wv = tid >> 6, lane = tid & 63;
  const int quad = lane >> 4, l15 = lane & 15;
  const int wr = wv >> 1, wc = wv & 1;

  // staging: chunk c = wv*2NS+j -> kslice ksc=c>>3, rowgroup rg=c&7.
  // lane L: row rg*16+(L>>2), k-octet (L&3)^((L>>3)&3) (64B-local perm).
  const bf16_t* gA[2 * NS];
  const bf16_t* gW[2 * NS];
  int dof[2 * NS];  // wave-uniform LDS elem offset within parity buffer
  const int soct = (lane & 3) ^ ((lane >> 3) & 3);
#pragma unroll
  for (int j = 0; j < 2 * NS; ++j) {
    const int c = wv * 2 * NS + j;
    const int ksc = c >> 3;
    const int rg = c & 7;
    const int rr = rg * 16 + (lane >> 2);
    const int cc = ksc * 32 + soct * 8;
    gA[j] = Ap + (row0 + rr) * lda + cc;
    gW[j] = Wp + (col0 + rr) * ldw + cc;
    dof[j] = ksc * 4096 + rg * 512;
  }

  f32x4 acc[4][4];
#pragma unroll
  for (int mi = 0; mi < 4; ++mi)
#pragma unroll
    for (int ni = 0; ni < 4; ++ni) acc[mi][ni] = (f32x4)0.f;

#pragma unroll
  for (int j = 0; j < 2 * NS; ++j) {
    gll16(gA[j], &As[0][0][0] + dof[j]);
    gll16(gW[j], &Bs[0][0][0] + dof[j]);
  }

  // frag lane offset: row=base+l15 -> l15*32 + swizzled 16B slot
  const int fro = l15 * 32 + (quad ^ ((l15 >> 1) & 3)) * 8;

  int p = 0;
  for (int k0 = 0; k0 < kend; k0 += BK, p ^= 1) {
    __syncthreads();
    const int kn = k0 + BK;
    if (kn < kend) {
#pragma unroll
      for (int j = 0; j < 2 * NS; ++j) {
        gll16(gA[j] + kn, &As[p ^ 1][0][0] + dof[j]);
        gll16(gW[j] + kn, &Bs[p ^ 1][0][0] + dof[j]);
      }
    }
#pragma unroll
    for (int ks = 0; ks < NS; ++ks) {
      bf16x8 af[4], bfv[4];
#pragma unroll
      for (int mi = 0; mi < 4; ++mi)
        af[mi] = *(const bf16x8*)(As[p][ks] + (wr * 4 + mi) * 512 + fro);
#pragma unroll
      for (int ni = 0; ni < 4; ++ni)
        bfv[ni] = *(const bf16x8*)(Bs[p][ks] + (wc * 4 + ni) * 512 + fro);
#pragma unroll
      for (int mi = 0; mi < 4; ++mi)
#pragma unroll
        for (int ni = 0; ni < 4; ++ni)
          acc[mi][ni] = __builtin_amdgcn_mfma_f32_16x16x32_bf16(
              af[mi], bfv[ni], acc[mi][ni], 0, 0, 0);
    }
  }

  float* Cf = (float*)Cp;
  bf16_t* Cb = (bf16_t*)Cp;
#pragma unroll
  for (int mi = 0; mi < 4; ++mi) {
    const size_t gr = row0 + wr * 64 + mi * 16 + quad * 4;
#pragma unroll
    for (int ni = 0; ni < 4; ++ni) {
      const size_t gc = col0 + wc * 64 + ni * 16 + l15;
      float bv = 0.f;
      if (EPI == 0 || EPI == 2 || EPI == 3) bv = biasp ? (float)biasp[gc] : 0.f;
#pragma unroll
      for (int r = 0; r < 4; ++r) {
        float v = acc[mi][ni][r];
        const size_t idx = zoffC + (gr + r) * ldc + gc;
        if (EPI == 0) {
          Cb[idx] = (bf16_t)((v + bv) * scl);
        } else if (EPI == 1) {
          Cb[idx] = (bf16_t)v;
        } else if (EPI == 2) {
          Cf[idx] = res[idx] + v + bv;
        } else {
          float t = v + bv;
          Cb[idx] = (bf16_t)(t * (1.f / (1.f + __expf(-1.702f * t))));
        }
      }
    }
  }
}

// ---------------- 256x256 8-phase GEMM engine (T3+T4+T5) --------------------
// 512 threads = 8 waves (2M x 4N); wave tile 128x64; BK=64 as two kslice
// slots per operand; 2x double-buffer => 8 slots, 128 KiB total.
// Slab per kslice slot = [256 rows][32 k] row-major with the same 16B-slot
// swizzle as gemm_bt. Staging: wave wid covers rowgroups 2wid, 2wid+1 per
// half; lane L reads row rg*16+(L>>2), k-octet (L&3)^((L>>3)&3); gll16
// dest linear rowgroups.
// Half-tile ring: half h = {tile u=h>>2, ks=(h>>1)&1, op=h&1}; prologue
// issues h=0..5; phase g stages h=g+6 (after the phase-start barrier).
// Phase g=4t+q computes quadrant q of tile t. ONE barrier per phase:
//   [PH0 only: s_waitcnt vmcnt(4|0)] -> s_barrier -> stage -> ds_read
//   -> setprio(1) 16xMFMA setprio(0)
// No sched_barrier / no inline lgkmcnt: ds_reads are IR-visible, the
// compiler emits fine-grained lgkmcnt and interleaves reads with MFMA.
// Hazard audit: stage@phase k writes a slot last READ at phase k-1;
// reader's ds_reads complete before its MFMAs issue, which precede its
// arrival at barrier@k, which gates the writer. Write->read publication
// is the PH0 vmcnt(4) (2 halves in flight) + barrier.
// EPI: 0 = bf16 (acc+bias)*scale; 1 = bf16 acc; 3 = QuickGELU bf16.
// MODE: 0 = plain z-batch; 1 = causal score (skip bx>by); 3 = fused QKV.
template <int EPI, int MODE>
__global__ __launch_bounds__(512, 2) void gemm256(
    const bf16_t* __restrict__ A, const bf16_t* __restrict__ Aalt,
    long lda, long sA,
    const bf16_t* __restrict__ W0, const bf16_t* __restrict__ W1,
    const bf16_t* __restrict__ W2, long ldw, long sW,
    void* __restrict__ C0, void* __restrict__ C1, void* __restrict__ C2,
    long ldc, long sC,
    const bf16_t* __restrict__ bias, float scale, int K) {
  // XCD-aware bijective chunked swizzle (all launch grids have nwg % 8 == 0).
  const int gx = gridDim.x, gy = gridDim.y;
  const int nwg = gx * gy * (int)gridDim.z;
  const int hw = (int)blockIdx.x + gx * ((int)blockIdx.y + gy * (int)blockIdx.z);
  const int logical = (hw & 7) * (nwg >> 3) + (hw >> 3);
  const int bx = logical % gx;
  const int by = (logical / gx) % gy;
  const int z  = logical / (gx * gy);
  const size_t row0 = (size_t)by * 256, col0 = (size_t)bx * 256;
  if (MODE == 1 && bx > by) return;  // fully-masked causal tile

  const bf16_t* Ap = (MODE == 3) ? (z == 0 ? A : Aalt) : A + (size_t)z * sA;
  const bf16_t* Wp = (MODE == 3) ? (z == 0 ? W0 : (z == 1 ? W1 : W2))
                                 : W0 + (size_t)z * sW;
  void* Cp = (MODE == 3) ? (z == 0 ? C0 : (z == 1 ? C1 : C2)) : C0;
  const size_t zoffC = (MODE == 3) ? 0 : (size_t)z * sC;
  const bf16_t* biasp = bias ? bias + (MODE == 3 ? z * 1024 : 0) : nullptr;
  const float scl = (MODE == 3 && z != 0) ? 1.f : scale;

  __shared__ __align__(16) bf16_t As[2][2][8192];  // [parity][kslice]
  __shared__ __align__(16) bf16_t Bs[2][2][8192];

  const int tid = threadIdx.x;
  const int lane = tid & 63, wid = tid >> 6;
  const int l15 = lane & 15, quad = lane >> 4;
  const int wm = wid >> 2, wn = wid & 3;

  // Staging: wave wid covers rowgroups 2*wid and 2*wid+1 of each half.
  const int soct = (lane & 3) ^ ((lane >> 3) & 3);
  const bf16_t* pA[2];
  const bf16_t* pB[2];
#pragma unroll
  for (int j = 0; j < 2; ++j) {
    const int rr = (wid * 2 + j) * 16 + (lane >> 2);
    const int kc = soct * 8;
    pA[j] = Ap + (row0 + rr) * lda + kc;
    pB[j] = Wp + (col0 + rr) * ldw + kc;
  }
  const int d0 = (wid * 2) * 512;      // wave-uniform LDS elem base, j=0
  const int d1 = (wid * 2 + 1) * 512;  // j=1

  const int T = K >> 6;    // number of BK=64 tiles
  const int HT = 4 * T;    // total half-tiles

  auto stage = [&](int h) {
    if (h >= HT) return;
    const int u = h >> 2, ks = (h >> 1) & 1;
    const int coff = u * 64 + ks * 32;
    if (h & 1) {
      gll16(pB[0] + coff, &Bs[u & 1][ks][0] + d0);
      gll16(pB[1] + coff, &Bs[u & 1][ks][0] + d1);
    } else {
      gll16(pA[0] + coff, &As[u & 1][ks][0] + d0);
      gll16(pA[1] + coff, &As[u & 1][ks][0] + d1);
    }
  };

  f32x4 acc[2][4][4];
#pragma unroll
  for (int mh = 0; mh < 2; ++mh)
#pragma unroll
    for (int mi = 0; mi < 4; ++mi)
#pragma unroll
      for (int ni = 0; ni < 4; ++ni) acc[mh][mi][ni] = (f32x4)0.f;

  // prologue: 6 halves in flight before the first compute phase
#pragma unroll
  for (int h = 0; h < 6; ++h) stage(h);

  // frag lane offset: row=base+l15 -> l15*32 + swizzled 16B slot
  const int fro = l15 * 32 + (quad ^ ((l15 >> 1) & 3)) * 8;

  for (int t = 0; t < T; ++t) {
    const int p = t & 1;
    const int g4 = 4 * t;
    bf16x8 bfv[4];

// PH: phase 0..3; KK: k-slice; MH: fragment-half. B fragments loaded when
// MH==0, reused (in regs, across phases) when MH==1. One barrier per
// phase; stage is issued AFTER the barrier (slot-overwrite hazard gate).
#define PHASE(PH, KK, MH)                                                     \
    {                                                                         \
      if (PH == 0) {                                                          \
        /* gate tile t's staging: 2 newest halves may stay in flight */       \
        if (t + 1 < T) asm volatile("s_waitcnt vmcnt(4)" ::: "memory");       \
        else           asm volatile("s_waitcnt vmcnt(0)" ::: "memory");       \
      }                                                                       \
      __builtin_amdgcn_s_barrier();                                          \
      stage(g4 + 6 + PH);                                                     \
      bf16x8 af[4];                                                           \
      _Pragma("unroll")                                                       \
      for (int mi = 0; mi < 4; ++mi)                                          \
        af[mi] = *(const bf16x8*)(&As[p][KK][0] +                             \
                                  (wm * 8 + MH * 4 + mi) * 512 + fro);        \
      if (MH == 0) {                                                          \
        _Pragma("unroll")                                                     \
        for (int ni = 0; ni < 4; ++ni)                                        \
          bfv[ni] = *(const bf16x8*)(&Bs[p][KK][0] +                          \
                                     (wn * 4 + ni) * 512 + fro);              \
      }                                                                       \
      __builtin_amdgcn_s_setprio(1);                                         \
      _Pragma("unroll")                                                       \
      for (int mi = 0; mi < 4; ++mi)                                          \
        _Pragma("unroll")                                                     \
        for (int ni = 0; ni < 4; ++ni)                                        \
          acc[MH][mi][ni] = __builtin_amdgcn_mfma_f32_16x16x32_bf16(          \
              af[mi], bfv[ni], acc[MH][mi][ni], 0, 0, 0);                     \
      __builtin_amdgcn_s_setprio(0);                                          \
    }

    PHASE(0, 0, 0)
    PHASE(1, 0, 1)
    PHASE(2, 1, 0)
    PHASE(3, 1, 1)
#undef PHASE
  }

  // epilogue: C/D layout col=lane&15, row=quad*4+r
  bf16_t* Cb = (bf16_t*)Cp;
#pragma unroll
  for (int mh = 0; mh < 2; ++mh)
#pragma unroll
    for (int mi = 0; mi < 4; ++mi) {
      const size_t gr = row0 + wm * 128 + mh * 64 + mi * 16 + quad * 4;
#pragma unroll
      for (int ni = 0; ni < 4; ++ni) {
        const size_t gc = col0 + wn * 64 + ni * 16 + l15;
        float bv = 0.f;
        if (EPI == 0 || EPI == 3) bv = biasp ? (float)biasp[gc] : 0.f;
#pragma unroll
        for (int r = 0; r < 4; ++r) {
          const float v = acc[mh][mi][ni][r];
          const size_t idx = zoffC + (gr + r) * ldc + gc;
          if (EPI == 0) {
            Cb[idx] = (bf16_t)((v + bv) * scl);
          } else if (EPI == 1) {
            Cb[idx] = (bf16_t)v;
          } else {
            const float tt = v + bv;
            Cb[idx] = (bf16_t)(tt * (1.f / (1.f + __expf(-1.702f * tt))));
          }
        }
      }
    }
}

// ---------------- host-side launch helpers ----------------------------------
template <int EPI, int MODE, int NS = 1>
static void launch_gemm(hipStream_t stream, int M, int N, int Z,
                        const void* A, const void* Aalt, long lda, long sA,
                        const void* W0, const void* W1, const void* W2,
                        long ldw, long sW,
                        void* C0, void* C1, void* C2, long ldc, long sC,
                        const void* bias, const float* res, float scale, int K) {
  dim3 grid(N / 128, M / 128, Z);
  gemm_bt<EPI, MODE, NS><<<grid, dim3(256), 0, stream>>>(
      (const bf16_t*)A, (const bf16_t*)Aalt, lda, sA,
      (const bf16_t*)W0, (const bf16_t*)W1, (const bf16_t*)W2, ldw, sW,
      C0, C1, C2, ldc, sC, (const bf16_t*)bias, res, scale, K);
}

template <int EPI, int MODE>
static void launch_gemm256(hipStream_t stream, int M, int N, int Z,
                           const void* A, const void* Aalt, long lda, long sA,
                           const void* W0, const void* W1, const void* W2,
                           long ldw, long sW,
                           void* C0, void* C1, void* C2, long ldc, long sC,
                           const void* bias, float scale, int K) {
  dim3 grid(N / 256, M / 256, Z);  // nwg % 8 == 0 for all call sites
  gemm256<EPI, MODE><<<grid, dim3(512), 0, stream>>>(
      (const bf16_t*)A, (const bf16_t*)Aalt, lda, sA,
      (const bf16_t*)W0, (const bf16_t*)W1, (const bf16_t*)W2, ldw, sW,
      C0, C1, C2, ldc, sC, (const bf16_t*)bias, scale, K);
}

extern "C" void kernel_launch(void* const* d_in, const int* in_sizes, int n_in,
                              void* d_out, int out_size, void* d_ws, size_t ws_size,
                              hipStream_t stream) {
  (void)in_sizes; (void)n_in; (void)out_size; (void)ws_size;
  const float* tgt  = (const float*)d_in[0];
  const float* mem  = (const float*)d_in[1];
  // d_in[2] (mask) unused: causality applied structurally.
  const float* sa_qw = (const float*)d_in[3];
  const float* sa_kw = (const float*)d_in[4];
  const float* sa_vw = (const float*)d_in[5];
  const float* sa_b  = (const float*)d_in[6];
  const float* sa_ow = (const float*)d_in[7];
  const float* sa_ob = (const float*)d_in[8];
  const float* ca_qw = (const float*)d_in[9];
  const float* ca_kw = (const float*)d_in[10];
  const float* ca_vw = (const float*)d_in[11];
  const float* ca_b  = (const float*)d_in[12];
  const float* ca_ow = (const float*)d_in[13];
  const float* ca_ob = (const float*)d_in[14];
  const float* ln1g = (const float*)d_in[15];
  const float* ln1b = (const float*)d_in[16];
  const float* ln2g = (const float*)d_in[17];
  const float* ln2b = (const float*)d_in[18];
  const float* ln3g = (const float*)d_in[19];
  const float* ln3b = (const float*)d_in[20];
  const float* w1 = (const float*)d_in[21];
  const float* b1 = (const float*)d_in[22];
  const float* w2 = (const float*)d_in[23];
  const float* b2 = (const float*)d_in[24];

  char* ws = (char*)d_ws;
  const size_t MB = 1048576;
  float*  xf   = (float*)(ws);             // [0,32)   fp32 residual
  bf16_t* hb   = (bf16_t*)(ws + 32 * MB);  // [32,48)  LN out
  bf16_t* vb   = (bf16_t*)(ws + 48 * MB);  // [48,64)  V
  bf16_t* qb   = (bf16_t*)(ws + 64 * MB);  // [64,80)  Q
  bf16_t* kb   = (bf16_t*)(ws + 80 * MB);  // [80,96)  K
  bf16_t* vt   = (bf16_t*)(ws + 96 * MB);  // [96,112) V^T [n][e][s]
  bf16_t* sb   = (bf16_t*)(ws + 32 * MB);  // [32,64)  scores/probs
  bf16_t* ao   = kb;                       // [80,96)  attn out (kb dead)
  bf16_t* hid  = (bf16_t*)(ws + 48 * MB);  // [48,112) MLP hidden
  bf16_t* memb = (bf16_t*)(ws + 112 * MB); // [112,128) bf16 memory
  bf16_t* wt   = (bf16_t*)(ws + 128 * MB); // [128,160) bf16 weights
  bf16_t* bb   = (bf16_t*)(ws + 160 * MB); // biases

  const size_t M1 = 1048576;  // elems per E*E weight
  bf16_t* saq = wt,          *sak = wt + M1,     *sav = wt + 2 * M1;
  bf16_t* sao = wt + 3 * M1, *caq = wt + 4 * M1, *cak = wt + 5 * M1;
  bf16_t* cav = wt + 6 * M1, *cao = wt + 7 * M1;
  bf16_t* w1b = wt + 8 * M1;   // 4M elems
  bf16_t* w2b = wt + 12 * M1;  // 4M elems

  const float qscale = 0.03125f;  // 1024^-0.5

  // ---- fused weight/bias conversions (one launch) ----
  CastDesc cd;
  auto seg = [&](int i, const float* s, bf16_t* d, int elems) {
    cd.s[i] = CastSeg{s, d, elems / 1024};
  };
  seg(0, sa_qw, saq, 1 << 20);  seg(1, sa_kw, sak, 1 << 20);
  seg(2, sa_vw, sav, 1 << 20);  seg(3, sa_ow, sao, 1 << 20);
  seg(4, ca_qw, caq, 1 << 20);  seg(5, ca_kw, cak, 1 << 20);
  seg(6, ca_vw, cav, 1 << 20);  seg(7, ca_ow, cao, 1 << 20);
  seg(8, w1, w1b, 1 << 22);     seg(9, w2, w2b, 1 << 22);
  seg(10, sa_b, bb, 3072);      seg(11, sa_ob, bb + 3072, 1024);
  seg(12, ca_b, bb + 4096, 3072); seg(13, ca_ob, bb + 7168, 1024);
  seg(14, b1, bb + 8192, 4096); seg(15, b2, bb + 12288, 1024);
  int total_chunks = 0;
  for (int i = 0; i < 16; ++i) total_chunks += cd.s[i].chunks;
  cast_multi<<<total_chunks, 256, 0, stream>>>(cd);
  f32_to_bf16_n<<<4096, 256, 0, stream>>>(mem, memb, 1 << 23);

  // ================= self-attention (causal) =================
  ln_kernel<<<8192, 256, 0, stream>>>(tgt, ln1g, ln1b, hb);
  launch_gemm256<0, 3>(stream, 8192, 1024, 3, hb, hb, 1024, 0,
                       saq, sak, sav, 1024, 0, qb, kb, vb, 1024, 0,
                       bb, qscale, 1024);
  transpose_v<<<dim3(32, 16, 4), 256, 0, stream>>>(vb, vt);
  launch_gemm256<1, 1>(stream, 2048, 2048, 4, qb, nullptr, 4096, 1024,
                       kb, nullptr, nullptr, 4096, 1024,
                       sb, nullptr, nullptr, 2048, 4194304, nullptr,
                       1.f, 1024);
  softmax_kernel<1><<<8192, 256, 0, stream>>>(sb);
  launch_gemm<0, 2, 2>(stream, 2048, 1024, 4, sb, nullptr, 2048, 4194304,
                       vt, nullptr, nullptr, 2048, 2097152,
                       ao, nullptr, nullptr, 4096, 1024, nullptr, nullptr,
                       1.f, 2048);
  launch_gemm<2, 0, 2>(stream, 8192, 1024, 1, ao, nullptr, 1024, 0,
                       sao, nullptr, nullptr, 1024, 0,
                       xf, nullptr, nullptr, 1024, 0, bb + 3072, tgt,
                       1.f, 1024);

  // ================= cross-attention (no mask) =================
  ln_kernel<<<8192, 256, 0, stream>>>(xf, ln2g, ln2b, hb);
  launch_gemm256<0, 3>(stream, 8192, 1024, 3, hb, memb, 1024, 0,
                       caq, cak, cav, 1024, 0, qb, kb, vb, 1024, 0,
                       bb + 4096, qscale, 1024);
  transpose_v<<<dim3(32, 16, 4), 256, 0, stream>>>(vb, vt);
  launch_gemm256<1, 0>(stream, 2048, 2048, 4, qb, nullptr, 4096, 1024,
                       kb, nullptr, nullptr, 4096, 1024,
                       sb, nullptr, nullptr, 2048, 4194304, nullptr,
                       1.f, 1024);
  softmax_kernel<0><<<8192, 256, 0, stream>>>(sb);
  launch_gemm<0, 0, 2>(stream, 2048, 1024, 4, sb, nullptr, 2048, 4194304,
                       vt, nullptr, nullptr, 2048, 2097152,
                       ao, nullptr, nullptr, 4096, 1024, nullptr, nullptr,
                       1.f, 2048);
  launch_gemm<2, 0, 2>(stream, 8192, 1024, 1, ao, nullptr, 1024, 0,
                       cao, nullptr, nullptr, 1024, 0,
                       xf, nullptr, nullptr, 1024, 0, bb + 7168, xf,
                       1.f, 1024);

  // ================= MLP (QuickGELU) =================
  ln_kernel<<<8192, 256, 0, stream>>>(xf, ln3g, ln3b, hb);
  launch_gemm256<3, 0>(stream, 8192, 4096, 1, hb, nullptr, 1024, 0,
                       w1b, nullptr, nullptr, 1024, 0,
                       hid, nullptr, nullptr, 4096, 0, bb + 8192,
                       1.f, 1024);
  launch_gemm<2, 0, 2>(stream, 8192, 1024, 1, hid, nullptr, 4096, 0,
                       w2b, nullptr, nullptr, 4096, 0,
                       d_out, nullptr, nullptr, 1024, 0, bb + 12288, xf,
                       1.f, 4096);
}

// Round 5
// 810.483 us; speedup vs baseline: 1.2117x; 1.0140x over previous
//
#include <hip/hip_runtime.h>
#include <hip/hip_bf16.h>
#include <cstdint>
#include <cstddef>

// SingleheadTransformerDecoderLayer: L=S=2048, N=4, E=1024, FF=4096, fp32 I/O.
// Round 12: free-running half-tiles in gemm256. Closed-form accounting from
// round 11 counters: 16x16x32 MFMA = ~16 cyc/SIMD (1017 FLOP/cyc/SIMD at
// 2.5PF dense), so a phase carries 515 cyc of MFMA; measured 1970 cyc/phase
// at MfmaUtil 26.4% (26.4% x 1970 = 520 -- exact). The barrier-per-phase
// lockstep serialized the block's 48-64KB/phase LDS read storm (~430-580
// cyc @ ~112 B/cyc/CU) against the MFMA window. New K-loop: TWO barriers
// per tile (start: vmcnt(4) publish gate; mid: w-a-r gate for ks0 slot
// overwrite); within each half-tile every wave free-runs
// {stage, 12x ds_read_b128, 32 MFMA} so cross-wave skew overlaps the LDS
// port with the MFMA pipe. Ring depth 6 halves unchanged; hazards audited
// (ks1 overwrite gated by start barrier, ks0 by mid barrier; KK1 reads may
// legally hoist above mid barrier since published at tile start).
// gemm_bt engine untouched this round.
//
// Workspace layout (161MB):
//   [0,32)    xf   : fp32 residual [8192,1024]
//   [32,48)   hb   : bf16 LN out
//   [48,64)   vb   : bf16 V          } sb bf16 scores [n][l][s] = [32,64)
//   [64,80)   qb   : bf16 Q          }   (hb,vb dead by score-GEMM time)
//   [80,96)   kb   : bf16 K  (reused as attn-out ao after score GEMM)
//   [96,112)  vt   : bf16 V^T [n][e][s]
//   [48,112)  hid  : bf16 MLP hidden [8192,4096] (vb,qb,kb,vt dead)
//   [112,128) memb : bf16 copy of `memory`
//   [128,160) wts  : bf16 weights; [160,161) bb : bf16 biases

using bf16_t = __bf16;
typedef __bf16 bf16x8 __attribute__((ext_vector_type(8)));
typedef __bf16 bf16x4 __attribute__((ext_vector_type(4)));
typedef float f32x4 __attribute__((ext_vector_type(4)));

// ---------------- async global->LDS, 16B/lane, wave-uniform LDS base --------
__device__ __forceinline__ void gll16(const void* g, void* lds) {
  __builtin_amdgcn_global_load_lds(
      (__attribute__((address_space(1))) void*)(g),
      (__attribute__((address_space(3))) void*)(lds), 16, 0, 0);
}

// ---------------- fp32 -> bf16 cast (8 elems/thread) ------------------------
__global__ __launch_bounds__(256) void f32_to_bf16_n(
    const float* __restrict__ in, bf16_t* __restrict__ out, int n) {
  const size_t i = ((size_t)blockIdx.x * 256 + threadIdx.x) * 8;
  if (i >= (size_t)n) return;
  f32x4 a = *(const f32x4*)(in + i);
  f32x4 b = *(const f32x4*)(in + i + 4);
  bf16x8 v;
#pragma unroll
  for (int j = 0; j < 4; ++j) { v[j] = (bf16_t)a[j]; v[4 + j] = (bf16_t)b[j]; }
  *(bf16x8*)(out + i) = v;
}

// ---------------- fused multi-segment fp32 -> bf16 cast ---------------------
struct CastSeg { const float* src; bf16_t* dst; int chunks; };
struct CastDesc { CastSeg s[16]; };
__global__ __launch_bounds__(256) void cast_multi(CastDesc d) {
  int blk = blockIdx.x, seg = 0, base = 0;
  while (blk - base >= d.s[seg].chunks) { base += d.s[seg].chunks; ++seg; }
  const size_t i = (size_t)(blk - base) * 1024 + threadIdx.x * 4;
  f32x4 a = *(const f32x4*)(d.s[seg].src + i);
  bf16x4 v;
#pragma unroll
  for (int j = 0; j < 4; ++j) v[j] = (bf16_t)a[j];
  *(bf16x4*)(d.s[seg].dst + i) = v;
}

// ---------------- LayerNorm over E=1024, one block per row ------------------
__global__ __launch_bounds__(256) void ln_kernel(
    const float* __restrict__ x, const float* __restrict__ g,
    const float* __restrict__ b, bf16_t* __restrict__ out) {
  const int row = blockIdx.x, tid = threadIdx.x;
  const float* xr = x + (size_t)row * 1024;
  float v0 = xr[tid], v1 = xr[tid + 256], v2 = xr[tid + 512], v3 = xr[tid + 768];
  float s = v0 + v1 + v2 + v3;
  float ss = v0 * v0 + v1 * v1 + v2 * v2 + v3 * v3;
#pragma unroll
  for (int off = 32; off > 0; off >>= 1) {
    s += __shfl_down(s, off, 64);
    ss += __shfl_down(ss, off, 64);
  }
  __shared__ float red[8];
  const int w = tid >> 6, lane = tid & 63;
  if (lane == 0) { red[w] = s; red[4 + w] = ss; }
  __syncthreads();
  s = red[0] + red[1] + red[2] + red[3];
  ss = red[4] + red[5] + red[6] + red[7];
  const float mean = s * (1.f / 1024.f);
  float var = ss * (1.f / 1024.f) - mean * mean;
  var = var < 0.f ? 0.f : var;
  const float inv = rsqrtf(var + 1e-5f);
  bf16_t* orow = out + (size_t)row * 1024;
  orow[tid]       = (bf16_t)((v0 - mean) * inv * g[tid]       + b[tid]);
  orow[tid + 256] = (bf16_t)((v1 - mean) * inv * g[tid + 256] + b[tid + 256]);
  orow[tid + 512] = (bf16_t)((v2 - mean) * inv * g[tid + 512] + b[tid + 512]);
  orow[tid + 768] = (bf16_t)((v3 - mean) * inv * g[tid + 768] + b[tid + 768]);
}

// ---------------- softmax over S=2048, bf16 in-place, optional causal -------
template <int CAUSAL>
__global__ __launch_bounds__(256) void softmax_kernel(bf16_t* __restrict__ sc) {
  const int row = blockIdx.x, tid = threadIdx.x;
  const int l = row & 2047;
  bf16_t* sr = sc + (size_t)row * 2048;
  float v[8];
  float mx = -3.4e38f;
#pragma unroll
  for (int i = 0; i < 8; ++i) {
    const int j = tid + i * 256;
    v[i] = (CAUSAL && j > l) ? -3.4e38f : (float)sr[j];
    mx = fmaxf(mx, v[i]);
  }
#pragma unroll
  for (int off = 32; off > 0; off >>= 1) mx = fmaxf(mx, __shfl_down(mx, off, 64));
  __shared__ float red[8];
  const int w = tid >> 6, lane = tid & 63;
  if (lane == 0) red[w] = mx;
  __syncthreads();
  mx = fmaxf(fmaxf(red[0], red[1]), fmaxf(red[2], red[3]));
  float sum = 0.f;
#pragma unroll
  for (int i = 0; i < 8; ++i) { v[i] = __expf(v[i] - mx); sum += v[i]; }
#pragma unroll
  for (int off = 32; off > 0; off >>= 1) sum += __shfl_down(sum, off, 64);
  if (lane == 0) red[4 + w] = sum;
  __syncthreads();
  sum = red[4] + red[5] + red[6] + red[7];
  const float r = 1.f / sum;
#pragma unroll
  for (int i = 0; i < 8; ++i) sr[tid + i * 256] = (bf16_t)(v[i] * r);
}

// ---------------- V transpose: [s*4+n, e] -> vt[n][e][s] --------------------
__global__ __launch_bounds__(256) void transpose_v(const bf16_t* __restrict__ v,
                                                   bf16_t* __restrict__ vt) {
  __shared__ bf16_t tile[64][72];
  const int n = blockIdx.z;
  const int s0 = blockIdx.x * 64, e0 = blockIdx.y * 64;
  const int tid = threadIdx.x;
#pragma unroll
  for (int j = 0; j < 2; ++j) {
    int flat = j * 256 + tid;
    int r = flat >> 3, c8 = (flat & 7) * 8;
    bf16x8 val = *(const bf16x8*)(v + ((size_t)(s0 + r) * 4 + n) * 1024 + e0 + c8);
#pragma unroll
    for (int i = 0; i < 8; ++i) tile[r][c8 + i] = val[i];
  }
  __syncthreads();
#pragma unroll
  for (int j = 0; j < 2; ++j) {
    int flat = j * 256 + tid;
    int er = flat >> 3, s8 = (flat & 7) * 8;
    bf16x8 val;
#pragma unroll
    for (int i = 0; i < 8; ++i) val[i] = tile[s8 + i][er];
    *(bf16x8*)(vt + ((size_t)n * 1024 + e0 + er) * 2048 + s0 + s8) = val;
  }
}

// ---------------- generic C = A @ W^T GEMM, double-buffered LDS -------------
// (128x128 engine -- for the 128-block grids: PV, out-proj, MLP2)
// Slab per kslice = [128 rows][32 k] row-major (64B row stride), 16B slots
// swizzled: elem(r,k) at byte r*64 + ((k>>3)^((r>>1)&3))*16 + (k&7)*2.
// Staging: gll16 writes linear 1024B rowgroups; global source lane L reads
// row rg*16+(L>>2), k-octet (L&3)^((L>>3)&3) (permutation within one 64B
// run -> coalesced). Frag read: row*32 + (quad^((l15>>1)&3))*8 elems.
// EPI: 0 = bf16 store (acc+bias)*scale; 1 = bf16 store acc;
//      2 = fp32 store res[idx]+acc+bias; 3 = QuickGELU -> bf16.
// MODE: 0 = plain (z = batch); 1 = causal score (skip col0 > row0);
//       2 = causal PV (K capped at row0+128); 3 = fused QKV.
template <int EPI, int MODE, int NS>
__global__ __launch_bounds__(256) void gemm_bt(
    const bf16_t* __restrict__ A, const bf16_t* __restrict__ Aalt,
    long lda, long sA,
    const bf16_t* __restrict__ W0, const bf16_t* __restrict__ W1,
    const bf16_t* __restrict__ W2, long ldw, long sW,
    void* __restrict__ C0, void* __restrict__ C1, void* __restrict__ C2,
    long ldc, long sC,
    const bf16_t* __restrict__ bias, const float* __restrict__ res,
    float scale, int K) {
  const size_t row0 = (size_t)blockIdx.y * 128;
  const size_t col0 = (size_t)blockIdx.x * 128;
  if (MODE == 1 && col0 > row0) return;  // fully-masked causal tile
  const int z = blockIdx.z;
  constexpr int BK = NS * 32;

  const bf16_t* Ap = (MODE == 3) ? (z == 0 ? A : Aalt) : A + (size_t)z * sA;
  const bf16_t* Wp = (MODE == 3) ? (z == 0 ? W0 : (z == 1 ? W1 : W2))
                                 : W0 + (size_t)z * sW;
  void* Cp = (MODE == 3) ? (z == 0 ? C0 : (z == 1 ? C1 : C2)) : C0;
  const size_t zoffC = (MODE == 3) ? 0 : (size_t)z * sC;
  const bf16_t* biasp = bias ? bias + (MODE == 3 ? z * 1024 : 0) : nullptr;
  const float scl = (MODE == 3 && z != 0) ? 1.f : scale;
  const int kend = (MODE == 2) ? min(K, (int)row0 + 128) : K;

  __shared__ __align__(16) bf16_t As[2][NS][128 * 32];
  __shared__ __align__(16) bf16_t Bs[2][NS][128 * 32];
  const int tid = threadIdx.x;
  const int wv = tid >> 6, lane = tid & 63;
  const int quad = lane >> 4, l15 = lane & 15;
  const int wr = wv >> 1, wc = wv & 1;

  // staging: chunk c = wv*2NS+j -> kslice ksc=c>>3, rowgroup rg=c&7.
  // lane L: row rg*16+(L>>2), k-octet (L&3)^((L>>3)&3) (64B-local perm).
  const bf16_t* gA[2 * NS];
  const bf16_t* gW[2 * NS];
  int dof[2 * NS];  // wave-uniform LDS elem offset within parity buffer
  const int soct = (lane & 3) ^ ((lane >> 3) & 3);
#pragma unroll
  for (int j = 0; j < 2 * NS; ++j) {
    const int c = wv * 2 * NS + j;
    const int ksc = c >> 3;
    const int rg = c & 7;
    const int rr = rg * 16 + (lane >> 2);
    const int cc = ksc * 32 + soct * 8;
    gA[j] = Ap + (row0 + rr) * lda + cc;
    gW[j] = Wp + (col0 + rr) * ldw + cc;
    dof[j] = ksc * 4096 + rg * 512;
  }

  f32x4 acc[4][4];
#pragma unroll
  for (int mi = 0; mi < 4; ++mi)
#pragma unroll
    for (int ni = 0; ni < 4; ++ni) acc[mi][ni] = (f32x4)0.f;

#pragma unroll
  for (int j = 0; j < 2 * NS; ++j) {
    gll16(gA[j], &As[0][0][0] + dof[j]);
    gll16(gW[j], &Bs[0][0][0] + dof[j]);
  }

  // frag lane offset: row=base+l15 -> l15*32 + swizzled 16B slot
  const int fro = l15 * 32 + (quad ^ ((l15 >> 1) & 3)) * 8;

  int p = 0;
  for (int k0 = 0; k0 < kend; k0 += BK, p ^= 1) {
    __syncthreads();
    const int kn = k0 + BK;
    if (kn < kend) {
#pragma unroll
      for (int j = 0; j < 2 * NS; ++j) {
        gll16(gA[j] + kn, &As[p ^ 1][0][0] + dof[j]);
        gll16(gW[j] + kn, &Bs[p ^ 1][0][0] + dof[j]);
      }
    }
#pragma unroll
    for (int ks = 0; ks < NS; ++ks) {
      bf16x8 af[4], bfv[4];
#pragma unroll
      for (int mi = 0; mi < 4; ++mi)
        af[mi] = *(const bf16x8*)(As[p][ks] + (wr * 4 + mi) * 512 + fro);
#pragma unroll
      for (int ni = 0; ni < 4; ++ni)
        bfv[ni] = *(const bf16x8*)(Bs[p][ks] + (wc * 4 + ni) * 512 + fro);
#pragma unroll
      for (int mi = 0; mi < 4; ++mi)
#pragma unroll
        for (int ni = 0; ni < 4; ++ni)
          acc[mi][ni] = __builtin_amdgcn_mfma_f32_16x16x32_bf16(
              af[mi], bfv[ni], acc[mi][ni], 0, 0, 0);
    }
  }

  float* Cf = (float*)Cp;
  bf16_t* Cb = (bf16_t*)Cp;
#pragma unroll
  for (int mi = 0; mi < 4; ++mi) {
    const size_t gr = row0 + wr * 64 + mi * 16 + quad * 4;
#pragma unroll
    for (int ni = 0; ni < 4; ++ni) {
      const size_t gc = col0 + wc * 64 + ni * 16 + l15;
      float bv = 0.f;
      if (EPI == 0 || EPI == 2 || EPI == 3) bv = biasp ? (float)biasp[gc] : 0.f;
#pragma unroll
      for (int r = 0; r < 4; ++r) {
        float v = acc[mi][ni][r];
        const size_t idx = zoffC + (gr + r) * ldc + gc;
        if (EPI == 0) {
          Cb[idx] = (bf16_t)((v + bv) * scl);
        } else if (EPI == 1) {
          Cb[idx] = (bf16_t)v;
        } else if (EPI == 2) {
          Cf[idx] = res[idx] + v + bv;
        } else {
          float t = v + bv;
          Cb[idx] = (bf16_t)(t * (1.f / (1.f + __expf(-1.702f * t))));
        }
      }
    }
  }
}

// ---------------- 256x256 8-phase GEMM engine (T3+T4+T5) --------------------
// 512 threads = 8 waves (2M x 4N); wave tile 128x64; BK=64 as two kslice
// slots per operand; 2x double-buffer => 8 slots, 128 KiB total.
// Slab per kslice slot = [256 rows][32 k] row-major with the same 16B-slot
// swizzle as gemm_bt. Staging: wave wid covers rowgroups 2wid, 2wid+1 per
// half; lane L reads row rg*16+(L>>2), k-octet (L&3)^((L>>3)&3); gll16
// dest linear rowgroups.
// Half-tile ring: half h = {tile u=h>>2, ks=(h>>1)&1, op=h&1}; prologue
// issues h=0..5. K-loop: TWO barriers per tile.
//   tile start: [vmcnt(4) | vmcnt(0) last] -> s_barrier
//     (publishes tile t; gates overwrite of tile t+1 parity slots whose
//      last reader was tile t-1)
//   half 0 (KK=0): stage(4t+6); read bfv+af0; stage(4t+7); read af1;
//                  setprio(1) 32 MFMA setprio(0)
//   mid barrier: all waves done with KK=0 reads -> ks0 slots reusable
//   half 1 (KK=1): stage(4t+8); ... stage(4t+9); ... 32 MFMA
// Within each half waves free-run: cross-wave skew overlaps the LDS read
// storm with the MFMA pipe (the round-11 lockstep serialized them).
// EPI: 0 = bf16 (acc+bias)*scale; 1 = bf16 acc; 3 = QuickGELU bf16.
// MODE: 0 = plain z-batch; 1 = causal score (skip bx>by); 3 = fused QKV.
template <int EPI, int MODE>
__global__ __launch_bounds__(512, 2) void gemm256(
    const bf16_t* __restrict__ A, const bf16_t* __restrict__ Aalt,
    long lda, long sA,
    const bf16_t* __restrict__ W0, const bf16_t* __restrict__ W1,
    const bf16_t* __restrict__ W2, long ldw, long sW,
    void* __restrict__ C0, void* __restrict__ C1, void* __restrict__ C2,
    long ldc, long sC,
    const bf16_t* __restrict__ bias, float scale, int K) {
  // XCD-aware bijective chunked swizzle (all launch grids have nwg % 8 == 0).
  const int gx = gridDim.x, gy = gridDim.y;
  const int nwg = gx * gy * (int)gridDim.z;
  const int hw = (int)blockIdx.x + gx * ((int)blockIdx.y + gy * (int)blockIdx.z);
  const int logical = (hw & 7) * (nwg >> 3) + (hw >> 3);
  const int bx = logical % gx;
  const int by = (logical / gx) % gy;
  const int z  = logical / (gx * gy);
  const size_t row0 = (size_t)by * 256, col0 = (size_t)bx * 256;
  if (MODE == 1 && bx > by) return;  // fully-masked causal tile

  const bf16_t* Ap = (MODE == 3) ? (z == 0 ? A : Aalt) : A + (size_t)z * sA;
  const bf16_t* Wp = (MODE == 3) ? (z == 0 ? W0 : (z == 1 ? W1 : W2))
                                 : W0 + (size_t)z * sW;
  void* Cp = (MODE == 3) ? (z == 0 ? C0 : (z == 1 ? C1 : C2)) : C0;
  const size_t zoffC = (MODE == 3) ? 0 : (size_t)z * sC;
  const bf16_t* biasp = bias ? bias + (MODE == 3 ? z * 1024 : 0) : nullptr;
  const float scl = (MODE == 3 && z != 0) ? 1.f : scale;

  __shared__ __align__(16) bf16_t As[2][2][8192];  // [parity][kslice]
  __shared__ __align__(16) bf16_t Bs[2][2][8192];

  const int tid = threadIdx.x;
  const int lane = tid & 63, wid = tid >> 6;
  const int l15 = lane & 15, quad = lane >> 4;
  const int wm = wid >> 2, wn = wid & 3;

  // Staging: wave wid covers rowgroups 2*wid and 2*wid+1 of each half.
  const int soct = (lane & 3) ^ ((lane >> 3) & 3);
  const bf16_t* pA[2];
  const bf16_t* pB[2];
#pragma unroll
  for (int j = 0; j < 2; ++j) {
    const int rr = (wid * 2 + j) * 16 + (lane >> 2);
    const int kc = soct * 8;
    pA[j] = Ap + (row0 + rr) * lda + kc;
    pB[j] = Wp + (col0 + rr) * ldw + kc;
  }
  const int d0 = (wid * 2) * 512;      // wave-uniform LDS elem base, j=0
  const int d1 = (wid * 2 + 1) * 512;  // j=1

  const int T = K >> 6;    // number of BK=64 tiles
  const int HT = 4 * T;    // total half-tiles

  auto stage = [&](int h) {
    if (h >= HT) return;
    const int u = h >> 2, ks = (h >> 1) & 1;
    const int coff = u * 64 + ks * 32;
    if (h & 1) {
      gll16(pB[0] + coff, &Bs[u & 1][ks][0] + d0);
      gll16(pB[1] + coff, &Bs[u & 1][ks][0] + d1);
    } else {
      gll16(pA[0] + coff, &As[u & 1][ks][0] + d0);
      gll16(pA[1] + coff, &As[u & 1][ks][0] + d1);
    }
  };

  f32x4 acc[2][4][4];
#pragma unroll
  for (int mh = 0; mh < 2; ++mh)
#pragma unroll
    for (int mi = 0; mi < 4; ++mi)
#pragma unroll
      for (int ni = 0; ni < 4; ++ni) acc[mh][mi][ni] = (f32x4)0.f;

  // prologue: 6 halves in flight before the first tile
#pragma unroll
  for (int h = 0; h < 6; ++h) stage(h);

  // frag lane offset: row=base+l15 -> l15*32 + swizzled 16B slot
  const int fro = l15 * 32 + (quad ^ ((l15 >> 1) & 3)) * 8;

  for (int t = 0; t < T; ++t) {
    const int p = t & 1;
    const int g4 = 4 * t;

    // ---- tile-start gate: tile t halves landed (<=4 vmem of t+1 ks0 in
    // flight); barrier also retires tile t-1 reads so t+1-parity slots
    // (h = g4+6, g4+7) may be overwritten below.
    if (t + 1 < T) asm volatile("s_waitcnt vmcnt(4)" ::: "memory");
    else           asm volatile("s_waitcnt vmcnt(0)" ::: "memory");
    __builtin_amdgcn_s_barrier();

    // ---- half 0: KK=0 (MH 0,1); stages tile t+1 ks1 halves ----
    {
      stage(g4 + 6);
      bf16x8 bfv[4], af0[4], af1[4];
#pragma unroll
      for (int ni = 0; ni < 4; ++ni)
        bfv[ni] = *(const bf16x8*)(&Bs[p][0][0] + (wn * 4 + ni) * 512 + fro);
#pragma unroll
      for (int mi = 0; mi < 4; ++mi)
        af0[mi] = *(const bf16x8*)(&As[p][0][0] + (wm * 8 + mi) * 512 + fro);
      stage(g4 + 7);
#pragma unroll
      for (int mi = 0; mi < 4; ++mi)
        af1[mi] = *(const bf16x8*)(&As[p][0][0] + (wm * 8 + 4 + mi) * 512 + fro);
      __builtin_amdgcn_s_setprio(1);
#pragma unroll
      for (int mi = 0; mi < 4; ++mi)
#pragma unroll
        for (int ni = 0; ni < 4; ++ni)
          acc[0][mi][ni] = __builtin_amdgcn_mfma_f32_16x16x32_bf16(
              af0[mi], bfv[ni], acc[0][mi][ni], 0, 0, 0);
#pragma unroll
      for (int mi = 0; mi < 4; ++mi)
#pragma unroll
        for (int ni = 0; ni < 4; ++ni)
          acc[1][mi][ni] = __builtin_amdgcn_mfma_f32_16x16x32_bf16(
              af1[mi], bfv[ni], acc[1][mi][ni], 0, 0, 0);
      __builtin_amdgcn_s_setprio(0);
    }

    // ---- mid gate: all waves done with KK=0 reads -> tile-t ks0 slots
    // (h = g4+8, g4+9) may be overwritten.
    __builtin_amdgcn_s_barrier();

    // ---- half 1: KK=1; stages tile t+2 ks0 halves ----
    {
      stage(g4 + 8);
      bf16x8 bfv[4], af0[4], af1[4];
#pragma unroll
      for (int ni = 0; ni < 4; ++ni)
        bfv[ni] = *(const bf16x8*)(&Bs[p][1][0] + (wn * 4 + ni) * 512 + fro);
#pragma unroll
      for (int mi = 0; mi < 4; ++mi)
        af0[mi] = *(const bf16x8*)(&As[p][1][0] + (wm * 8 + mi) * 512 + fro);
      stage(g4 + 9);
#pragma unroll
      for (int mi = 0; mi < 4; ++mi)
        af1[mi] = *(const bf16x8*)(&As[p][1][0] + (wm * 8 + 4 + mi) * 512 + fro);
      __builtin_amdgcn_s_setprio(1);
#pragma unroll
      for (int mi = 0; mi < 4; ++mi)
#pragma unroll
        for (int ni = 0; ni < 4; ++ni)
          acc[0][mi][ni] = __builtin_amdgcn_mfma_f32_16x16x32_bf16(
              af0[mi], bfv[ni], acc[0][mi][ni], 0, 0, 0);
#pragma unroll
      for (int mi = 0; mi < 4; ++mi)
#pragma unroll
        for (int ni = 0; ni < 4; ++ni)
          acc[1][mi][ni] = __builtin_amdgcn_mfma_f32_16x16x32_bf16(
              af1[mi], bfv[ni], acc[1][mi][ni], 0, 0, 0);
      __builtin_amdgcn_s_setprio(0);
    }
  }

  // epilogue: C/D layout col=lane&15, row=quad*4+r
  bf16_t* Cb = (bf16_t*)Cp;
#pragma unroll
  for (int mh = 0; mh < 2; ++mh)
#pragma unroll
    for (int mi = 0; mi < 4; ++mi) {
      const size_t gr = row0 + wm * 128 + mh * 64 + mi * 16 + quad * 4;
#pragma unroll
      for (int ni = 0; ni < 4; ++ni) {
        const size_t gc = col0 + wn * 64 + ni * 16 + l15;
        float bv = 0.f;
        if (EPI == 0 || EPI == 3) bv = biasp ? (float)biasp[gc] : 0.f;
#pragma unroll
        for (int r = 0; r < 4; ++r) {
          const float v = acc[mh][mi][ni][r];
          const size_t idx = zoffC + (gr + r) * ldc + gc;
          if (EPI == 0) {
            Cb[idx] = (bf16_t)((v + bv) * scl);
          } else if (EPI == 1) {
            Cb[idx] = (bf16_t)v;
          } else {
            const float tt = v + bv;
            Cb[idx] = (bf16_t)(tt * (1.f / (1.f + __expf(-1.702f * tt))));
          }
        }
      }
    }
}

// ---------------- host-side launch helpers ----------------------------------
template <int EPI, int MODE, int NS = 1>
static void launch_gemm(hipStream_t stream, int M, int N, int Z,
                        const void* A, const void* Aalt, long lda, long sA,
                        const void* W0, const void* W1, const void* W2,
                        long ldw, long sW,
                        void* C0, void* C1, void* C2, long ldc, long sC,
                        const void* bias, const float* res, float scale, int K) {
  dim3 grid(N / 128, M / 128, Z);
  gemm_bt<EPI, MODE, NS><<<grid, dim3(256), 0, stream>>>(
      (const bf16_t*)A, (const bf16_t*)Aalt, lda, sA,
      (const bf16_t*)W0, (const bf16_t*)W1, (const bf16_t*)W2, ldw, sW,
      C0, C1, C2, ldc, sC, (const bf16_t*)bias, res, scale, K);
}

template <int EPI, int MODE>
static void launch_gemm256(hipStream_t stream, int M, int N, int Z,
                           const void* A, const void* Aalt, long lda, long sA,
                           const void* W0, const void* W1, const void* W2,
                           long ldw, long sW,
                           void* C0, void* C1, void* C2, long ldc, long sC,
                           const void* bias, float scale, int K) {
  dim3 grid(N / 256, M / 256, Z);  // nwg % 8 == 0 for all call sites
  gemm256<EPI, MODE><<<grid, dim3(512), 0, stream>>>(
      (const bf16_t*)A, (const bf16_t*)Aalt, lda, sA,
      (const bf16_t*)W0, (const bf16_t*)W1, (const bf16_t*)W2, ldw, sW,
      C0, C1, C2, ldc, sC, (const bf16_t*)bias, scale, K);
}

extern "C" void kernel_launch(void* const* d_in, const int* in_sizes, int n_in,
                              void* d_out, int out_size, void* d_ws, size_t ws_size,
                              hipStream_t stream) {
  (void)in_sizes; (void)n_in; (void)out_size; (void)ws_size;
  const float* tgt  = (const float*)d_in[0];
  const float* mem  = (const float*)d_in[1];
  // d_in[2] (mask) unused: causality applied structurally.
  const float* sa_qw = (const float*)d_in[3];
  const float* sa_kw = (const float*)d_in[4];
  const float* sa_vw = (const float*)d_in[5];
  const float* sa_b  = (const float*)d_in[6];
  const float* sa_ow = (const float*)d_in[7];
  const float* sa_ob = (const float*)d_in[8];
  const float* ca_qw = (const float*)d_in[9];
  const float* ca_kw = (const float*)d_in[10];
  const float* ca_vw = (const float*)d_in[11];
  const float* ca_b  = (const float*)d_in[12];
  const float* ca_ow = (const float*)d_in[13];
  const float* ca_ob = (const float*)d_in[14];
  const float* ln1g = (const float*)d_in[15];
  const float* ln1b = (const float*)d_in[16];
  const float* ln2g = (const float*)d_in[17];
  const float* ln2b = (const float*)d_in[18];
  const float* ln3g = (const float*)d_in[19];
  const float* ln3b = (const float*)d_in[20];
  const float* w1 = (const float*)d_in[21];
  const float* b1 = (const float*)d_in[22];
  const float* w2 = (const float*)d_in[23];
  const float* b2 = (const float*)d_in[24];

  char* ws = (char*)d_ws;
  const size_t MB = 1048576;
  float*  xf   = (float*)(ws);             // [0,32)   fp32 residual
  bf16_t* hb   = (bf16_t*)(ws + 32 * MB);  // [32,48)  LN out
  bf16_t* vb   = (bf16_t*)(ws + 48 * MB);  // [48,64)  V
  bf16_t* qb   = (bf16_t*)(ws + 64 * MB);  // [64,80)  Q
  bf16_t* kb   = (bf16_t*)(ws + 80 * MB);  // [80,96)  K
  bf16_t* vt   = (bf16_t*)(ws + 96 * MB);  // [96,112) V^T [n][e][s]
  bf16_t* sb   = (bf16_t*)(ws + 32 * MB);  // [32,64)  scores/probs
  bf16_t* ao   = kb;                       // [80,96)  attn out (kb dead)
  bf16_t* hid  = (bf16_t*)(ws + 48 * MB);  // [48,112) MLP hidden
  bf16_t* memb = (bf16_t*)(ws + 112 * MB); // [112,128) bf16 memory
  bf16_t* wt   = (bf16_t*)(ws + 128 * MB); // [128,160) bf16 weights
  bf16_t* bb   = (bf16_t*)(ws + 160 * MB); // biases

  const size_t M1 = 1048576;  // elems per E*E weight
  bf16_t* saq = wt,          *sak = wt + M1,     *sav = wt + 2 * M1;
  bf16_t* sao = wt + 3 * M1, *caq = wt + 4 * M1, *cak = wt + 5 * M1;
  bf16_t* cav = wt + 6 * M1, *cao = wt + 7 * M1;
  bf16_t* w1b = wt + 8 * M1;   // 4M elems
  bf16_t* w2b = wt + 12 * M1;  // 4M elems

  const float qscale = 0.03125f;  // 1024^-0.5

  // ---- fused weight/bias conversions (one launch) ----
  CastDesc cd;
  auto seg = [&](int i, const float* s, bf16_t* d, int elems) {
    cd.s[i] = CastSeg{s, d, elems / 1024};
  };
  seg(0, sa_qw, saq, 1 << 20);  seg(1, sa_kw, sak, 1 << 20);
  seg(2, sa_vw, sav, 1 << 20);  seg(3, sa_ow, sao, 1 << 20);
  seg(4, ca_qw, caq, 1 << 20);  seg(5, ca_kw, cak, 1 << 20);
  seg(6, ca_vw, cav, 1 << 20);  seg(7, ca_ow, cao, 1 << 20);
  seg(8, w1, w1b, 1 << 22);     seg(9, w2, w2b, 1 << 22);
  seg(10, sa_b, bb, 3072);      seg(11, sa_ob, bb + 3072, 1024);
  seg(12, ca_b, bb + 4096, 3072); seg(13, ca_ob, bb + 7168, 1024);
  seg(14, b1, bb + 8192, 4096); seg(15, b2, bb + 12288, 1024);
  int total_chunks = 0;
  for (int i = 0; i < 16; ++i) total_chunks += cd.s[i].chunks;
  cast_multi<<<total_chunks, 256, 0, stream>>>(cd);
  f32_to_bf16_n<<<4096, 256, 0, stream>>>(mem, memb, 1 << 23);

  // ================= self-attention (causal) =================
  ln_kernel<<<8192, 256, 0, stream>>>(tgt, ln1g, ln1b, hb);
  launch_gemm256<0, 3>(stream, 8192, 1024, 3, hb, hb, 1024, 0,
                       saq, sak, sav, 1024, 0, qb, kb, vb, 1024, 0,
                       bb, qscale, 1024);
  transpose_v<<<dim3(32, 16, 4), 256, 0, stream>>>(vb, vt);
  launch_gemm256<1, 1>(stream, 2048, 2048, 4, qb, nullptr, 4096, 1024,
                       kb, nullptr, nullptr, 4096, 1024,
                       sb, nullptr, nullptr, 2048, 4194304, nullptr,
                       1.f, 1024);
  softmax_kernel<1><<<8192, 256, 0, stream>>>(sb);
  launch_gemm<0, 2, 2>(stream, 2048, 1024, 4, sb, nullptr, 2048, 4194304,
                       vt, nullptr, nullptr, 2048, 2097152,
                       ao, nullptr, nullptr, 4096, 1024, nullptr, nullptr,
                       1.f, 2048);
  launch_gemm<2, 0, 2>(stream, 8192, 1024, 1, ao, nullptr, 1024, 0,
                       sao, nullptr, nullptr, 1024, 0,
                       xf, nullptr, nullptr, 1024, 0, bb + 3072, tgt,
                       1.f, 1024);

  // ================= cross-attention (no mask) =================
  ln_kernel<<<8192, 256, 0, stream>>>(xf, ln2g, ln2b, hb);
  launch_gemm256<0, 3>(stream, 8192, 1024, 3, hb, memb, 1024, 0,
                       caq, cak, cav, 1024, 0, qb, kb, vb, 1024, 0,
                       bb + 4096, qscale, 1024);
  transpose_v<<<dim3(32, 16, 4), 256, 0, stream>>>(vb, vt);
  launch_gemm256<1, 0>(stream, 2048, 2048, 4, qb, nullptr, 4096, 1024,
                       kb, nullptr, nullptr, 4096, 1024,
                       sb, nullptr, nullptr, 2048, 4194304, nullptr,
                       1.f, 1024);
  softmax_kernel<0><<<8192, 256, 0, stream>>>(sb);
  launch_gemm<0, 0, 2>(stream, 2048, 1024, 4, sb, nullptr, 2048, 4194304,
                       vt, nullptr, nullptr, 2048, 2097152,
                       ao, nullptr, nullptr, 4096, 1024, nullptr, nullptr,
                       1.f, 2048);
  launch_gemm<2, 0, 2>(stream, 8192, 1024, 1, ao, nullptr, 1024, 0,
                       cao, nullptr, nullptr, 1024, 0,
                       xf, nullptr, nullptr, 1024, 0, bb + 7168, xf,
                       1.f, 1024);

  // ================= MLP (QuickGELU) =================
  ln_kernel<<<8192, 256, 0, stream>>>(xf, ln3g, ln3b, hb);
  launch_gemm256<3, 0>(stream, 8192, 4096, 1, hb, nullptr, 1024, 0,
                       w1b, nullptr, nullptr, 1024, 0,
                       hid, nullptr, nullptr, 4096, 0, bb + 8192,
                       1.f, 1024);
  launch_gemm<2, 0, 2>(stream, 8192, 1024, 1, hid, nullptr, 4096, 0,
                       w2b, nullptr, nullptr, 4096, 0,
                       d_out, nullptr, nullptr, 1024, 0, bb + 12288, xf,
                       1.f, 4096);
}

// Round 6
// 807.221 us; speedup vs baseline: 1.2166x; 1.0040x over previous
//
#include <hip/hip_runtime.h>
#include <hip/hip_bf16.h>
#include <cstdint>
#include <cstddef>

// SingleheadTransformerDecoderLayer: L=S=2048, N=4, E=1024, FF=4096, fp32 I/O.
// Round 13: exact m201-template phase order in gemm256. Occupancy analysis
// closed the alternatives: acc=128 regs/wave -> 2 waves/SIMD, 1 block/CU is
// structural; overlap must come from the phase schedule. Remaining material
// diff vs the verified template: ds_reads must come BEFORE the gll16 stage
// in each phase -- a read that FOLLOWS a global_load_lds in program order
// can make the compiler emit a vmcnt drain before the read burst (the only
// HW mechanism to order LDS-DMA write vs ds_read), silently serializing
// the prefetch ring every phase (explains the r10/r11/r12 ~27% plateau
// invariant to barrier structure). Phase body now:
//   reads(af, bfv if MH0) -> stage(g+6) -> [PH0: vmcnt(2|0)] -> s_barrier
//   -> asm lgkmcnt(0) + sched_barrier(0) -> setprio(1) 16xMFMA setprio(0)
//   -> s_barrier
// Ring h=g+6; once-per-tile gate vmcnt(2) at PH0 retires h<=4t+5 (this
// tile's later phases + next tile's PH0 reads); tail: vmcnt(0) at t=T-1;
// prologue: stage h=0..5, vmcnt(8), barrier. WAR audited: stage@PH2
// (As[p][0], read at PH0/PH1) sits behind PH1's end barrier; ks1 slabs
// behind previous tile's end barrier. gemm_bt untouched.
//
// Workspace layout (161MB):
//   [0,32)    xf   : fp32 residual [8192,1024]
//   [32,48)   hb   : bf16 LN out
//   [48,64)   vb   : bf16 V          } sb bf16 scores [n][l][s] = [32,64)
//   [64,80)   qb   : bf16 Q          }   (hb,vb dead by score-GEMM time)
//   [80,96)   kb   : bf16 K  (reused as attn-out ao after score GEMM)
//   [96,112)  vt   : bf16 V^T [n][e][s]
//   [48,112)  hid  : bf16 MLP hidden [8192,4096] (vb,qb,kb,vt dead)
//   [112,128) memb : bf16 copy of `memory`
//   [128,160) wts  : bf16 weights; [160,161) bb : bf16 biases

using bf16_t = __bf16;
typedef __bf16 bf16x8 __attribute__((ext_vector_type(8)));
typedef __bf16 bf16x4 __attribute__((ext_vector_type(4)));
typedef float f32x4 __attribute__((ext_vector_type(4)));

// ---------------- async global->LDS, 16B/lane, wave-uniform LDS base --------
__device__ __forceinline__ void gll16(const void* g, void* lds) {
  __builtin_amdgcn_global_load_lds(
      (__attribute__((address_space(1))) void*)(g),
      (__attribute__((address_space(3))) void*)(lds), 16, 0, 0);
}

// ---------------- fp32 -> bf16 cast (8 elems/thread) ------------------------
__global__ __launch_bounds__(256) void f32_to_bf16_n(
    const float* __restrict__ in, bf16_t* __restrict__ out, int n) {
  const size_t i = ((size_t)blockIdx.x * 256 + threadIdx.x) * 8;
  if (i >= (size_t)n) return;
  f32x4 a = *(const f32x4*)(in + i);
  f32x4 b = *(const f32x4*)(in + i + 4);
  bf16x8 v;
#pragma unroll
  for (int j = 0; j < 4; ++j) { v[j] = (bf16_t)a[j]; v[4 + j] = (bf16_t)b[j]; }
  *(bf16x8*)(out + i) = v;
}

// ---------------- fused multi-segment fp32 -> bf16 cast ---------------------
struct CastSeg { const float* src; bf16_t* dst; int chunks; };
struct CastDesc { CastSeg s[16]; };
__global__ __launch_bounds__(256) void cast_multi(CastDesc d) {
  int blk = blockIdx.x, seg = 0, base = 0;
  while (blk - base >= d.s[seg].chunks) { base += d.s[seg].chunks; ++seg; }
  const size_t i = (size_t)(blk - base) * 1024 + threadIdx.x * 4;
  f32x4 a = *(const f32x4*)(d.s[seg].src + i);
  bf16x4 v;
#pragma unroll
  for (int j = 0; j < 4; ++j) v[j] = (bf16_t)a[j];
  *(bf16x4*)(d.s[seg].dst + i) = v;
}

// ---------------- LayerNorm over E=1024, one block per row ------------------
__global__ __launch_bounds__(256) void ln_kernel(
    const float* __restrict__ x, const float* __restrict__ g,
    const float* __restrict__ b, bf16_t* __restrict__ out) {
  const int row = blockIdx.x, tid = threadIdx.x;
  const float* xr = x + (size_t)row * 1024;
  float v0 = xr[tid], v1 = xr[tid + 256], v2 = xr[tid + 512], v3 = xr[tid + 768];
  float s = v0 + v1 + v2 + v3;
  float ss = v0 * v0 + v1 * v1 + v2 * v2 + v3 * v3;
#pragma unroll
  for (int off = 32; off > 0; off >>= 1) {
    s += __shfl_down(s, off, 64);
    ss += __shfl_down(ss, off, 64);
  }
  __shared__ float red[8];
  const int w = tid >> 6, lane = tid & 63;
  if (lane == 0) { red[w] = s; red[4 + w] = ss; }
  __syncthreads();
  s = red[0] + red[1] + red[2] + red[3];
  ss = red[4] + red[5] + red[6] + red[7];
  const float mean = s * (1.f / 1024.f);
  float var = ss * (1.f / 1024.f) - mean * mean;
  var = var < 0.f ? 0.f : var;
  const float inv = rsqrtf(var + 1e-5f);
  bf16_t* orow = out + (size_t)row * 1024;
  orow[tid]       = (bf16_t)((v0 - mean) * inv * g[tid]       + b[tid]);
  orow[tid + 256] = (bf16_t)((v1 - mean) * inv * g[tid + 256] + b[tid + 256]);
  orow[tid + 512] = (bf16_t)((v2 - mean) * inv * g[tid + 512] + b[tid + 512]);
  orow[tid + 768] = (bf16_t)((v3 - mean) * inv * g[tid + 768] + b[tid + 768]);
}

// ---------------- softmax over S=2048, bf16 in-place, optional causal -------
template <int CAUSAL>
__global__ __launch_bounds__(256) void softmax_kernel(bf16_t* __restrict__ sc) {
  const int row = blockIdx.x, tid = threadIdx.x;
  const int l = row & 2047;
  bf16_t* sr = sc + (size_t)row * 2048;
  float v[8];
  float mx = -3.4e38f;
#pragma unroll
  for (int i = 0; i < 8; ++i) {
    const int j = tid + i * 256;
    v[i] = (CAUSAL && j > l) ? -3.4e38f : (float)sr[j];
    mx = fmaxf(mx, v[i]);
  }
#pragma unroll
  for (int off = 32; off > 0; off >>= 1) mx = fmaxf(mx, __shfl_down(mx, off, 64));
  __shared__ float red[8];
  const int w = tid >> 6, lane = tid & 63;
  if (lane == 0) red[w] = mx;
  __syncthreads();
  mx = fmaxf(fmaxf(red[0], red[1]), fmaxf(red[2], red[3]));
  float sum = 0.f;
#pragma unroll
  for (int i = 0; i < 8; ++i) { v[i] = __expf(v[i] - mx); sum += v[i]; }
#pragma unroll
  for (int off = 32; off > 0; off >>= 1) sum += __shfl_down(sum, off, 64);
  if (lane == 0) red[4 + w] = sum;
  __syncthreads();
  sum = red[4] + red[5] + red[6] + red[7];
  const float r = 1.f / sum;
#pragma unroll
  for (int i = 0; i < 8; ++i) sr[tid + i * 256] = (bf16_t)(v[i] * r);
}

// ---------------- V transpose: [s*4+n, e] -> vt[n][e][s] --------------------
__global__ __launch_bounds__(256) void transpose_v(const bf16_t* __restrict__ v,
                                                   bf16_t* __restrict__ vt) {
  __shared__ bf16_t tile[64][72];
  const int n = blockIdx.z;
  const int s0 = blockIdx.x * 64, e0 = blockIdx.y * 64;
  const int tid = threadIdx.x;
#pragma unroll
  for (int j = 0; j < 2; ++j) {
    int flat = j * 256 + tid;
    int r = flat >> 3, c8 = (flat & 7) * 8;
    bf16x8 val = *(const bf16x8*)(v + ((size_t)(s0 + r) * 4 + n) * 1024 + e0 + c8);
#pragma unroll
    for (int i = 0; i < 8; ++i) tile[r][c8 + i] = val[i];
  }
  __syncthreads();
#pragma unroll
  for (int j = 0; j < 2; ++j) {
    int flat = j * 256 + tid;
    int er = flat >> 3, s8 = (flat & 7) * 8;
    bf16x8 val;
#pragma unroll
    for (int i = 0; i < 8; ++i) val[i] = tile[s8 + i][er];
    *(bf16x8*)(vt + ((size_t)n * 1024 + e0 + er) * 2048 + s0 + s8) = val;
  }
}

// ---------------- generic C = A @ W^T GEMM, double-buffered LDS -------------
// (128x128 engine -- for the 128-block grids: PV, out-proj, MLP2)
// Slab per kslice = [128 rows][32 k] row-major (64B row stride), 16B slots
// swizzled: elem(r,k) at byte r*64 + ((k>>3)^((r>>1)&3))*16 + (k&7)*2.
// Staging: gll16 writes linear 1024B rowgroups; global source lane L reads
// row rg*16+(L>>2), k-octet (L&3)^((L>>3)&3) (permutation within one 64B
// run -> coalesced). Frag read: row*32 + (quad^((l15>>1)&3))*8 elems.
// EPI: 0 = bf16 store (acc+bias)*scale; 1 = bf16 store acc;
//      2 = fp32 store res[idx]+acc+bias; 3 = QuickGELU -> bf16.
// MODE: 0 = plain (z = batch); 1 = causal score (skip col0 > row0);
//       2 = causal PV (K capped at row0+128); 3 = fused QKV.
template <int EPI, int MODE, int NS>
__global__ __launch_bounds__(256) void gemm_bt(
    const bf16_t* __restrict__ A, const bf16_t* __restrict__ Aalt,
    long lda, long sA,
    const bf16_t* __restrict__ W0, const bf16_t* __restrict__ W1,
    const bf16_t* __restrict__ W2, long ldw, long sW,
    void* __restrict__ C0, void* __restrict__ C1, void* __restrict__ C2,
    long ldc, long sC,
    const bf16_t* __restrict__ bias, const float* __restrict__ res,
    float scale, int K) {
  const size_t row0 = (size_t)blockIdx.y * 128;
  const size_t col0 = (size_t)blockIdx.x * 128;
  if (MODE == 1 && col0 > row0) return;  // fully-masked causal tile
  const int z = blockIdx.z;
  constexpr int BK = NS * 32;

  const bf16_t* Ap = (MODE == 3) ? (z == 0 ? A : Aalt) : A + (size_t)z * sA;
  const bf16_t* Wp = (MODE == 3) ? (z == 0 ? W0 : (z == 1 ? W1 : W2))
                                 : W0 + (size_t)z * sW;
  void* Cp = (MODE == 3) ? (z == 0 ? C0 : (z == 1 ? C1 : C2)) : C0;
  const size_t zoffC = (MODE == 3) ? 0 : (size_t)z * sC;
  const bf16_t* biasp = bias ? bias + (MODE == 3 ? z * 1024 : 0) : nullptr;
  const float scl = (MODE == 3 && z != 0) ? 1.f : scale;
  const int kend = (MODE == 2) ? min(K, (int)row0 + 128) : K;

  __shared__ __align__(16) bf16_t As[2][NS][128 * 32];
  __shared__ __align__(16) bf16_t Bs[2][NS][128 * 32];
  const int tid = threadIdx.x;
  const int wv = tid >> 6, lane = tid & 63;
  const int quad = lane >> 4, l15 = lane & 15;
  const int wr = wv >> 1, wc = wv & 1;

  // staging: chunk c = wv*2NS+j -> kslice ksc=c>>3, rowgroup rg=c&7.
  // lane L: row rg*16+(L>>2), k-octet (L&3)^((L>>3)&3) (64B-local perm).
  const bf16_t* gA[2 * NS];
  const bf16_t* gW[2 * NS];
  int dof[2 * NS];  // wave-uniform LDS elem offset within parity buffer
  const int soct = (lane & 3) ^ ((lane >> 3) & 3);
#pragma unroll
  for (int j = 0; j < 2 * NS; ++j) {
    const int c = wv * 2 * NS + j;
    const int ksc = c >> 3;
    const int rg = c & 7;
    const int rr = rg * 16 + (lane >> 2);
    const int cc = ksc * 32 + soct * 8;
    gA[j] = Ap + (row0 + rr) * lda + cc;
    gW[j] = Wp + (col0 + rr) * ldw + cc;
    dof[j] = ksc * 4096 + rg * 512;
  }

  f32x4 acc[4][4];
#pragma unroll
  for (int mi = 0; mi < 4; ++mi)
#pragma unroll
    for (int ni = 0; ni < 4; ++ni) acc[mi][ni] = (f32x4)0.f;

#pragma unroll
  for (int j = 0; j < 2 * NS; ++j) {
    gll16(gA[j], &As[0][0][0] + dof[j]);
    gll16(gW[j], &Bs[0][0][0] + dof[j]);
  }

  // frag lane offset: row=base+l15 -> l15*32 + swizzled 16B slot
  const int fro = l15 * 32 + (quad ^ ((l15 >> 1) & 3)) * 8;

  int p = 0;
  for (int k0 = 0; k0 < kend; k0 += BK, p ^= 1) {
    __syncthreads();
    const int kn = k0 + BK;
    if (kn < kend) {
#pragma unroll
      for (int j = 0; j < 2 * NS; ++j) {
        gll16(gA[j] + kn, &As[p ^ 1][0][0] + dof[j]);
        gll16(gW[j] + kn, &Bs[p ^ 1][0][0] + dof[j]);
      }
    }
#pragma unroll
    for (int ks = 0; ks < NS; ++ks) {
      bf16x8 af[4], bfv[4];
#pragma unroll
      for (int mi = 0; mi < 4; ++mi)
        af[mi] = *(const bf16x8*)(As[p][ks] + (wr * 4 + mi) * 512 + fro);
#pragma unroll
      for (int ni = 0; ni < 4; ++ni)
        bfv[ni] = *(const bf16x8*)(Bs[p][ks] + (wc * 4 + ni) * 512 + fro);
#pragma unroll
      for (int mi = 0; mi < 4; ++mi)
#pragma unroll
        for (int ni = 0; ni < 4; ++ni)
          acc[mi][ni] = __builtin_amdgcn_mfma_f32_16x16x32_bf16(
              af[mi], bfv[ni], acc[mi][ni], 0, 0, 0);
    }
  }

  float* Cf = (float*)Cp;
  bf16_t* Cb = (bf16_t*)Cp;
#pragma unroll
  for (int mi = 0; mi < 4; ++mi) {
    const size_t gr = row0 + wr * 64 + mi * 16 + quad * 4;
#pragma unroll
    for (int ni = 0; ni < 4; ++ni) {
      const size_t gc = col0 + wc * 64 + ni * 16 + l15;
      float bv = 0.f;
      if (EPI == 0 || EPI == 2 || EPI == 3) bv = biasp ? (float)biasp[gc] : 0.f;
#pragma unroll
      for (int r = 0; r < 4; ++r) {
        float v = acc[mi][ni][r];
        const size_t idx = zoffC + (gr + r) * ldc + gc;
        if (EPI == 0) {
          Cb[idx] = (bf16_t)((v + bv) * scl);
        } else if (EPI == 1) {
          Cb[idx] = (bf16_t)v;
        } else if (EPI == 2) {
          Cf[idx] = res[idx] + v + bv;
        } else {
          float t = v + bv;
          Cb[idx] = (bf16_t)(t * (1.f / (1.f + __expf(-1.702f * t))));
        }
      }
    }
  }
}

// ---------------- 256x256 8-phase GEMM engine (T3+T4+T5) --------------------
// 512 threads = 8 waves (2M x 4N); wave tile 128x64; BK=64 as two kslice
// slots per operand; 2x double-buffer => 8 slots, 128 KiB total.
// Slab per kslice slot = [256 rows][32 k] row-major with the same 16B-slot
// swizzle as gemm_bt. Staging: wave wid covers rowgroups 2wid, 2wid+1 per
// half; lane L reads row rg*16+(L>>2), k-octet (L&3)^((L>>3)&3); gll16
// dest linear rowgroups.
// Half-tile ring h = {tile u=h>>2, ks=(h>>1)&1, op=h&1}; phase g stages
// h = g+6. m201-template phase body (reads FIRST, stage second -- a read
// following a gll16 in program order can draw a compiler vmcnt drain):
//   reads(af; bfv if MH0) -> stage(g+6) -> [PH0: vmcnt(2), last tile 0]
//   -> s_barrier -> asm lgkmcnt(0) + sched_barrier(0)
//   -> setprio(1) 16xMFMA setprio(0) -> s_barrier
// vmcnt(2)@PH0 retires h<=4t+5: tile t phases 1-3 AND tile t+1 PH0 reads;
// publication = PH0 mid-barrier. Prologue: stage h=0..5, vmcnt(8), barrier.
// WAR: stage@PH2 (As[p][0]; read at PH0/PH1) behind PH1 end barrier;
// ks1 slabs behind previous tile's end barrier.
// EPI: 0 = bf16 (acc+bias)*scale; 1 = bf16 acc; 3 = QuickGELU bf16.
// MODE: 0 = plain z-batch; 1 = causal score (skip bx>by); 3 = fused QKV.
template <int EPI, int MODE>
__global__ __launch_bounds__(512, 2) void gemm256(
    const bf16_t* __restrict__ A, const bf16_t* __restrict__ Aalt,
    long lda, long sA,
    const bf16_t* __restrict__ W0, const bf16_t* __restrict__ W1,
    const bf16_t* __restrict__ W2, long ldw, long sW,
    void* __restrict__ C0, void* __restrict__ C1, void* __restrict__ C2,
    long ldc, long sC,
    const bf16_t* __restrict__ bias, float scale, int K) {
  // XCD-aware bijective chunked swizzle (all launch grids have nwg % 8 == 0).
  const int gx = gridDim.x, gy = gridDim.y;
  const int nwg = gx * gy * (int)gridDim.z;
  const int hw = (int)blockIdx.x + gx * ((int)blockIdx.y + gy * (int)blockIdx.z);
  const int logical = (hw & 7) * (nwg >> 3) + (hw >> 3);
  const int bx = logical % gx;
  const int by = (logical / gx) % gy;
  const int z  = logical / (gx * gy);
  const size_t row0 = (size_t)by * 256, col0 = (size_t)bx * 256;
  if (MODE == 1 && bx > by) return;  // fully-masked causal tile

  const bf16_t* Ap = (MODE == 3) ? (z == 0 ? A : Aalt) : A + (size_t)z * sA;
  const bf16_t* Wp = (MODE == 3) ? (z == 0 ? W0 : (z == 1 ? W1 : W2))
                                 : W0 + (size_t)z * sW;
  void* Cp = (MODE == 3) ? (z == 0 ? C0 : (z == 1 ? C1 : C2)) : C0;
  const size_t zoffC = (MODE == 3) ? 0 : (size_t)z * sC;
  const bf16_t* biasp = bias ? bias + (MODE == 3 ? z * 1024 : 0) : nullptr;
  const float scl = (MODE == 3 && z != 0) ? 1.f : scale;

  __shared__ __align__(16) bf16_t As[2][2][8192];  // [parity][kslice]
  __shared__ __align__(16) bf16_t Bs[2][2][8192];

  const int tid = threadIdx.x;
  const int lane = tid & 63, wid = tid >> 6;
  const int l15 = lane & 15, quad = lane >> 4;
  const int wm = wid >> 2, wn = wid & 3;

  // Staging: wave wid covers rowgroups 2*wid and 2*wid+1 of each half.
  const int soct = (lane & 3) ^ ((lane >> 3) & 3);
  const bf16_t* pA[2];
  const bf16_t* pB[2];
#pragma unroll
  for (int j = 0; j < 2; ++j) {
    const int rr = (wid * 2 + j) * 16 + (lane >> 2);
    const int kc = soct * 8;
    pA[j] = Ap + (row0 + rr) * lda + kc;
    pB[j] = Wp + (col0 + rr) * ldw + kc;
  }
  const int d0 = (wid * 2) * 512;      // wave-uniform LDS elem base, j=0
  const int d1 = (wid * 2 + 1) * 512;  // j=1

  const int T = K >> 6;    // number of BK=64 tiles
  const int HT = 4 * T;    // total half-tiles

  auto stage = [&](int h) {
    if (h >= HT) return;
    const int u = h >> 2, ks = (h >> 1) & 1;
    const int coff = u * 64 + ks * 32;
    if (h & 1) {
      gll16(pB[0] + coff, &Bs[u & 1][ks][0] + d0);
      gll16(pB[1] + coff, &Bs[u & 1][ks][0] + d1);
    } else {
      gll16(pA[0] + coff, &As[u & 1][ks][0] + d0);
      gll16(pA[1] + coff, &As[u & 1][ks][0] + d1);
    }
  };

  f32x4 acc[2][4][4];
#pragma unroll
  for (int mh = 0; mh < 2; ++mh)
#pragma unroll
    for (int mi = 0; mi < 4; ++mi)
#pragma unroll
      for (int ni = 0; ni < 4; ++ni) acc[mh][mi][ni] = (f32x4)0.f;

  // prologue: 6 halves in flight; gate h=0,1 (tile 0 ks0) then publish
#pragma unroll
  for (int h = 0; h < 6; ++h) stage(h);
  asm volatile("s_waitcnt vmcnt(8)" ::: "memory");
  __builtin_amdgcn_s_barrier();

  // frag lane offset: row=base+l15 -> l15*32 + swizzled 16B slot
  const int fro = l15 * 32 + (quad ^ ((l15 >> 1) & 3)) * 8;

  for (int t = 0; t < T; ++t) {
    const int p = t & 1;
    const int g4 = 4 * t;
    bf16x8 bfv[4];

// PH: phase 0..3; KK: k-slice; MH: fragment-half. B fragments loaded when
// MH==0, reused (in regs, across phases) when MH==1. Template order:
// reads FIRST, then stage, then gate/barrier, then MFMA.
#define PHASE(PH, KK, MH)                                                     \
    {                                                                         \
      bf16x8 af[4];                                                           \
      _Pragma("unroll")                                                       \
      for (int mi = 0; mi < 4; ++mi)                                          \
        af[mi] = *(const bf16x8*)(&As[p][KK][0] +                             \
                                  (wm * 8 + MH * 4 + mi) * 512 + fro);        \
      if (MH == 0) {                                                          \
        _Pragma("unroll")                                                     \
        for (int ni = 0; ni < 4; ++ni)                                        \
          bfv[ni] = *(const bf16x8*)(&Bs[p][KK][0] +                          \
                                     (wn * 4 + ni) * 512 + fro);              \
      }                                                                       \
      stage(g4 + 6 + PH);                                                     \
      if (PH == 0) {                                                          \
        if (t < T - 1) asm volatile("s_waitcnt vmcnt(2)" ::: "memory");       \
        else           asm volatile("s_waitcnt vmcnt(0)" ::: "memory");       \
      }                                                                       \
      __builtin_amdgcn_s_barrier();                                          \
      asm volatile("s_waitcnt lgkmcnt(0)" ::: "memory");                      \
      __builtin_amdgcn_sched_barrier(0);                                      \
      __builtin_amdgcn_s_setprio(1);                                         \
      _Pragma("unroll")                                                       \
      for (int mi = 0; mi < 4; ++mi)                                          \
        _Pragma("unroll")                                                     \
        for (int ni = 0; ni < 4; ++ni)                                        \
          acc[MH][mi][ni] = __builtin_amdgcn_mfma_f32_16x16x32_bf16(          \
              af[mi], bfv[ni], acc[MH][mi][ni], 0, 0, 0);                     \
      __builtin_amdgcn_s_setprio(0);                                          \
      __builtin_amdgcn_s_barrier();                                          \
    }

    PHASE(0, 0, 0)
    PHASE(1, 0, 1)
    PHASE(2, 1, 0)
    PHASE(3, 1, 1)
#undef PHASE
  }

  // epilogue: C/D layout col=lane&15, row=quad*4+r
  bf16_t* Cb = (bf16_t*)Cp;
#pragma unroll
  for (int mh = 0; mh < 2; ++mh)
#pragma unroll
    for (int mi = 0; mi < 4; ++mi) {
      const size_t gr = row0 + wm * 128 + mh * 64 + mi * 16 + quad * 4;
#pragma unroll
      for (int ni = 0; ni < 4; ++ni) {
        const size_t gc = col0 + wn * 64 + ni * 16 + l15;
        float bv = 0.f;
        if (EPI == 0 || EPI == 3) bv = biasp ? (float)biasp[gc] : 0.f;
#pragma unroll
        for (int r = 0; r < 4; ++r) {
          const float v = acc[mh][mi][ni][r];
          const size_t idx = zoffC + (gr + r) * ldc + gc;
          if (EPI == 0) {
            Cb[idx] = (bf16_t)((v + bv) * scl);
          } else if (EPI == 1) {
            Cb[idx] = (bf16_t)v;
          } else {
            const float tt = v + bv;
            Cb[idx] = (bf16_t)(tt * (1.f / (1.f + __expf(-1.702f * tt))));
          }
        }
      }
    }
}

// ---------------- host-side launch helpers ----------------------------------
template <int EPI, int MODE, int NS = 1>
static void launch_gemm(hipStream_t stream, int M, int N, int Z,
                        const void* A, const void* Aalt, long lda, long sA,
                        const void* W0, const void* W1, const void* W2,
                        long ldw, long sW,
                        void* C0, void* C1, void* C2, long ldc, long sC,
                        const void* bias, const float* res, float scale, int K) {
  dim3 grid(N / 128, M / 128, Z);
  gemm_bt<EPI, MODE, NS><<<grid, dim3(256), 0, stream>>>(
      (const bf16_t*)A, (const bf16_t*)Aalt, lda, sA,
      (const bf16_t*)W0, (const bf16_t*)W1, (const bf16_t*)W2, ldw, sW,
      C0, C1, C2, ldc, sC, (const bf16_t*)bias, res, scale, K);
}

template <int EPI, int MODE>
static void launch_gemm256(hipStream_t stream, int M, int N, int Z,
                           const void* A, const void* Aalt, long lda, long sA,
                           const void* W0, const void* W1, const void* W2,
                           long ldw, long sW,
                           void* C0, void* C1, void* C2, long ldc, long sC,
                           const void* bias, float scale, int K) {
  dim3 grid(N / 256, M / 256, Z);  // nwg % 8 == 0 for all call sites
  gemm256<EPI, MODE><<<grid, dim3(512), 0, stream>>>(
      (const bf16_t*)A, (const bf16_t*)Aalt, lda, sA,
      (const bf16_t*)W0, (const bf16_t*)W1, (const bf16_t*)W2, ldw, sW,
      C0, C1, C2, ldc, sC, (const bf16_t*)bias, scale, K);
}

extern "C" void kernel_launch(void* const* d_in, const int* in_sizes, int n_in,
                              void* d_out, int out_size, void* d_ws, size_t ws_size,
                              hipStream_t stream) {
  (void)in_sizes; (void)n_in; (void)out_size; (void)ws_size;
  const float* tgt  = (const float*)d_in[0];
  const float* mem  = (const float*)d_in[1];
  // d_in[2] (mask) unused: causality applied structurally.
  const float* sa_qw = (const float*)d_in[3];
  const float* sa_kw = (const float*)d_in[4];
  const float* sa_vw = (const float*)d_in[5];
  const float* sa_b  = (const float*)d_in[6];
  const float* sa_ow = (const float*)d_in[7];
  const float* sa_ob = (const float*)d_in[8];
  const float* ca_qw = (const float*)d_in[9];
  const float* ca_kw = (const float*)d_in[10];
  const float* ca_vw = (const float*)d_in[11];
  const float* ca_b  = (const float*)d_in[12];
  const float* ca_ow = (const float*)d_in[13];
  const float* ca_ob = (const float*)d_in[14];
  const float* ln1g = (const float*)d_in[15];
  const float* ln1b = (const float*)d_in[16];
  const float* ln2g = (const float*)d_in[17];
  const float* ln2b = (const float*)d_in[18];
  const float* ln3g = (const float*)d_in[19];
  const float* ln3b = (const float*)d_in[20];
  const float* w1 = (const float*)d_in[21];
  const float* b1 = (const float*)d_in[22];
  const float* w2 = (const float*)d_in[23];
  const float* b2 = (const float*)d_in[24];

  char* ws = (char*)d_ws;
  const size_t MB = 1048576;
  float*  xf   = (float*)(ws);             // [0,32)   fp32 residual
  bf16_t* hb   = (bf16_t*)(ws + 32 * MB);  // [32,48)  LN out
  bf16_t* vb   = (bf16_t*)(ws + 48 * MB);  // [48,64)  V
  bf16_t* qb   = (bf16_t*)(ws + 64 * MB);  // [64,80)  Q
  bf16_t* kb   = (bf16_t*)(ws + 80 * MB);  // [80,96)  K
  bf16_t* vt   = (bf16_t*)(ws + 96 * MB);  // [96,112) V^T [n][e][s]
  bf16_t* sb   = (bf16_t*)(ws + 32 * MB);  // [32,64)  scores/probs
  bf16_t* ao   = kb;                       // [80,96)  attn out (kb dead)
  bf16_t* hid  = (bf16_t*)(ws + 48 * MB);  // [48,112) MLP hidden
  bf16_t* memb = (bf16_t*)(ws + 112 * MB); // [112,128) bf16 memory
  bf16_t* wt   = (bf16_t*)(ws + 128 * MB); // [128,160) bf16 weights
  bf16_t* bb   = (bf16_t*)(ws + 160 * MB); // biases

  const size_t M1 = 1048576;  // elems per E*E weight
  bf16_t* saq = wt,          *sak = wt + M1,     *sav = wt + 2 * M1;
  bf16_t* sao = wt + 3 * M1, *caq = wt + 4 * M1, *cak = wt + 5 * M1;
  bf16_t* cav = wt + 6 * M1, *cao = wt + 7 * M1;
  bf16_t* w1b = wt + 8 * M1;   // 4M elems
  bf16_t* w2b = wt + 12 * M1;  // 4M elems

  const float qscale = 0.03125f;  // 1024^-0.5

  // ---- fused weight/bias conversions (one launch) ----
  CastDesc cd;
  auto seg = [&](int i, const float* s, bf16_t* d, int elems) {
    cd.s[i] = CastSeg{s, d, elems / 1024};
  };
  seg(0, sa_qw, saq, 1 << 20);  seg(1, sa_kw, sak, 1 << 20);
  seg(2, sa_vw, sav, 1 << 20);  seg(3, sa_ow, sao, 1 << 20);
  seg(4, ca_qw, caq, 1 << 20);  seg(5, ca_kw, cak, 1 << 20);
  seg(6, ca_vw, cav, 1 << 20);  seg(7, ca_ow, cao, 1 << 20);
  seg(8, w1, w1b, 1 << 22);     seg(9, w2, w2b, 1 << 22);
  seg(10, sa_b, bb, 3072);      seg(11, sa_ob, bb + 3072, 1024);
  seg(12, ca_b, bb + 4096, 3072); seg(13, ca_ob, bb + 7168, 1024);
  seg(14, b1, bb + 8192, 4096); seg(15, b2, bb + 12288, 1024);
  int total_chunks = 0;
  for (int i = 0; i < 16; ++i) total_chunks += cd.s[i].chunks;
  cast_multi<<<total_chunks, 256, 0, stream>>>(cd);
  f32_to_bf16_n<<<4096, 256, 0, stream>>>(mem, memb, 1 << 23);

  // ================= self-attention (causal) =================
  ln_kernel<<<8192, 256, 0, stream>>>(tgt, ln1g, ln1b, hb);
  launch_gemm256<0, 3>(stream, 8192, 1024, 3, hb, hb, 1024, 0,
                       saq, sak, sav, 1024, 0, qb, kb, vb, 1024, 0,
                       bb, qscale, 1024);
  transpose_v<<<dim3(32, 16, 4), 256, 0, stream>>>(vb, vt);
  launch_gemm256<1, 1>(stream, 2048, 2048, 4, qb, nullptr, 4096, 1024,
                       kb, nullptr, nullptr, 4096, 1024,
                       sb, nullptr, nullptr, 2048, 4194304, nullptr,
                       1.f, 1024);
  softmax_kernel<1><<<8192, 256, 0, stream>>>(sb);
  launch_gemm<0, 2, 2>(stream, 2048, 1024, 4, sb, nullptr, 2048, 4194304,
                       vt, nullptr, nullptr, 2048, 2097152,
                       ao, nullptr, nullptr, 4096, 1024, nullptr, nullptr,
                       1.f, 2048);
  launch_gemm<2, 0, 2>(stream, 8192, 1024, 1, ao, nullptr, 1024, 0,
                       sao, nullptr, nullptr, 1024, 0,
                       xf, nullptr, nullptr, 1024, 0, bb + 3072, tgt,
                       1.f, 1024);

  // ================= cross-attention (no mask) =================
  ln_kernel<<<8192, 256, 0, stream>>>(xf, ln2g, ln2b, hb);
  launch_gemm256<0, 3>(stream, 8192, 1024, 3, hb, memb, 1024, 0,
                       caq, cak, cav, 1024, 0, qb, kb, vb, 1024, 0,
                       bb + 4096, qscale, 1024);
  transpose_v<<<dim3(32, 16, 4), 256, 0, stream>>>(vb, vt);
  launch_gemm256<1, 0>(stream, 2048, 2048, 4, qb, nullptr, 4096, 1024,
                       kb, nullptr, nullptr, 4096, 1024,
                       sb, nullptr, nullptr, 2048, 4194304, nullptr,
                       1.f, 1024);
  softmax_kernel<0><<<8192, 256, 0, stream>>>(sb);
  launch_gemm<0, 0, 2>(stream, 2048, 1024, 4, sb, nullptr, 2048, 4194304,
                       vt, nullptr, nullptr, 2048, 2097152,
                       ao, nullptr, nullptr, 4096, 1024, nullptr, nullptr,
                       1.f, 2048);
  launch_gemm<2, 0, 2>(stream, 8192, 1024, 1, ao, nullptr, 1024, 0,
                       cao, nullptr, nullptr, 1024, 0,
                       xf, nullptr, nullptr, 1024, 0, bb + 7168, xf,
                       1.f, 1024);

  // ================= MLP (QuickGELU) =================
  ln_kernel<<<8192, 256, 0, stream>>>(xf, ln3g, ln3b, hb);
  launch_gemm256<3, 0>(stream, 8192, 4096, 1, hb, nullptr, 1024, 0,
                       w1b, nullptr, nullptr, 1024, 0,
                       hid, nullptr, nullptr, 4096, 0, bb + 8192,
                       1.f, 1024);
  launch_gemm<2, 0, 2>(stream, 8192, 1024, 1, hid, nullptr, 4096, 0,
                       w2b, nullptr, nullptr, 4096, 0,
                       d_out, nullptr, nullptr, 1024, 0, bb + 12288, xf,
                       1.f, 4096);
}

// Round 8
// 803.642 us; speedup vs baseline: 1.2220x; 1.0045x over previous
//
#include <hip/hip_runtime.h>
#include <hip/hip_bf16.h>
#include <cstdint>
#include <cstddef>

// SingleheadTransformerDecoderLayer: L=S=2048, N=4, E=1024, FF=4096, fp32 I/O.
// Round 15 == Round 14 resubmitted verbatim (round-14 bench died to an infra
// container failure before running; deadlock audit found no kernel hang path:
// s_waitcnt is wave-local, all barriers uniform, prologue reachable).
// Round 14: correct the gemm256 ring gates. r13's vmcnt(2) was double-duty:
// it (accidentally) published NEXT tile's ks0 for PH0's early reads while
// allowing only 1 half-tile in flight -> every PH0 stalls on a load issued
// 1 phase earlier (~440 cyc/phase: 516 MFMA + ~570 unoverlapped port +
// ~300 barrier + ~440 drain = 1823 measured). Now TWO counted gates/tile,
// each with 2-3 phases of landing slack:
//   PH0: vmcnt(6)  -- lands tile t ks1 (h=4t+2,3)
//   PH3: vmcnt(8)  -- lands tile t+1 ks0 (h=4t+4,5) for next PH0's early
//        reads  [t==T-2: vmcnt(4); t==T-1: skip; last-tile PH0: vmcnt(0)]
// Also removed per-phase asm lgkmcnt(0)+sched_barrier(0) (rule #18 is for
// asm ds_reads; IR-visible reads get per-MFMA counted lgkmcnt from the
// compiler -> early MFMAs overlap the port drain). WAR/RAW audited per
// stage vs gates. gemm_bt untouched.
//
// Workspace layout (161MB):
//   [0,32)    xf   : fp32 residual [8192,1024]
//   [32,48)   hb   : bf16 LN out
//   [48,64)   vb   : bf16 V          } sb bf16 scores [n][l][s] = [32,64)
//   [64,80)   qb   : bf16 Q          }   (hb,vb dead by score-GEMM time)
//   [80,96)   kb   : bf16 K  (reused as attn-out ao after score GEMM)
//   [96,112)  vt   : bf16 V^T [n][e][s]
//   [48,112)  hid  : bf16 MLP hidden [8192,4096] (vb,qb,kb,vt dead)
//   [112,128) memb : bf16 copy of `memory`
//   [128,160) wts  : bf16 weights; [160,161) bb : bf16 biases

using bf16_t = __bf16;
typedef __bf16 bf16x8 __attribute__((ext_vector_type(8)));
typedef __bf16 bf16x4 __attribute__((ext_vector_type(4)));
typedef float f32x4 __attribute__((ext_vector_type(4)));

// ---------------- async global->LDS, 16B/lane, wave-uniform LDS base --------
__device__ __forceinline__ void gll16(const void* g, void* lds) {
  __builtin_amdgcn_global_load_lds(
      (__attribute__((address_space(1))) void*)(g),
      (__attribute__((address_space(3))) void*)(lds), 16, 0, 0);
}

// ---------------- fp32 -> bf16 cast (8 elems/thread) ------------------------
__global__ __launch_bounds__(256) void f32_to_bf16_n(
    const float* __restrict__ in, bf16_t* __restrict__ out, int n) {
  const size_t i = ((size_t)blockIdx.x * 256 + threadIdx.x) * 8;
  if (i >= (size_t)n) return;
  f32x4 a = *(const f32x4*)(in + i);
  f32x4 b = *(const f32x4*)(in + i + 4);
  bf16x8 v;
#pragma unroll
  for (int j = 0; j < 4; ++j) { v[j] = (bf16_t)a[j]; v[4 + j] = (bf16_t)b[j]; }
  *(bf16x8*)(out + i) = v;
}

// ---------------- fused multi-segment fp32 -> bf16 cast ---------------------
struct CastSeg { const float* src; bf16_t* dst; int chunks; };
struct CastDesc { CastSeg s[16]; };
__global__ __launch_bounds__(256) void cast_multi(CastDesc d) {
  int blk = blockIdx.x, seg = 0, base = 0;
  while (blk - base >= d.s[seg].chunks) { base += d.s[seg].chunks; ++seg; }
  const size_t i = (size_t)(blk - base) * 1024 + threadIdx.x * 4;
  f32x4 a = *(const f32x4*)(d.s[seg].src + i);
  bf16x4 v;
#pragma unroll
  for (int j = 0; j < 4; ++j) v[j] = (bf16_t)a[j];
  *(bf16x4*)(d.s[seg].dst + i) = v;
}

// ---------------- LayerNorm over E=1024, one block per row ------------------
__global__ __launch_bounds__(256) void ln_kernel(
    const float* __restrict__ x, const float* __restrict__ g,
    const float* __restrict__ b, bf16_t* __restrict__ out) {
  const int row = blockIdx.x, tid = threadIdx.x;
  const float* xr = x + (size_t)row * 1024;
  float v0 = xr[tid], v1 = xr[tid + 256], v2 = xr[tid + 512], v3 = xr[tid + 768];
  float s = v0 + v1 + v2 + v3;
  float ss = v0 * v0 + v1 * v1 + v2 * v2 + v3 * v3;
#pragma unroll
  for (int off = 32; off > 0; off >>= 1) {
    s += __shfl_down(s, off, 64);
    ss += __shfl_down(ss, off, 64);
  }
  __shared__ float red[8];
  const int w = tid >> 6, lane = tid & 63;
  if (lane == 0) { red[w] = s; red[4 + w] = ss; }
  __syncthreads();
  s = red[0] + red[1] + red[2] + red[3];
  ss = red[4] + red[5] + red[6] + red[7];
  const float mean = s * (1.f / 1024.f);
  float var = ss * (1.f / 1024.f) - mean * mean;
  var = var < 0.f ? 0.f : var;
  const float inv = rsqrtf(var + 1e-5f);
  bf16_t* orow = out + (size_t)row * 1024;
  orow[tid]       = (bf16_t)((v0 - mean) * inv * g[tid]       + b[tid]);
  orow[tid + 256] = (bf16_t)((v1 - mean) * inv * g[tid + 256] + b[tid + 256]);
  orow[tid + 512] = (bf16_t)((v2 - mean) * inv * g[tid + 512] + b[tid + 512]);
  orow[tid + 768] = (bf16_t)((v3 - mean) * inv * g[tid + 768] + b[tid + 768]);
}

// ---------------- softmax over S=2048, bf16 in-place, optional causal -------
template <int CAUSAL>
__global__ __launch_bounds__(256) void softmax_kernel(bf16_t* __restrict__ sc) {
  const int row = blockIdx.x, tid = threadIdx.x;
  const int l = row & 2047;
  bf16_t* sr = sc + (size_t)row * 2048;
  float v[8];
  float mx = -3.4e38f;
#pragma unroll
  for (int i = 0; i < 8; ++i) {
    const int j = tid + i * 256;
    v[i] = (CAUSAL && j > l) ? -3.4e38f : (float)sr[j];
    mx = fmaxf(mx, v[i]);
  }
#pragma unroll
  for (int off = 32; off > 0; off >>= 1) mx = fmaxf(mx, __shfl_down(mx, off, 64));
  __shared__ float red[8];
  const int w = tid >> 6, lane = tid & 63;
  if (lane == 0) red[w] = mx;
  __syncthreads();
  mx = fmaxf(fmaxf(red[0], red[1]), fmaxf(red[2], red[3]));
  float sum = 0.f;
#pragma unroll
  for (int i = 0; i < 8; ++i) { v[i] = __expf(v[i] - mx); sum += v[i]; }
#pragma unroll
  for (int off = 32; off > 0; off >>= 1) sum += __shfl_down(sum, off, 64);
  if (lane == 0) red[4 + w] = sum;
  __syncthreads();
  sum = red[4] + red[5] + red[6] + red[7];
  const float r = 1.f / sum;
#pragma unroll
  for (int i = 0; i < 8; ++i) sr[tid + i * 256] = (bf16_t)(v[i] * r);
}

// ---------------- V transpose: [s*4+n, e] -> vt[n][e][s] --------------------
__global__ __launch_bounds__(256) void transpose_v(const bf16_t* __restrict__ v,
                                                   bf16_t* __restrict__ vt) {
  __shared__ bf16_t tile[64][72];
  const int n = blockIdx.z;
  const int s0 = blockIdx.x * 64, e0 = blockIdx.y * 64;
  const int tid = threadIdx.x;
#pragma unroll
  for (int j = 0; j < 2; ++j) {
    int flat = j * 256 + tid;
    int r = flat >> 3, c8 = (flat & 7) * 8;
    bf16x8 val = *(const bf16x8*)(v + ((size_t)(s0 + r) * 4 + n) * 1024 + e0 + c8);
#pragma unroll
    for (int i = 0; i < 8; ++i) tile[r][c8 + i] = val[i];
  }
  __syncthreads();
#pragma unroll
  for (int j = 0; j < 2; ++j) {
    int flat = j * 256 + tid;
    int er = flat >> 3, s8 = (flat & 7) * 8;
    bf16x8 val;
#pragma unroll
    for (int i = 0; i < 8; ++i) val[i] = tile[s8 + i][er];
    *(bf16x8*)(vt + ((size_t)n * 1024 + e0 + er) * 2048 + s0 + s8) = val;
  }
}

// ---------------- generic C = A @ W^T GEMM, double-buffered LDS -------------
// (128x128 engine -- for the 128-block grids: PV, out-proj, MLP2)
// Slab per kslice = [128 rows][32 k] row-major (64B row stride), 16B slots
// swizzled: elem(r,k) at byte r*64 + ((k>>3)^((r>>1)&3))*16 + (k&7)*2.
// Staging: gll16 writes linear 1024B rowgroups; global source lane L reads
// row rg*16+(L>>2), k-octet (L&3)^((L>>3)&3) (permutation within one 64B
// run -> coalesced). Frag read: row*32 + (quad^((l15>>1)&3))*8 elems.
// EPI: 0 = bf16 store (acc+bias)*scale; 1 = bf16 store acc;
//      2 = fp32 store res[idx]+acc+bias; 3 = QuickGELU -> bf16.
// MODE: 0 = plain (z = batch); 1 = causal score (skip col0 > row0);
//       2 = causal PV (K capped at row0+128); 3 = fused QKV.
template <int EPI, int MODE, int NS>
__global__ __launch_bounds__(256) void gemm_bt(
    const bf16_t* __restrict__ A, const bf16_t* __restrict__ Aalt,
    long lda, long sA,
    const bf16_t* __restrict__ W0, const bf16_t* __restrict__ W1,
    const bf16_t* __restrict__ W2, long ldw, long sW,
    void* __restrict__ C0, void* __restrict__ C1, void* __restrict__ C2,
    long ldc, long sC,
    const bf16_t* __restrict__ bias, const float* __restrict__ res,
    float scale, int K) {
  const size_t row0 = (size_t)blockIdx.y * 128;
  const size_t col0 = (size_t)blockIdx.x * 128;
  if (MODE == 1 && col0 > row0) return;  // fully-masked causal tile
  const int z = blockIdx.z;
  constexpr int BK = NS * 32;

  const bf16_t* Ap = (MODE == 3) ? (z == 0 ? A : Aalt) : A + (size_t)z * sA;
  const bf16_t* Wp = (MODE == 3) ? (z == 0 ? W0 : (z == 1 ? W1 : W2))
                                 : W0 + (size_t)z * sW;
  void* Cp = (MODE == 3) ? (z == 0 ? C0 : (z == 1 ? C1 : C2)) : C0;
  const size_t zoffC = (MODE == 3) ? 0 : (size_t)z * sC;
  const bf16_t* biasp = bias ? bias + (MODE == 3 ? z * 1024 : 0) : nullptr;
  const float scl = (MODE == 3 && z != 0) ? 1.f : scale;
  const int kend = (MODE == 2) ? min(K, (int)row0 + 128) : K;

  __shared__ __align__(16) bf16_t As[2][NS][128 * 32];
  __shared__ __align__(16) bf16_t Bs[2][NS][128 * 32];
  const int tid = threadIdx.x;
  const int wv = tid >> 6, lane = tid & 63;
  const int quad = lane >> 4, l15 = lane & 15;
  const int wr = wv >> 1, wc = wv & 1;

  // staging: chunk c = wv*2NS+j -> kslice ksc=c>>3, rowgroup rg=c&7.
  // lane L: row rg*16+(L>>2), k-octet (L&3)^((L>>3)&3) (64B-local perm).
  const bf16_t* gA[2 * NS];
  const bf16_t* gW[2 * NS];
  int dof[2 * NS];  // wave-uniform LDS elem offset within parity buffer
  const int soct = (lane & 3) ^ ((lane >> 3) & 3);
#pragma unroll
  for (int j = 0; j < 2 * NS; ++j) {
    const int c = wv * 2 * NS + j;
    const int ksc = c >> 3;
    const int rg = c & 7;
    const int rr = rg * 16 + (lane >> 2);
    const int cc = ksc * 32 + soct * 8;
    gA[j] = Ap + (row0 + rr) * lda + cc;
    gW[j] = Wp + (col0 + rr) * ldw + cc;
    dof[j] = ksc * 4096 + rg * 512;
  }

  f32x4 acc[4][4];
#pragma unroll
  for (int mi = 0; mi < 4; ++mi)
#pragma unroll
    for (int ni = 0; ni < 4; ++ni) acc[mi][ni] = (f32x4)0.f;

#pragma unroll
  for (int j = 0; j < 2 * NS; ++j) {
    gll16(gA[j], &As[0][0][0] + dof[j]);
    gll16(gW[j], &Bs[0][0][0] + dof[j]);
  }

  // frag lane offset: row=base+l15 -> l15*32 + swizzled 16B slot
  const int fro = l15 * 32 + (quad ^ ((l15 >> 1) & 3)) * 8;

  int p = 0;
  for (int k0 = 0; k0 < kend; k0 += BK, p ^= 1) {
    __syncthreads();
    const int kn = k0 + BK;
    if (kn < kend) {
#pragma unroll
      for (int j = 0; j < 2 * NS; ++j) {
        gll16(gA[j] + kn, &As[p ^ 1][0][0] + dof[j]);
        gll16(gW[j] + kn, &Bs[p ^ 1][0][0] + dof[j]);
      }
    }
#pragma unroll
    for (int ks = 0; ks < NS; ++ks) {
      bf16x8 af[4], bfv[4];
#pragma unroll
      for (int mi = 0; mi < 4; ++mi)
        af[mi] = *(const bf16x8*)(As[p][ks] + (wr * 4 + mi) * 512 + fro);
#pragma unroll
      for (int ni = 0; ni < 4; ++ni)
        bfv[ni] = *(const bf16x8*)(Bs[p][ks] + (wc * 4 + ni) * 512 + fro);
#pragma unroll
      for (int mi = 0; mi < 4; ++mi)
#pragma unroll
        for (int ni = 0; ni < 4; ++ni)
          acc[mi][ni] = __builtin_amdgcn_mfma_f32_16x16x32_bf16(
              af[mi], bfv[ni], acc[mi][ni], 0, 0, 0);
    }
  }

  float* Cf = (float*)Cp;
  bf16_t* Cb = (bf16_t*)Cp;
#pragma unroll
  for (int mi = 0; mi < 4; ++mi) {
    const size_t gr = row0 + wr * 64 + mi * 16 + quad * 4;
#pragma unroll
    for (int ni = 0; ni < 4; ++ni) {
      const size_t gc = col0 + wc * 64 + ni * 16 + l15;
      float bv = 0.f;
      if (EPI == 0 || EPI == 2 || EPI == 3) bv = biasp ? (float)biasp[gc] : 0.f;
#pragma unroll
      for (int r = 0; r < 4; ++r) {
        float v = acc[mi][ni][r];
        const size_t idx = zoffC + (gr + r) * ldc + gc;
        if (EPI == 0) {
          Cb[idx] = (bf16_t)((v + bv) * scl);
        } else if (EPI == 1) {
          Cb[idx] = (bf16_t)v;
        } else if (EPI == 2) {
          Cf[idx] = res[idx] + v + bv;
        } else {
          float t = v + bv;
          Cb[idx] = (bf16_t)(t * (1.f / (1.f + __expf(-1.702f * t))));
        }
      }
    }
  }
}

// ---------------- 256x256 8-phase GEMM engine (T3+T4+T5) --------------------
// 512 threads = 8 waves (2M x 4N); wave tile 128x64; BK=64 as two kslice
// slots per operand; 2x double-buffer => 8 slots, 128 KiB total.
// Slab per kslice slot = [256 rows][32 k] row-major with the same 16B-slot
// swizzle as gemm_bt. Staging: wave wid covers rowgroups 2wid, 2wid+1 per
// half; lane L reads row rg*16+(L>>2), k-octet (L&3)^((L>>3)&3); gll16
// dest linear rowgroups.
// Half-tile ring h = {tile u=h>>2, ks=(h>>1)&1, op=h&1}; phase g stages
// h = g+6. Phase body (template order, no pinning):
//   reads(af; bfv if MH0) -> stage(g+6) -> [gate] -> s_barrier
//   -> setprio(1) 16xMFMA setprio(0) -> s_barrier
// Gates (counted, 2-3 phases of landing slack each):
//   PH0: vmcnt(6) lands tile t ks1 (h=4t+2,3); last tile: vmcnt(0)
//   PH3 (t<T-1): vmcnt(8) lands tile t+1 ks0 (h=4t+4,5) for the NEXT
//        PH0's pre-gate reads; t==T-2: vmcnt(4) (ring tail shortens)
// Prologue: stage h=0..5, vmcnt(8) (lands h=0,1), barrier.
// No asm lgkmcnt / sched_barrier: IR-visible ds_reads get per-MFMA counted
// lgkmcnt from the compiler, so early MFMAs overlap the LDS port drain.
// EPI: 0 = bf16 (acc+bias)*scale; 1 = bf16 acc; 3 = QuickGELU bf16.
// MODE: 0 = plain z-batch; 1 = causal score (skip bx>by); 3 = fused QKV.
template <int EPI, int MODE>
__global__ __launch_bounds__(512, 2) void gemm256(
    const bf16_t* __restrict__ A, const bf16_t* __restrict__ Aalt,
    long lda, long sA,
    const bf16_t* __restrict__ W0, const bf16_t* __restrict__ W1,
    const bf16_t* __restrict__ W2, long ldw, long sW,
    void* __restrict__ C0, void* __restrict__ C1, void* __restrict__ C2,
    long ldc, long sC,
    const bf16_t* __restrict__ bias, float scale, int K) {
  // XCD-aware bijective chunked swizzle (all launch grids have nwg % 8 == 0).
  const int gx = gridDim.x, gy = gridDim.y;
  const int nwg = gx * gy * (int)gridDim.z;
  const int hw = (int)blockIdx.x + gx * ((int)blockIdx.y + gy * (int)blockIdx.z);
  const int logical = (hw & 7) * (nwg >> 3) + (hw >> 3);
  const int bx = logical % gx;
  const int by = (logical / gx) % gy;
  const int z  = logical / (gx * gy);
  const size_t row0 = (size_t)by * 256, col0 = (size_t)bx * 256;
  if (MODE == 1 && bx > by) return;  // fully-masked causal tile

  const bf16_t* Ap = (MODE == 3) ? (z == 0 ? A : Aalt) : A + (size_t)z * sA;
  const bf16_t* Wp = (MODE == 3) ? (z == 0 ? W0 : (z == 1 ? W1 : W2))
                                 : W0 + (size_t)z * sW;
  void* Cp = (MODE == 3) ? (z == 0 ? C0 : (z == 1 ? C1 : C2)) : C0;
  const size_t zoffC = (MODE == 3) ? 0 : (size_t)z * sC;
  const bf16_t* biasp = bias ? bias + (MODE == 3 ? z * 1024 : 0) : nullptr;
  const float scl = (MODE == 3 && z != 0) ? 1.f : scale;

  __shared__ __align__(16) bf16_t As[2][2][8192];  // [parity][kslice]
  __shared__ __align__(16) bf16_t Bs[2][2][8192];

  const int tid = threadIdx.x;
  const int lane = tid & 63, wid = tid >> 6;
  const int l15 = lane & 15, quad = lane >> 4;
  const int wm = wid >> 2, wn = wid & 3;

  // Staging: wave wid covers rowgroups 2*wid and 2*wid+1 of each half.
  const int soct = (lane & 3) ^ ((lane >> 3) & 3);
  const bf16_t* pA[2];
  const bf16_t* pB[2];
#pragma unroll
  for (int j = 0; j < 2; ++j) {
    const int rr = (wid * 2 + j) * 16 + (lane >> 2);
    const int kc = soct * 8;
    pA[j] = Ap + (row0 + rr) * lda + kc;
    pB[j] = Wp + (col0 + rr) * ldw + kc;
  }
  const int d0 = (wid * 2) * 512;      // wave-uniform LDS elem base, j=0
  const int d1 = (wid * 2 + 1) * 512;  // j=1

  const int T = K >> 6;    // number of BK=64 tiles
  const int HT = 4 * T;    // total half-tiles

  auto stage = [&](int h) {
    if (h >= HT) return;
    const int u = h >> 2, ks = (h >> 1) & 1;
    const int coff = u * 64 + ks * 32;
    if (h & 1) {
      gll16(pB[0] + coff, &Bs[u & 1][ks][0] + d0);
      gll16(pB[1] + coff, &Bs[u & 1][ks][0] + d1);
    } else {
      gll16(pA[0] + coff, &As[u & 1][ks][0] + d0);
      gll16(pA[1] + coff, &As[u & 1][ks][0] + d1);
    }
  };

  f32x4 acc[2][4][4];
#pragma unroll
  for (int mh = 0; mh < 2; ++mh)
#pragma unroll
    for (int mi = 0; mi < 4; ++mi)
#pragma unroll
      for (int ni = 0; ni < 4; ++ni) acc[mh][mi][ni] = (f32x4)0.f;

  // prologue: 6 halves in flight; vmcnt(8) lands h=0,1 (tile 0 ks0), publish
#pragma unroll
  for (int h = 0; h < 6; ++h) stage(h);
  asm volatile("s_waitcnt vmcnt(8)" ::: "memory");
  __builtin_amdgcn_s_barrier();

  // frag lane offset: row=base+l15 -> l15*32 + swizzled 16B slot
  const int fro = l15 * 32 + (quad ^ ((l15 >> 1) & 3)) * 8;

  for (int t = 0; t < T; ++t) {
    const int p = t & 1;
    const int g4 = 4 * t;
    bf16x8 bfv[4];

// PH: phase 0..3; KK: k-slice; MH: fragment-half. B fragments loaded when
// MH==0, reused (in regs, across phases) when MH==1. Template order:
// reads FIRST, then stage, then gate/barrier, then MFMA (no pinning).
#define PHASE(PH, KK, MH)                                                     \
    {                                                                         \
      bf16x8 af[4];                                                           \
      _Pragma("unroll")                                                       \
      for (int mi = 0; mi < 4; ++mi)                                          \
        af[mi] = *(const bf16x8*)(&As[p][KK][0] +                             \
                                  (wm * 8 + MH * 4 + mi) * 512 + fro);        \
      if (MH == 0) {                                                          \
        _Pragma("unroll")                                                     \
        for (int ni = 0; ni < 4; ++ni)                                        \
          bfv[ni] = *(const bf16x8*)(&Bs[p][KK][0] +                          \
                                     (wn * 4 + ni) * 512 + fro);              \
      }                                                                       \
      stage(g4 + 6 + PH);                                                     \
      if (PH == 0) {                                                          \
        if (t < T - 1) asm volatile("s_waitcnt vmcnt(6)" ::: "memory");       \
        else           asm volatile("s_waitcnt vmcnt(0)" ::: "memory");       \
      }                                                                       \
      if (PH == 3 && t < T - 1) {                                             \
        if (t == T - 2) asm volatile("s_waitcnt vmcnt(4)" ::: "memory");      \
        else            asm volatile("s_waitcnt vmcnt(8)" ::: "memory");      \
      }                                                                       \
      __builtin_amdgcn_s_barrier();                                          \
      __builtin_amdgcn_s_setprio(1);                                         \
      _Pragma("unroll")                                                       \
      for (int mi = 0; mi < 4; ++mi)                                          \
        _Pragma("unroll")                                                     \
        for (int ni = 0; ni < 4; ++ni)                                        \
          acc[MH][mi][ni] = __builtin_amdgcn_mfma_f32_16x16x32_bf16(          \
              af[mi], bfv[ni], acc[MH][mi][ni], 0, 0, 0);                     \
      __builtin_amdgcn_s_setprio(0);                                          \
      __builtin_amdgcn_s_barrier();                                          \
    }

    PHASE(0, 0, 0)
    PHASE(1, 0, 1)
    PHASE(2, 1, 0)
    PHASE(3, 1, 1)
#undef PHASE
  }

  // epilogue: C/D layout col=lane&15, row=quad*4+r
  bf16_t* Cb = (bf16_t*)Cp;
#pragma unroll
  for (int mh = 0; mh < 2; ++mh)
#pragma unroll
    for (int mi = 0; mi < 4; ++mi) {
      const size_t gr = row0 + wm * 128 + mh * 64 + mi * 16 + quad * 4;
#pragma unroll
      for (int ni = 0; ni < 4; ++ni) {
        const size_t gc = col0 + wn * 64 + ni * 16 + l15;
        float bv = 0.f;
        if (EPI == 0 || EPI == 3) bv = biasp ? (float)biasp[gc] : 0.f;
#pragma unroll
        for (int r = 0; r < 4; ++r) {
          const float v = acc[mh][mi][ni][r];
          const size_t idx = zoffC + (gr + r) * ldc + gc;
          if (EPI == 0) {
            Cb[idx] = (bf16_t)((v + bv) * scl);
          } else if (EPI == 1) {
            Cb[idx] = (bf16_t)v;
          } else {
            const float tt = v + bv;
            Cb[idx] = (bf16_t)(tt * (1.f / (1.f + __expf(-1.702f * tt))));
          }
        }
      }
    }
}

// ---------------- host-side launch helpers ----------------------------------
template <int EPI, int MODE, int NS = 1>
static void launch_gemm(hipStream_t stream, int M, int N, int Z,
                        const void* A, const void* Aalt, long lda, long sA,
                        const void* W0, const void* W1, const void* W2,
                        long ldw, long sW,
                        void* C0, void* C1, void* C2, long ldc, long sC,
                        const void* bias, const float* res, float scale, int K) {
  dim3 grid(N / 128, M / 128, Z);
  gemm_bt<EPI, MODE, NS><<<grid, dim3(256), 0, stream>>>(
      (const bf16_t*)A, (const bf16_t*)Aalt, lda, sA,
      (const bf16_t*)W0, (const bf16_t*)W1, (const bf16_t*)W2, ldw, sW,
      C0, C1, C2, ldc, sC, (const bf16_t*)bias, res, scale, K);
}

template <int EPI, int MODE>
static void launch_gemm256(hipStream_t stream, int M, int N, int Z,
                           const void* A, const void* Aalt, long lda, long sA,
                           const void* W0, const void* W1, const void* W2,
                           long ldw, long sW,
                           void* C0, void* C1, void* C2, long ldc, long sC,
                           const void* bias, float scale, int K) {
  dim3 grid(N / 256, M / 256, Z);  // nwg % 8 == 0 for all call sites
  gemm256<EPI, MODE><<<grid, dim3(512), 0, stream>>>(
      (const bf16_t*)A, (const bf16_t*)Aalt, lda, sA,
      (const bf16_t*)W0, (const bf16_t*)W1, (const bf16_t*)W2, ldw, sW,
      C0, C1, C2, ldc, sC, (const bf16_t*)bias, scale, K);
}

extern "C" void kernel_launch(void* const* d_in, const int* in_sizes, int n_in,
                              void* d_out, int out_size, void* d_ws, size_t ws_size,
                              hipStream_t stream) {
  (void)in_sizes; (void)n_in; (void)out_size; (void)ws_size;
  const float* tgt  = (const float*)d_in[0];
  const float* mem  = (const float*)d_in[1];
  // d_in[2] (mask) unused: causality applied structurally.
  const float* sa_qw = (const float*)d_in[3];
  const float* sa_kw = (const float*)d_in[4];
  const float* sa_vw = (const float*)d_in[5];
  const float* sa_b  = (const float*)d_in[6];
  const float* sa_ow = (const float*)d_in[7];
  const float* sa_ob = (const float*)d_in[8];
  const float* ca_qw = (const float*)d_in[9];
  const float* ca_kw = (const float*)d_in[10];
  const float* ca_vw = (const float*)d_in[11];
  const float* ca_b  = (const float*)d_in[12];
  const float* ca_ow = (const float*)d_in[13];
  const float* ca_ob = (const float*)d_in[14];
  const float* ln1g = (const float*)d_in[15];
  const float* ln1b = (const float*)d_in[16];
  const float* ln2g = (const float*)d_in[17];
  const float* ln2b = (const float*)d_in[18];
  const float* ln3g = (const float*)d_in[19];
  const float* ln3b = (const float*)d_in[20];
  const float* w1 = (const float*)d_in[21];
  const float* b1 = (const float*)d_in[22];
  const float* w2 = (const float*)d_in[23];
  const float* b2 = (const float*)d_in[24];

  char* ws = (char*)d_ws;
  const size_t MB = 1048576;
  float*  xf   = (float*)(ws);             // [0,32)   fp32 residual
  bf16_t* hb   = (bf16_t*)(ws + 32 * MB);  // [32,48)  LN out
  bf16_t* vb   = (bf16_t*)(ws + 48 * MB);  // [48,64)  V
  bf16_t* qb   = (bf16_t*)(ws + 64 * MB);  // [64,80)  Q
  bf16_t* kb   = (bf16_t*)(ws + 80 * MB);  // [80,96)  K
  bf16_t* vt   = (bf16_t*)(ws + 96 * MB);  // [96,112) V^T [n][e][s]
  bf16_t* sb   = (bf16_t*)(ws + 32 * MB);  // [32,64)  scores/probs
  bf16_t* ao   = kb;                       // [80,96)  attn out (kb dead)
  bf16_t* hid  = (bf16_t*)(ws + 48 * MB);  // [48,112) MLP hidden
  bf16_t* memb = (bf16_t*)(ws + 112 * MB); // [112,128) bf16 memory
  bf16_t* wt   = (bf16_t*)(ws + 128 * MB); // [128,160) bf16 weights
  bf16_t* bb   = (bf16_t*)(ws + 160 * MB); // biases

  const size_t M1 = 1048576;  // elems per E*E weight
  bf16_t* saq = wt,          *sak = wt + M1,     *sav = wt + 2 * M1;
  bf16_t* sao = wt + 3 * M1, *caq = wt + 4 * M1, *cak = wt + 5 * M1;
  bf16_t* cav = wt + 6 * M1, *cao = wt + 7 * M1;
  bf16_t* w1b = wt + 8 * M1;   // 4M elems
  bf16_t* w2b = wt + 12 * M1;  // 4M elems

  const float qscale = 0.03125f;  // 1024^-0.5

  // ---- fused weight/bias conversions (one launch) ----
  CastDesc cd;
  auto seg = [&](int i, const float* s, bf16_t* d, int elems) {
    cd.s[i] = CastSeg{s, d, elems / 1024};
  };
  seg(0, sa_qw, saq, 1 << 20);  seg(1, sa_kw, sak, 1 << 20);
  seg(2, sa_vw, sav, 1 << 20);  seg(3, sa_ow, sao, 1 << 20);
  seg(4, ca_qw, caq, 1 << 20);  seg(5, ca_kw, cak, 1 << 20);
  seg(6, ca_vw, cav, 1 << 20);  seg(7, ca_ow, cao, 1 << 20);
  seg(8, w1, w1b, 1 << 22);     seg(9, w2, w2b, 1 << 22);
  seg(10, sa_b, bb, 3072);      seg(11, sa_ob, bb + 3072, 1024);
  seg(12, ca_b, bb + 4096, 3072); seg(13, ca_ob, bb + 7168, 1024);
  seg(14, b1, bb + 8192, 4096); seg(15, b2, bb + 12288, 1024);
  int total_chunks = 0;
  for (int i = 0; i < 16; ++i) total_chunks += cd.s[i].chunks;
  cast_multi<<<total_chunks, 256, 0, stream>>>(cd);
  f32_to_bf16_n<<<4096, 256, 0, stream>>>(mem, memb, 1 << 23);

  // ================= self-attention (causal) =================
  ln_kernel<<<8192, 256, 0, stream>>>(tgt, ln1g, ln1b, hb);
  launch_gemm256<0, 3>(stream, 8192, 1024, 3, hb, hb, 1024, 0,
                       saq, sak, sav, 1024, 0, qb, kb, vb, 1024, 0,
                       bb, qscale, 1024);
  transpose_v<<<dim3(32, 16, 4), 256, 0, stream>>>(vb, vt);
  launch_gemm256<1, 1>(stream, 2048, 2048, 4, qb, nullptr, 4096, 1024,
                       kb, nullptr, nullptr, 4096, 1024,
                       sb, nullptr, nullptr, 2048, 4194304, nullptr,
                       1.f, 1024);
  softmax_kernel<1><<<8192, 256, 0, stream>>>(sb);
  launch_gemm<0, 2, 2>(stream, 2048, 1024, 4, sb, nullptr, 2048, 4194304,
                       vt, nullptr, nullptr, 2048, 2097152,
                       ao, nullptr, nullptr, 4096, 1024, nullptr, nullptr,
                       1.f, 2048);
  launch_gemm<2, 0, 2>(stream, 8192, 1024, 1, ao, nullptr, 1024, 0,
                       sao, nullptr, nullptr, 1024, 0,
                       xf, nullptr, nullptr, 1024, 0, bb + 3072, tgt,
                       1.f, 1024);

  // ================= cross-attention (no mask) =================
  ln_kernel<<<8192, 256, 0, stream>>>(xf, ln2g, ln2b, hb);
  launch_gemm256<0, 3>(stream, 8192, 1024, 3, hb, memb, 1024, 0,
                       caq, cak, cav, 1024, 0, qb, kb, vb, 1024, 0,
                       bb + 4096, qscale, 1024);
  transpose_v<<<dim3(32, 16, 4), 256, 0, stream>>>(vb, vt);
  launch_gemm256<1, 0>(stream, 2048, 2048, 4, qb, nullptr, 4096, 1024,
                       kb, nullptr, nullptr, 4096, 1024,
                       sb, nullptr, nullptr, 2048, 4194304, nullptr,
                       1.f, 1024);
  softmax_kernel<0><<<8192, 256, 0, stream>>>(sb);
  launch_gemm<0, 0, 2>(stream, 2048, 1024, 4, sb, nullptr, 2048, 4194304,
                       vt, nullptr, nullptr, 2048, 2097152,
                       ao, nullptr, nullptr, 4096, 1024, nullptr, nullptr,
                       1.f, 2048);
  launch_gemm<2, 0, 2>(stream, 8192, 1024, 1, ao, nullptr, 1024, 0,
                       cao, nullptr, nullptr, 1024, 0,
                       xf, nullptr, nullptr, 1024, 0, bb + 7168, xf,
                       1.f, 1024);

  // ================= MLP (QuickGELU) =================
  ln_kernel<<<8192, 256, 0, stream>>>(xf, ln3g, ln3b, hb);
  launch_gemm256<3, 0>(stream, 8192, 4096, 1, hb, nullptr, 1024, 0,
                       w1b, nullptr, nullptr, 1024, 0,
                       hid, nullptr, nullptr, 4096, 0, bb + 8192,
                       1.f, 1024);
  launch_gemm<2, 0, 2>(stream, 8192, 1024, 1, hid, nullptr, 4096, 0,
                       w2b, nullptr, nullptr, 4096, 0,
                       d_out, nullptr, nullptr, 1024, 0, bb + 12288, xf,
                       1.f, 4096);
}